// Round 12
// baseline (683.411 us; speedup 1.0000x reference)
//
#include <hip/hip_runtime.h>

typedef unsigned short u16;
typedef __bf16 bf16x8 __attribute__((ext_vector_type(8)));
typedef float f32x4 __attribute__((ext_vector_type(4)));
typedef unsigned short u16x8 __attribute__((ext_vector_type(8)));

static __device__ __forceinline__ u16 f2bf(float f) {
  unsigned u = __builtin_bit_cast(unsigned, f);
  u = u + 0x7FFFu + ((u >> 16) & 1u);   // RNE
  return (u16)(u >> 16);
}
static __device__ __forceinline__ float bf2f(u16 h) {
  return __builtin_bit_cast(float, (unsigned)h << 16);
}

#define GLOAD_LDS16(g, l) __builtin_amdgcn_global_load_lds(              \
    (const __attribute__((address_space(1))) void*)(g),                  \
    (__attribute__((address_space(3))) void*)(l), 16, 0, 0)
#define BAR() asm volatile("s_barrier" ::: "memory")
#define VMCNT(n) asm volatile("s_waitcnt vmcnt(" #n ")" ::: "memory")
#define LGKM0() do { asm volatile("s_waitcnt lgkmcnt(0)" ::: "memory");   \
                     __builtin_amdgcn_sched_barrier(0); } while (0)
#define LGKMF() asm volatile("s_waitcnt lgkmcnt(0)" ::: "memory")

// ------------- transpose + convert: W[K][N] f32 -> Wt[N][K] bf16 ----------
__global__ __launch_bounds__(256) void transpose_cvt(const float* __restrict__ W,
                                                     u16* __restrict__ Wt,
                                                     int K, int N) {
  __shared__ float tile[32][33];
  const int tx = threadIdx.x & 31, ty = threadIdx.x >> 5;  // ty: 0..7
  const int n0 = blockIdx.x * 32, k0 = blockIdx.y * 32;
#pragma unroll
  for (int i = 0; i < 4; ++i)
    tile[ty + i * 8][tx] = W[(long)(k0 + ty + i * 8) * N + n0 + tx];
  __syncthreads();
#pragma unroll
  for (int i = 0; i < 4; ++i) {
    int r = ty + i * 8;
    Wt[(long)(n0 + r) * K + k0 + tx] = f2bf(tile[tx][r]);
  }
}

// -------- y [16][77][768] f32 -> yp [16][80][768] bf16, pad rows = 0 -------
__global__ __launch_bounds__(256) void cvt_y_pad(const float* __restrict__ y,
                                                 u16* __restrict__ yp) {
  int idx = blockIdx.x * 256 + threadIdx.x;
  int e = idx * 4;  // element index into [16][80][768]
  int c = e % 768;
  int rb = e / 768;
  int r = rb % 80, b = rb / 80;
  ushort4 o;
  if (r < 77) {
    float4 v = *reinterpret_cast<const float4*>(y + ((long)(b * 77 + r) * 768 + c));
    o.x = f2bf(v.x); o.y = f2bf(v.y); o.z = f2bf(v.z); o.w = f2bf(v.w);
  } else {
    o.x = 0; o.y = 0; o.z = 0; o.w = 0;
  }
  *reinterpret_cast<ushort4*>(yp + e) = o;
}

// ---------------- bias concat: bkv = [bk | bv], 2048 f32 ------------------
__global__ __launch_bounds__(256) void concat_bias(const float* __restrict__ a,
                                                   const float* __restrict__ b,
                                                   float* __restrict__ o) {
  int i = blockIdx.x * 256 + threadIdx.x;
  o[i] = (i < 1024) ? a[i] : b[i - 1024];
}

// -- KV [16][80][2048] bf16 (V at col 1024) -> Vt [16][1024][96] (pad 0) ----
__global__ __launch_bounds__(256) void transpose_v(const u16* __restrict__ KV,
                                                   u16* __restrict__ Vt) {
  __shared__ u16 tile[32][34];
  const int tx = threadIdx.x & 31, ty = threadIdx.x >> 5;  // ty: 0..7
  const int b = blockIdx.z;
  const int k0 = blockIdx.y * 32;   // 0,32,64
  const int e0 = blockIdx.x * 32;
  const u16* src = KV + (long)b * 80 * 2048 + 1024;
#pragma unroll
  for (int i = 0; i < 4; ++i) {
    int k = k0 + ty + i * 8;
    tile[ty + i * 8][tx] = (k < 80) ? src[(long)k * 2048 + e0 + tx] : (u16)0;
  }
  __syncthreads();
  u16* dst = Vt + (long)b * 1024 * 96;
#pragma unroll
  for (int i = 0; i < 4; ++i) {
    int e = e0 + ty + i * 8;
    dst[(long)e * 96 + k0 + tx] = tile[tx][ty + i * 8];
  }
}

// ============ 256x256 m201-style 8-phase bf16 GEMM, C = A @ Bt^T + bias ====
// A_F32: A operand is f32 (x input), fused-converted in staging with a
// 3-phase issue->write distance (T14): A_LOAD at ph1/ph5, A_WRITE at ph4/ph8.
template <bool OUT_BF16, bool A_F32>
__global__ __launch_bounds__(512, 2) void gemm8(const u16* __restrict__ A,
                                                const float* __restrict__ Af,
                                                const u16* __restrict__ Bt,
                                                const float* __restrict__ bias,
                                                void* __restrict__ Cv,
                                                int M, int N, int K) {
  extern __shared__ __align__(16) u16 lds[];
  const int tid = threadIdx.x;
  const int lane = tid & 63, wid = tid >> 6;
  const int lr = lane & 15, lk = lane >> 4;
  const int wr = wid >> 2, wc = wid & 3;

  // T1: chunked XCD swizzle (bijective when grid % 8 == 0)
  int flat = blockIdx.x;
  int nb = gridDim.x;
  int widx = flat;
  if ((nb & 7) == 0) {
    int per = nb >> 3;
    widx = (flat & 7) * per + (flat >> 3);
  }
  const int nbx = N >> 8;
  const long m0 = (long)(widx / nbx) * 256;
  const long n0 = (long)(widx % nbx) * 256;
  const int nt = K >> 6;

  f32x4 acc[8][4] = {};

  const long abase = m0 * (long)K;
  const long bbase = n0 * (long)K;
  const int srl = tid >> 3;
  const int scl = tid & 7;

#define STAGE_HALF(SRC, sbase, t_, half_, ldsbase)                           \
  do {                                                                       \
    long k0_ = (long)(t_) * 64;                                              \
    _Pragma("unroll")                                                        \
    for (int j_ = 0; j_ < 2; ++j_) {                                         \
      int row_ = (half_) * 128 + j_ * 64 + srl;                              \
      int cg_ = scl ^ (row_ & 7);                                            \
      GLOAD_LDS16(SRC + (sbase) + (long)row_ * K + k0_ + cg_ * 8,            \
                  lds + (ldsbase) + row_ * 64 + scl * 8);                    \
    }                                                                        \
  } while (0)

// A reg-stage (A_F32): issue 8 f32x4 loads covering rows 0..255 of tile t_
#define A_LOAD(t_)                                                           \
  _Pragma("unroll")                                                          \
  for (int c_ = 0; c_ < 4; ++c_) {                                           \
    int row_ = c_ * 64 + srl;                                                \
    int cg_ = scl ^ (row_ & 7);                                              \
    const float* ap_ = Af + (long)(m0 + row_) * K + (long)(t_) * 64 + cg_ * 8; \
    areg[c_][0] = *reinterpret_cast<const f32x4*>(ap_);                      \
    areg[c_][1] = *reinterpret_cast<const f32x4*>(ap_ + 4);                  \
  }

// convert + ds_write_b128 into A parity slot p_ (same layout as gload path)
#define A_WRITE(p_)                                                          \
  _Pragma("unroll")                                                          \
  for (int c_ = 0; c_ < 4; ++c_) {                                           \
    int row_ = c_ * 64 + srl;                                                \
    u16x8 v_;                                                                \
    _Pragma("unroll")                                                        \
    for (int e_ = 0; e_ < 4; ++e_) v_[e_] = f2bf(areg[c_][0][e_]);           \
    _Pragma("unroll")                                                        \
    for (int e_ = 0; e_ < 4; ++e_) v_[4 + e_] = f2bf(areg[c_][1][e_]);       \
    *reinterpret_cast<u16x8*>(lds + (p_) * 16384 + row_ * 64 + scl * 8) = v_; \
  }

#define LDB_ALL(p)                                                           \
  _Pragma("unroll")                                                          \
  for (int n_ = 0; n_ < 4; ++n_)                                             \
    _Pragma("unroll")                                                        \
    for (int kk_ = 0; kk_ < 2; ++kk_) {                                      \
      int row_ = wc * 64 + n_ * 16 + lr;                                     \
      int ch_ = (kk_ * 4 + lk) ^ (lr & 7);                                   \
      bq[n_][kk_] = *reinterpret_cast<const bf16x8*>(                        \
          lds + 32768 + (p) * 16384 + row_ * 64 + ch_ * 8);                  \
    }

#define LDA_Q(p, q)                                                          \
  _Pragma("unroll")                                                          \
  for (int i_ = 0; i_ < 2; ++i_)                                             \
    _Pragma("unroll")                                                        \
    for (int kk_ = 0; kk_ < 2; ++kk_) {                                      \
      int row_ = wr * 128 + ((q) * 2 + i_) * 16 + lr;                        \
      int ch_ = (kk_ * 4 + lk) ^ (lr & 7);                                   \
      af[i_][kk_] = *reinterpret_cast<const bf16x8*>(                        \
          lds + (p) * 16384 + row_ * 64 + ch_ * 8);                          \
    }

// kk_ outermost: 8 independent MFMAs between dependent accumulator reuses
#define MFMA_Q(q)                                                            \
  __builtin_amdgcn_s_setprio(1);                                             \
  _Pragma("unroll")                                                          \
  for (int kk_ = 0; kk_ < 2; ++kk_)                                          \
    _Pragma("unroll")                                                        \
    for (int i_ = 0; i_ < 2; ++i_)                                           \
      _Pragma("unroll")                                                      \
      for (int n_ = 0; n_ < 4; ++n_)                                         \
        acc[(q) * 2 + i_][n_] = __builtin_amdgcn_mfma_f32_16x16x32_bf16(     \
            af[i_][kk_], bq[n_][kk_], acc[(q) * 2 + i_][n_], 0, 0, 0);       \
  __builtin_amdgcn_s_setprio(0);

  f32x4 areg[4][2];
  (void)areg;

  // prologue
  if (A_F32) {
    A_LOAD(0);
  } else {
    STAGE_HALF(A, abase, 0, 0, 0);
    STAGE_HALF(A, abase, 0, 1, 0);
  }
  STAGE_HALF(Bt, bbase, 0, 0, 32768);
  STAGE_HALF(Bt, bbase, 0, 1, 32768);
  STAGE_HALF(Bt, bbase, 1, 0, 49152);
  STAGE_HALF(Bt, bbase, 1, 1, 49152);
  if (A_F32) { A_WRITE(0); LGKMF(); }
  VMCNT(4);   // leaves only B(1) in flight
  BAR();

  const int niter = nt >> 1;
  for (int tp = 0; tp < niter; ++tp) {
    const int T = tp << 1;
    const bool more = (T + 2 < nt);
    bf16x8 af[2][2], bq[4][2];

    // ---- tile T (parity 0) ----
    // ph1: issue A(T+1) f32 loads (A_F32) -- consumed 3 phases later
    LDB_ALL(0); LDA_Q(0, 0);
    if (A_F32) { A_LOAD(T + 1); }
    else STAGE_HALF(A, abase, T + 1, 0, 16384);
    BAR(); LGKM0(); MFMA_Q(0); BAR();

    // ph2
    LDA_Q(0, 1);
    if (A_F32) { if (more) STAGE_HALF(Bt, bbase, T + 2, 0, 32768); }
    else STAGE_HALF(A, abase, T + 1, 1, 16384);
    BAR(); LGKM0(); MFMA_Q(1); BAR();

    // ph3
    LDA_Q(0, 2);
    if (A_F32) { if (more) STAGE_HALF(Bt, bbase, T + 2, 1, 32768); }
    else if (more) STAGE_HALF(Bt, bbase, T + 2, 0, 32768);
    BAR(); LGKM0(); MFMA_Q(2); BAR();

    // ph4: A_F32: convert+write A(T+1) (reg-dep drains A loads + older B);
    //      publish ds_writes with lgkmcnt(0) BEFORE the barrier.
    LDA_Q(0, 3);
    if (A_F32) {
      A_WRITE(1); LGKMF();
    } else {
      if (more) { STAGE_HALF(Bt, bbase, T + 2, 1, 32768); VMCNT(4); }
      else VMCNT(0);
    }
    BAR(); LGKM0(); MFMA_Q(3); BAR();

    // ---- tile T+1 (parity 1) ----
    // ph5
    LDB_ALL(1); LDA_Q(1, 0);
    if (A_F32) { if (more) A_LOAD(T + 2); }
    else if (more) STAGE_HALF(A, abase, T + 2, 0, 0);
    BAR(); LGKM0(); MFMA_Q(0); BAR();

    // ph6
    LDA_Q(1, 1);
    if (A_F32) { if (more) STAGE_HALF(Bt, bbase, T + 3, 0, 49152); }
    else if (more) STAGE_HALF(A, abase, T + 2, 1, 0);
    BAR(); LGKM0(); MFMA_Q(1); BAR();

    // ph7
    LDA_Q(1, 2);
    if (A_F32) { if (more) STAGE_HALF(Bt, bbase, T + 3, 1, 49152); }
    else if (more) STAGE_HALF(Bt, bbase, T + 3, 0, 49152);
    BAR(); LGKM0(); MFMA_Q(2); BAR();

    // ph8
    LDA_Q(1, 3);
    if (A_F32) {
      if (more) { A_WRITE(0); LGKMF(); VMCNT(4); }  // B(T+3) stays in flight
    } else {
      if (more) { STAGE_HALF(Bt, bbase, T + 3, 1, 49152); VMCNT(4); }
    }
    BAR(); LGKM0(); MFMA_Q(3); BAR();
  }

  const long mrow = m0 + wr * 128;
  const long ncol = n0 + wc * 64;

  if (OUT_BF16) {
#pragma unroll
    for (int n = 0; n < 4; ++n) {
      long col = ncol + n * 16 + lr;
      float bb = bias[col];
#pragma unroll
      for (int m = 0; m < 8; ++m)
#pragma unroll
        for (int j = 0; j < 4; ++j) {
          long row = mrow + m * 16 + lk * 4 + j;
          unsigned h = f2bf(acc[m][n][j] + bb);
          unsigned ph = h | (((unsigned)__shfl_xor((int)h, 1, 64)) << 16);
          unsigned p2 = (unsigned)__shfl_xor((int)ph, 2, 64);
          if ((lane & 3) == 0) {
            uint2 o; o.x = ph; o.y = p2;
            *reinterpret_cast<uint2*>((u16*)Cv + row * N + col) = o;
          }
        }
    }
  } else {
    // f32 epilogue: per-wave LDS transpose (stride 68, 2-way = free) ->
    // coalesced f32x4 stores (4 rows x 256B contiguous per instruction)
    __syncthreads();
    float* ep = reinterpret_cast<float*>(lds) + wid * (16 * 68);
    float bb[4];
#pragma unroll
    for (int n = 0; n < 4; ++n) bb[n] = bias[ncol + n * 16 + lr];
    const int rr = lane >> 4, cc = lane & 15;
#pragma unroll
    for (int m = 0; m < 8; ++m) {
#pragma unroll
      for (int n = 0; n < 4; ++n)
#pragma unroll
        for (int j = 0; j < 4; ++j)
          ep[(lk * 4 + j) * 68 + n * 16 + lr] = acc[m][n][j] + bb[n];
      asm volatile("s_waitcnt lgkmcnt(0)" ::: "memory");
#pragma unroll
      for (int s = 0; s < 4; ++s) {
        f32x4 v = *reinterpret_cast<const f32x4*>(ep + (s * 4 + rr) * 68 + cc * 4);
        *reinterpret_cast<f32x4*>((float*)Cv + (mrow + m * 16 + s * 4 + rr) * N +
                                  ncol + cc * 4) = v;
      }
      asm volatile("s_waitcnt lgkmcnt(0)" ::: "memory");
    }
  }
#undef STAGE_HALF
#undef A_LOAD
#undef A_WRITE
#undef LDB_ALL
#undef LDA_Q
#undef MFMA_Q
}

// ------- fused attention (r7-proven): 16 q-rows per block, in-place on Q ---
// Q [16*4096][1024] bf16 (overwritten), KV [16][80][2048] bf16 (K = cols
// 0..1023; rows 77..79 masked), Vt [16][1024][96] bf16 (k-pad zeroed).
__global__ __launch_bounds__(256) void attn_fused(u16* __restrict__ Q,
                                                  const u16* __restrict__ KV,
                                                  const u16* __restrict__ Vt) {
  const int blk = blockIdx.x;
  const int b = blk >> 8;               // 256 blocks per batch (4096/16)
  const int q0 = (blk & 255) << 4;
  const long qoff = ((long)b * 4096 + q0) * 1024;
  const int tid = threadIdx.x;
  const int lane = tid & 63, wave = tid >> 6;
  const int lr = lane & 15, lk = lane >> 4;

  __shared__ float S4[4][16][80];
  __shared__ __align__(16) u16 P_lds[16][104];  // bf16 P, stride 104 breaks banks

  // Phase 1: scores via MFMA; wave w covers k-dim slice w*256 .. +255
  f32x4 acc[5] = {};
  const u16* qb = Q + qoff;
  const u16* kb = KV + (long)b * 80 * 2048;
#pragma unroll
  for (int t = 0; t < 8; ++t) {
    int kk = wave * 8 + t;
    bf16x8 qa = *reinterpret_cast<const bf16x8*>(qb + lr * 1024 + kk * 32 + lk * 8);
#pragma unroll
    for (int n = 0; n < 5; ++n) {
      bf16x8 kf = *reinterpret_cast<const bf16x8*>(kb + (long)(n * 16 + lr) * 2048 + kk * 32 + lk * 8);
      acc[n] = __builtin_amdgcn_mfma_f32_16x16x32_bf16(qa, kf, acc[n], 0, 0, 0);
    }
  }
#pragma unroll
  for (int n = 0; n < 5; ++n)
#pragma unroll
    for (int j = 0; j < 4; ++j)
      S4[wave][lk * 4 + j][n * 16 + lr] = acc[n][j];
  __syncthreads();

  // Phase 2: cross-wave reduce + softmax -> P_lds (bf16, cols 80..95 zeroed)
  {
    const int r = tid >> 4, ci = tid & 15;
    const float scale = 0.088388347648318447f;  // 1/sqrt(128)
    float v[5];
    float mx = -3e38f;
#pragma unroll
    for (int i = 0; i < 5; ++i) {
      int c = ci + 16 * i;
      float s = (S4[0][r][c] + S4[1][r][c]) + (S4[2][r][c] + S4[3][r][c]);
      s *= scale;
      if (c >= 77) s = -3e38f;
      v[i] = s;
      mx = fmaxf(mx, s);
    }
#pragma unroll
    for (int off = 1; off < 16; off <<= 1) mx = fmaxf(mx, __shfl_xor(mx, off, 64));
    float sum = 0.f, e[5];
#pragma unroll
    for (int i = 0; i < 5; ++i) { e[i] = __expf(v[i] - mx); sum += e[i]; }
#pragma unroll
    for (int off = 1; off < 16; off <<= 1) sum += __shfl_xor(sum, off, 64);
    float inv = 1.f / sum;
#pragma unroll
    for (int i = 0; i < 5; ++i) P_lds[r][ci + 16 * i] = f2bf(e[i] * inv);
    P_lds[r][80 + ci] = 0;
  }
  __syncthreads();

  // Phase 3: PV via MFMA. A = P (rows = q), B = Vt rows (cols = e), K = 96.
  bf16x8 pa[3];
#pragma unroll
  for (int kk = 0; kk < 3; ++kk)
    pa[kk] = *reinterpret_cast<const bf16x8*>(&P_lds[lr][kk * 32 + lk * 8]);
  const u16* vt = Vt + (long)b * 1024 * 96;
  u16* ob = Q + qoff;
#pragma unroll
  for (int n = 0; n < 16; ++n) {
    int col = wave * 256 + n * 16 + lr;
    f32x4 o = {};
#pragma unroll
    for (int kk = 0; kk < 3; ++kk) {
      bf16x8 vq = *reinterpret_cast<const bf16x8*>(vt + (long)col * 96 + kk * 32 + lk * 8);
      o = __builtin_amdgcn_mfma_f32_16x16x32_bf16(pa[kk], vq, o, 0, 0, 0);
    }
#pragma unroll
    for (int j = 0; j < 4; ++j) {
      unsigned h = f2bf(o[j]);
      unsigned ph = h | (((unsigned)__shfl_xor((int)h, 1, 64)) << 16);
      unsigned p2 = (unsigned)__shfl_xor((int)ph, 2, 64);
      if ((lane & 3) == 0) {
        uint2 st; st.x = ph; st.y = p2;
        *reinterpret_cast<uint2*>(ob + (long)(lk * 4 + j) * 1024 + col) = st;
      }
    }
  }
}

extern "C" void kernel_launch(void* const* d_in, const int* in_sizes, int n_in,
                              void* d_out, int out_size, void* d_ws, size_t ws_size,
                              hipStream_t stream) {
  const float* x  = (const float*)d_in[0];
  const float* y  = (const float*)d_in[1];
  const float* Wq = (const float*)d_in[2];
  const float* bq = (const float*)d_in[3];
  const float* Wk = (const float*)d_in[4];
  const float* bk = (const float*)d_in[5];
  const float* Wv = (const float*)d_in[6];
  const float* bv = (const float*)d_in[7];
  const float* Wo = (const float*)d_in[8];
  const float* bo = (const float*)d_in[9];

  const int B = 16, Lq = 4096, D = 1024, Dc = 768, Lp = 80;
  const long Mq = (long)B * Lq;  // 65536

  char* p = (char*)d_ws;
  u16* Qb   = (u16*)p; p += (size_t)Mq * D * 2;       // Q, then attn out (in-place)
  u16* Wqt  = (u16*)p; p += (size_t)D * D * 2;
  u16* Wkvt = (u16*)p; p += (size_t)2 * D * Dc * 2;   // [2048][768]: Wk^T | Wv^T
  u16* Wot  = (u16*)p; p += (size_t)D * D * 2;
  u16* yp   = (u16*)p; p += (size_t)B * Lp * Dc * 2;  // [16][80][768], pad zeroed
  u16* KV   = (u16*)p; p += (size_t)B * Lp * 2 * D * 2; // [16][80][2048]
  u16* Vt   = (u16*)p; p += (size_t)B * D * 96 * 2;   // [16][1024][96]
  float* bkv = (float*)p; p += (size_t)2 * D * 4;     // [2048]

  (void)hipFuncSetAttribute(reinterpret_cast<const void*>(&gemm8<true, false>),
                            hipFuncAttributeMaxDynamicSharedMemorySize, 131072);
  (void)hipFuncSetAttribute(reinterpret_cast<const void*>(&gemm8<true, true>),
                            hipFuncAttributeMaxDynamicSharedMemorySize, 131072);
  (void)hipFuncSetAttribute(reinterpret_cast<const void*>(&gemm8<false, false>),
                            hipFuncAttributeMaxDynamicSharedMemorySize, 131072);

  // weight conversions (x -> bf16 pass eliminated: fused into Q-proj staging)
  transpose_cvt<<<dim3(D / 32, D / 32), 256, 0, stream>>>(Wq, Wqt, D, D);
  transpose_cvt<<<dim3(D / 32, Dc / 32), 256, 0, stream>>>(Wk, Wkvt, Dc, D);
  transpose_cvt<<<dim3(D / 32, Dc / 32), 256, 0, stream>>>(Wv, Wkvt + (size_t)D * Dc, Dc, D);
  transpose_cvt<<<dim3(D / 32, D / 32), 256, 0, stream>>>(Wo, Wot, D, D);
  cvt_y_pad<<<(B * Lp * Dc / 4) / 256, 256, 0, stream>>>(y, yp);
  concat_bias<<<8, 256, 0, stream>>>(bk, bv, bkv);

  // fused K|V projection: [1280][768] @ [768][2048] -> [1280][2048]
  gemm8<true, false><<<(1280 / 256) * (2 * D / 256), 512, 131072, stream>>>(
      yp, nullptr, Wkvt, bkv, KV, B * Lp, 2 * D, Dc);

  // V transpose for MFMA PV: KV cols 1024.. -> [16][1024][96]
  transpose_v<<<dim3(D / 32, 3, B), 256, 0, stream>>>(KV, Vt);

  // Q projection: [65536][1024] f32 x (converted in-staging) @ [1024][1024]
  gemm8<true, true><<<(int)(Mq / 256) * (D / 256), 512, 131072, stream>>>(
      nullptr, x, Wqt, bq, Qb, (int)Mq, D, D);

  // fused attention, writes back into Qb (16 q-rows per block, r7 version)
  attn_fused<<<(int)(Mq / 16), 256, 0, stream>>>(Qb, KV, Vt);

  // output projection: [65536][1024] @ [1024][1024] -> d_out f32
  gemm8<false, false><<<(int)(Mq / 256) * (D / 256), 512, 131072, stream>>>(
      Qb, nullptr, Wot, bo, d_out, (int)Mq, D, D);
}

// Round 13
// 580.743 us; speedup vs baseline: 1.1768x; 1.1768x over previous
//
#include <hip/hip_runtime.h>

typedef unsigned short u16;
typedef __bf16 bf16x8 __attribute__((ext_vector_type(8)));
typedef float f32x4 __attribute__((ext_vector_type(4)));

static __device__ __forceinline__ u16 f2bf(float f) {
  unsigned u = __builtin_bit_cast(unsigned, f);
  u = u + 0x7FFFu + ((u >> 16) & 1u);   // RNE
  return (u16)(u >> 16);
}
static __device__ __forceinline__ float bf2f(u16 h) {
  return __builtin_bit_cast(float, (unsigned)h << 16);
}

#define GLOAD_LDS16(g, l) __builtin_amdgcn_global_load_lds(              \
    (const __attribute__((address_space(1))) void*)(g),                  \
    (__attribute__((address_space(3))) void*)(l), 16, 0, 0)
#define BAR() asm volatile("s_barrier" ::: "memory")
#define VMCNT(n) asm volatile("s_waitcnt vmcnt(" #n ")" ::: "memory")
#define LGKM0() do { asm volatile("s_waitcnt lgkmcnt(0)" ::: "memory");   \
                     __builtin_amdgcn_sched_barrier(0); } while (0)

// ---------------- elementwise f32 -> bf16 (4 elems/thread) ----------------
__global__ __launch_bounds__(256) void cvt_f32_bf16(const float* __restrict__ in,
                                                    u16* __restrict__ out, long n4) {
  long i = (long)blockIdx.x * 256 + threadIdx.x;
  if (i >= n4) return;
  float4 v = reinterpret_cast<const float4*>(in)[i];
  ushort4 o;
  o.x = f2bf(v.x); o.y = f2bf(v.y); o.z = f2bf(v.z); o.w = f2bf(v.w);
  reinterpret_cast<ushort4*>(out)[i] = o;
}

// ------------- transpose + convert: W[K][N] f32 -> Wt[N][K] bf16 ----------
__global__ __launch_bounds__(256) void transpose_cvt(const float* __restrict__ W,
                                                     u16* __restrict__ Wt,
                                                     int K, int N) {
  __shared__ float tile[32][33];
  const int tx = threadIdx.x & 31, ty = threadIdx.x >> 5;  // ty: 0..7
  const int n0 = blockIdx.x * 32, k0 = blockIdx.y * 32;
#pragma unroll
  for (int i = 0; i < 4; ++i)
    tile[ty + i * 8][tx] = W[(long)(k0 + ty + i * 8) * N + n0 + tx];
  __syncthreads();
#pragma unroll
  for (int i = 0; i < 4; ++i) {
    int r = ty + i * 8;
    Wt[(long)(n0 + r) * K + k0 + tx] = f2bf(tile[tx][r]);
  }
}

// -------- y [16][77][768] f32 -> yp [16][80][768] bf16, pad rows = 0 -------
__global__ __launch_bounds__(256) void cvt_y_pad(const float* __restrict__ y,
                                                 u16* __restrict__ yp) {
  int idx = blockIdx.x * 256 + threadIdx.x;
  int e = idx * 4;  // element index into [16][80][768]
  int c = e % 768;
  int rb = e / 768;
  int r = rb % 80, b = rb / 80;
  ushort4 o;
  if (r < 77) {
    float4 v = *reinterpret_cast<const float4*>(y + ((long)(b * 77 + r) * 768 + c));
    o.x = f2bf(v.x); o.y = f2bf(v.y); o.z = f2bf(v.z); o.w = f2bf(v.w);
  } else {
    o.x = 0; o.y = 0; o.z = 0; o.w = 0;
  }
  *reinterpret_cast<ushort4*>(yp + e) = o;
}

// ---------------- bias concat: bkv = [bk | bv], 2048 f32 ------------------
__global__ __launch_bounds__(256) void concat_bias(const float* __restrict__ a,
                                                   const float* __restrict__ b,
                                                   float* __restrict__ o) {
  int i = blockIdx.x * 256 + threadIdx.x;
  o[i] = (i < 1024) ? a[i] : b[i - 1024];
}

// -- KV [16][80][2048] bf16 (V at col 1024) -> Vt [16][1024][96] (pad 0) ----
__global__ __launch_bounds__(256) void transpose_v(const u16* __restrict__ KV,
                                                   u16* __restrict__ Vt) {
  __shared__ u16 tile[32][34];
  const int tx = threadIdx.x & 31, ty = threadIdx.x >> 5;  // ty: 0..7
  const int b = blockIdx.z;
  const int k0 = blockIdx.y * 32;   // 0,32,64
  const int e0 = blockIdx.x * 32;
  const u16* src = KV + (long)b * 80 * 2048 + 1024;
#pragma unroll
  for (int i = 0; i < 4; ++i) {
    int k = k0 + ty + i * 8;
    tile[ty + i * 8][tx] = (k < 80) ? src[(long)k * 2048 + e0 + tx] : (u16)0;
  }
  __syncthreads();
  u16* dst = Vt + (long)b * 1024 * 96;
#pragma unroll
  for (int i = 0; i < 4; ++i) {
    int e = e0 + ty + i * 8;
    dst[(long)e * 96 + k0 + tx] = tile[tx][ty + i * 8];
  }
}

// ============ 256x256 m201-style 8-phase bf16 GEMM, C = A @ Bt^T + bias ====
// (r7-proven loop; NEW: bf16 epilogue also goes through LDS transpose so
// every store instruction writes full 128B lines -- kills the 2.4x HBM
// write amplification measured on the shfl-pack path.)
template <bool OUT_BF16>
__global__ __launch_bounds__(512, 2) void gemm8(const u16* __restrict__ A,
                                                const u16* __restrict__ Bt,
                                                const float* __restrict__ bias,
                                                void* __restrict__ Cv,
                                                int M, int N, int K) {
  extern __shared__ __align__(16) u16 lds[];
  const int tid = threadIdx.x;
  const int lane = tid & 63, wid = tid >> 6;
  const int lr = lane & 15, lk = lane >> 4;
  const int wr = wid >> 2, wc = wid & 3;

  // T1: chunked XCD swizzle (bijective when grid % 8 == 0)
  int flat = blockIdx.x;
  int nb = gridDim.x;
  int widx = flat;
  if ((nb & 7) == 0) {
    int per = nb >> 3;
    widx = (flat & 7) * per + (flat >> 3);
  }
  const int nbx = N >> 8;
  const long m0 = (long)(widx / nbx) * 256;
  const long n0 = (long)(widx % nbx) * 256;
  const int nt = K >> 6;

  f32x4 acc[8][4] = {};

  const long abase = m0 * (long)K;
  const long bbase = n0 * (long)K;
  const int srl = tid >> 3;
  const int scl = tid & 7;

#define STAGE_HALF(SRC, sbase, t_, half_, ldsbase)                           \
  do {                                                                       \
    long k0_ = (long)(t_) * 64;                                              \
    _Pragma("unroll")                                                        \
    for (int j_ = 0; j_ < 2; ++j_) {                                         \
      int row_ = (half_) * 128 + j_ * 64 + srl;                              \
      int cg_ = scl ^ (row_ & 7);                                            \
      GLOAD_LDS16(SRC + (sbase) + (long)row_ * K + k0_ + cg_ * 8,            \
                  lds + (ldsbase) + row_ * 64 + scl * 8);                    \
    }                                                                        \
  } while (0)

#define LDB_ALL(p)                                                           \
  _Pragma("unroll")                                                          \
  for (int n_ = 0; n_ < 4; ++n_)                                             \
    _Pragma("unroll")                                                        \
    for (int kk_ = 0; kk_ < 2; ++kk_) {                                      \
      int row_ = wc * 64 + n_ * 16 + lr;                                     \
      int ch_ = (kk_ * 4 + lk) ^ (lr & 7);                                   \
      bq[n_][kk_] = *reinterpret_cast<const bf16x8*>(                        \
          lds + 32768 + (p) * 16384 + row_ * 64 + ch_ * 8);                  \
    }

#define LDA_Q(p, q)                                                          \
  _Pragma("unroll")                                                          \
  for (int i_ = 0; i_ < 2; ++i_)                                             \
    _Pragma("unroll")                                                        \
    for (int kk_ = 0; kk_ < 2; ++kk_) {                                      \
      int row_ = wr * 128 + ((q) * 2 + i_) * 16 + lr;                        \
      int ch_ = (kk_ * 4 + lk) ^ (lr & 7);                                   \
      af[i_][kk_] = *reinterpret_cast<const bf16x8*>(                        \
          lds + (p) * 16384 + row_ * 64 + ch_ * 8);                          \
    }

// kk_ outermost: 8 independent MFMAs between dependent accumulator reuses
#define MFMA_Q(q)                                                            \
  __builtin_amdgcn_s_setprio(1);                                             \
  _Pragma("unroll")                                                          \
  for (int kk_ = 0; kk_ < 2; ++kk_)                                          \
    _Pragma("unroll")                                                        \
    for (int i_ = 0; i_ < 2; ++i_)                                           \
      _Pragma("unroll")                                                      \
      for (int n_ = 0; n_ < 4; ++n_)                                         \
        acc[(q) * 2 + i_][n_] = __builtin_amdgcn_mfma_f32_16x16x32_bf16(     \
            af[i_][kk_], bq[n_][kk_], acc[(q) * 2 + i_][n_], 0, 0, 0);       \
  __builtin_amdgcn_s_setprio(0);

  STAGE_HALF(A, abase, 0, 0, 0);
  STAGE_HALF(A, abase, 0, 1, 0);
  STAGE_HALF(Bt, bbase, 0, 0, 32768);
  STAGE_HALF(Bt, bbase, 0, 1, 32768);
  STAGE_HALF(Bt, bbase, 1, 0, 49152);
  STAGE_HALF(Bt, bbase, 1, 1, 49152);
  VMCNT(4);
  BAR();

  const int niter = nt >> 1;
  for (int tp = 0; tp < niter; ++tp) {
    const int T = tp << 1;
    const bool more = (T + 2 < nt);
    bf16x8 af[2][2], bq[4][2];

    // ---- tile T (parity 0) ----
    LDB_ALL(0); LDA_Q(0, 0);
    STAGE_HALF(A, abase, T + 1, 0, 16384);
    BAR(); LGKM0(); MFMA_Q(0); BAR();
    LDA_Q(0, 1);
    STAGE_HALF(A, abase, T + 1, 1, 16384);
    BAR(); LGKM0(); MFMA_Q(1); BAR();
    LDA_Q(0, 2);
    if (more) STAGE_HALF(Bt, bbase, T + 2, 0, 32768);
    BAR(); LGKM0(); MFMA_Q(2); BAR();
    LDA_Q(0, 3);
    if (more) { STAGE_HALF(Bt, bbase, T + 2, 1, 32768); VMCNT(4); }
    else VMCNT(0);
    BAR(); LGKM0(); MFMA_Q(3); BAR();

    // ---- tile T+1 (parity 1) ----
    LDB_ALL(1); LDA_Q(1, 0);
    if (more) STAGE_HALF(A, abase, T + 2, 0, 0);
    BAR(); LGKM0(); MFMA_Q(0); BAR();
    LDA_Q(1, 1);
    if (more) STAGE_HALF(A, abase, T + 2, 1, 0);
    BAR(); LGKM0(); MFMA_Q(1); BAR();
    LDA_Q(1, 2);
    if (more) STAGE_HALF(Bt, bbase, T + 3, 0, 49152);
    BAR(); LGKM0(); MFMA_Q(2); BAR();
    LDA_Q(1, 3);
    if (more) { STAGE_HALF(Bt, bbase, T + 3, 1, 49152); VMCNT(4); }
    BAR(); LGKM0(); MFMA_Q(3); BAR();
  }

  const long mrow = m0 + wr * 128;
  const long ncol = n0 + wc * 64;

  if (OUT_BF16) {
    // bf16 epilogue via LDS transpose: per wave a 16x72 u16 tile (stride 72
    // -> 2-way bank alias = free); each store instruction then writes 4 rows
    // x 128B FULL lines (16 lanes x 8B contiguous; ncol*2B is 128B-aligned).
    __syncthreads();                       // K-loop LDS dead, reuse it
    u16* ep = lds + wid * (16 * 72);
    float bb[4];
#pragma unroll
    for (int n = 0; n < 4; ++n) bb[n] = bias[ncol + n * 16 + lr];
    const int rr = lane >> 4, cc = lane & 15;
#pragma unroll
    for (int m = 0; m < 8; ++m) {
#pragma unroll
      for (int n = 0; n < 4; ++n)
#pragma unroll
        for (int j = 0; j < 4; ++j)
          ep[(lk * 4 + j) * 72 + n * 16 + lr] = f2bf(acc[m][n][j] + bb[n]);
      asm volatile("s_waitcnt lgkmcnt(0)" ::: "memory");
#pragma unroll
      for (int s = 0; s < 4; ++s) {
        uint2 v = *reinterpret_cast<const uint2*>(ep + (s * 4 + rr) * 72 + cc * 4);
        *reinterpret_cast<uint2*>((u16*)Cv + (mrow + m * 16 + s * 4 + rr) * N +
                                  ncol + cc * 4) = v;
      }
      asm volatile("s_waitcnt lgkmcnt(0)" ::: "memory");
    }
  } else {
    // f32 epilogue: per-wave LDS transpose (stride 68, 2-way = free) ->
    // coalesced f32x4 stores (4 rows x 256B contiguous per instruction)
    __syncthreads();
    float* ep = reinterpret_cast<float*>(lds) + wid * (16 * 68);
    float bb[4];
#pragma unroll
    for (int n = 0; n < 4; ++n) bb[n] = bias[ncol + n * 16 + lr];
    const int rr = lane >> 4, cc = lane & 15;
#pragma unroll
    for (int m = 0; m < 8; ++m) {
#pragma unroll
      for (int n = 0; n < 4; ++n)
#pragma unroll
        for (int j = 0; j < 4; ++j)
          ep[(lk * 4 + j) * 68 + n * 16 + lr] = acc[m][n][j] + bb[n];
      asm volatile("s_waitcnt lgkmcnt(0)" ::: "memory");
#pragma unroll
      for (int s = 0; s < 4; ++s) {
        f32x4 v = *reinterpret_cast<const f32x4*>(ep + (s * 4 + rr) * 68 + cc * 4);
        *reinterpret_cast<f32x4*>((float*)Cv + (mrow + m * 16 + s * 4 + rr) * N +
                                  ncol + cc * 4) = v;
      }
      asm volatile("s_waitcnt lgkmcnt(0)" ::: "memory");
    }
  }
#undef STAGE_HALF
#undef LDB_ALL
#undef LDA_Q
#undef MFMA_Q
}

// ------- fused attention (r7-proven): 16 q-rows per block, in-place on Q ---
// Q [16*4096][1024] bf16 (overwritten), KV [16][80][2048] bf16 (K = cols
// 0..1023; rows 77..79 masked), Vt [16][1024][96] bf16 (k-pad zeroed).
__global__ __launch_bounds__(256) void attn_fused(u16* __restrict__ Q,
                                                  const u16* __restrict__ KV,
                                                  const u16* __restrict__ Vt) {
  const int blk = blockIdx.x;
  const int b = blk >> 8;               // 256 blocks per batch (4096/16)
  const int q0 = (blk & 255) << 4;
  const long qoff = ((long)b * 4096 + q0) * 1024;
  const int tid = threadIdx.x;
  const int lane = tid & 63, wave = tid >> 6;
  const int lr = lane & 15, lk = lane >> 4;

  __shared__ float S4[4][16][80];
  __shared__ __align__(16) u16 P_lds[16][104];  // bf16 P, stride 104 breaks banks

  // Phase 1: scores via MFMA; wave w covers k-dim slice w*256 .. +255
  f32x4 acc[5] = {};
  const u16* qb = Q + qoff;
  const u16* kb = KV + (long)b * 80 * 2048;
#pragma unroll
  for (int t = 0; t < 8; ++t) {
    int kk = wave * 8 + t;
    bf16x8 qa = *reinterpret_cast<const bf16x8*>(qb + lr * 1024 + kk * 32 + lk * 8);
#pragma unroll
    for (int n = 0; n < 5; ++n) {
      bf16x8 kf = *reinterpret_cast<const bf16x8*>(kb + (long)(n * 16 + lr) * 2048 + kk * 32 + lk * 8);
      acc[n] = __builtin_amdgcn_mfma_f32_16x16x32_bf16(qa, kf, acc[n], 0, 0, 0);
    }
  }
#pragma unroll
  for (int n = 0; n < 5; ++n)
#pragma unroll
    for (int j = 0; j < 4; ++j)
      S4[wave][lk * 4 + j][n * 16 + lr] = acc[n][j];
  __syncthreads();

  // Phase 2: cross-wave reduce + softmax -> P_lds (bf16, cols 80..95 zeroed)
  {
    const int r = tid >> 4, ci = tid & 15;
    const float scale = 0.088388347648318447f;  // 1/sqrt(128)
    float v[5];
    float mx = -3e38f;
#pragma unroll
    for (int i = 0; i < 5; ++i) {
      int c = ci + 16 * i;
      float s = (S4[0][r][c] + S4[1][r][c]) + (S4[2][r][c] + S4[3][r][c]);
      s *= scale;
      if (c >= 77) s = -3e38f;
      v[i] = s;
      mx = fmaxf(mx, s);
    }
#pragma unroll
    for (int off = 1; off < 16; off <<= 1) mx = fmaxf(mx, __shfl_xor(mx, off, 64));
    float sum = 0.f, e[5];
#pragma unroll
    for (int i = 0; i < 5; ++i) { e[i] = __expf(v[i] - mx); sum += e[i]; }
#pragma unroll
    for (int off = 1; off < 16; off <<= 1) sum += __shfl_xor(sum, off, 64);
    float inv = 1.f / sum;
#pragma unroll
    for (int i = 0; i < 5; ++i) P_lds[r][ci + 16 * i] = f2bf(e[i] * inv);
    P_lds[r][80 + ci] = 0;
  }
  __syncthreads();

  // Phase 3: PV via MFMA. A = P (rows = q), B = Vt rows (cols = e), K = 96.
  bf16x8 pa[3];
#pragma unroll
  for (int kk = 0; kk < 3; ++kk)
    pa[kk] = *reinterpret_cast<const bf16x8*>(&P_lds[lr][kk * 32 + lk * 8]);
  const u16* vt = Vt + (long)b * 1024 * 96;
  u16* ob = Q + qoff;
#pragma unroll
  for (int n = 0; n < 16; ++n) {
    int col = wave * 256 + n * 16 + lr;
    f32x4 o = {};
#pragma unroll
    for (int kk = 0; kk < 3; ++kk) {
      bf16x8 vq = *reinterpret_cast<const bf16x8*>(vt + (long)col * 96 + kk * 32 + lk * 8);
      o = __builtin_amdgcn_mfma_f32_16x16x32_bf16(pa[kk], vq, o, 0, 0, 0);
    }
#pragma unroll
    for (int j = 0; j < 4; ++j) {
      unsigned h = f2bf(o[j]);
      unsigned ph = h | (((unsigned)__shfl_xor((int)h, 1, 64)) << 16);
      unsigned p2 = (unsigned)__shfl_xor((int)ph, 2, 64);
      if ((lane & 3) == 0) {
        uint2 st; st.x = ph; st.y = p2;
        *reinterpret_cast<uint2*>(ob + (long)(lk * 4 + j) * 1024 + col) = st;
      }
    }
  }
}

extern "C" void kernel_launch(void* const* d_in, const int* in_sizes, int n_in,
                              void* d_out, int out_size, void* d_ws, size_t ws_size,
                              hipStream_t stream) {
  const float* x  = (const float*)d_in[0];
  const float* y  = (const float*)d_in[1];
  const float* Wq = (const float*)d_in[2];
  const float* bq = (const float*)d_in[3];
  const float* Wk = (const float*)d_in[4];
  const float* bk = (const float*)d_in[5];
  const float* Wv = (const float*)d_in[6];
  const float* bv = (const float*)d_in[7];
  const float* Wo = (const float*)d_in[8];
  const float* bo = (const float*)d_in[9];

  const int B = 16, Lq = 4096, D = 1024, Dc = 768, Lp = 80;
  const long Mq = (long)B * Lq;  // 65536

  char* p = (char*)d_ws;
  u16* Qb   = (u16*)p; p += (size_t)Mq * D * 2;       // Q, then attn out (in-place)
  u16* Wqt  = (u16*)p; p += (size_t)D * D * 2;
  u16* Wkvt = (u16*)p; p += (size_t)2 * D * Dc * 2;   // [2048][768]: Wk^T | Wv^T
  u16* Wot  = (u16*)p; p += (size_t)D * D * 2;
  u16* yp   = (u16*)p; p += (size_t)B * Lp * Dc * 2;  // [16][80][768], pad zeroed
  u16* KV   = (u16*)p; p += (size_t)B * Lp * 2 * D * 2; // [16][80][2048]
  u16* Vt   = (u16*)p; p += (size_t)B * D * 96 * 2;   // [16][1024][96]
  float* bkv = (float*)p; p += (size_t)2 * D * 4;     // [2048]
  u16* xb   = (u16*)d_out;  // scratch: x as bf16 lives in d_out until final GEMM

  (void)hipFuncSetAttribute(reinterpret_cast<const void*>(&gemm8<true>),
                            hipFuncAttributeMaxDynamicSharedMemorySize, 131072);
  (void)hipFuncSetAttribute(reinterpret_cast<const void*>(&gemm8<false>),
                            hipFuncAttributeMaxDynamicSharedMemorySize, 131072);

  // conversions
  cvt_f32_bf16<<<(int)(Mq * D / 1024), 256, 0, stream>>>(x, xb, Mq * D / 4);
  transpose_cvt<<<dim3(D / 32, D / 32), 256, 0, stream>>>(Wq, Wqt, D, D);
  transpose_cvt<<<dim3(D / 32, Dc / 32), 256, 0, stream>>>(Wk, Wkvt, Dc, D);
  transpose_cvt<<<dim3(D / 32, Dc / 32), 256, 0, stream>>>(Wv, Wkvt + (size_t)D * Dc, Dc, D);
  transpose_cvt<<<dim3(D / 32, D / 32), 256, 0, stream>>>(Wo, Wot, D, D);
  cvt_y_pad<<<(B * Lp * Dc / 4) / 256, 256, 0, stream>>>(y, yp);
  concat_bias<<<8, 256, 0, stream>>>(bk, bv, bkv);

  // fused K|V projection: [1280][768] @ [768][2048] -> [1280][2048]
  gemm8<true><<<(1280 / 256) * (2 * D / 256), 512, 131072, stream>>>(
      yp, Wkvt, bkv, KV, B * Lp, 2 * D, Dc);

  // V transpose for MFMA PV: KV cols 1024.. -> [16][1024][96]
  transpose_v<<<dim3(D / 32, 3, B), 256, 0, stream>>>(KV, Vt);

  // Q projection: [65536][1024] @ [1024][1024] -> [65536][1024] bf16
  gemm8<true><<<(int)(Mq / 256) * (D / 256), 512, 131072, stream>>>(xb, Wqt, bq, Qb, (int)Mq, D, D);

  // fused attention, writes back into Qb (16 q-rows per block)
  attn_fused<<<(int)(Mq / 16), 256, 0, stream>>>(Qb, KV, Vt);

  // output projection: [65536][1024] @ [1024][1024] -> d_out f32
  gemm8<false><<<(int)(Mq / 256) * (D / 256), 512, 131072, stream>>>(Qb, Wot, bo, d_out, (int)Mq, D, D);
}

// Round 14
// 568.808 us; speedup vs baseline: 1.2015x; 1.0210x over previous
//
#include <hip/hip_runtime.h>

typedef unsigned short u16;
typedef __bf16 bf16x8 __attribute__((ext_vector_type(8)));
typedef float f32x4 __attribute__((ext_vector_type(4)));

static __device__ __forceinline__ u16 f2bf(float f) {
  unsigned u = __builtin_bit_cast(unsigned, f);
  u = u + 0x7FFFu + ((u >> 16) & 1u);   // RNE
  return (u16)(u >> 16);
}
static __device__ __forceinline__ float bf2f(u16 h) {
  return __builtin_bit_cast(float, (unsigned)h << 16);
}

#define GLOAD_LDS16(g, l) __builtin_amdgcn_global_load_lds(              \
    (const __attribute__((address_space(1))) void*)(g),                  \
    (__attribute__((address_space(3))) void*)(l), 16, 0, 0)
#define BAR() asm volatile("s_barrier" ::: "memory")
#define VMCNT(n) asm volatile("s_waitcnt vmcnt(" #n ")" ::: "memory")
#define LGKM0() do { asm volatile("s_waitcnt lgkmcnt(0)" ::: "memory");   \
                     __builtin_amdgcn_sched_barrier(0); } while (0)

// ---------------- elementwise f32 -> bf16 (4 elems/thread) ----------------
__global__ __launch_bounds__(256) void cvt_f32_bf16(const float* __restrict__ in,
                                                    u16* __restrict__ out, long n4) {
  long i = (long)blockIdx.x * 256 + threadIdx.x;
  if (i >= n4) return;
  float4 v = reinterpret_cast<const float4*>(in)[i];
  ushort4 o;
  o.x = f2bf(v.x); o.y = f2bf(v.y); o.z = f2bf(v.z); o.w = f2bf(v.w);
  reinterpret_cast<ushort4*>(out)[i] = o;
}

// ------------- transpose + convert: W[K][N] f32 -> Wt[N][K] bf16 ----------
__global__ __launch_bounds__(256) void transpose_cvt(const float* __restrict__ W,
                                                     u16* __restrict__ Wt,
                                                     int K, int N) {
  __shared__ float tile[32][33];
  const int tx = threadIdx.x & 31, ty = threadIdx.x >> 5;  // ty: 0..7
  const int n0 = blockIdx.x * 32, k0 = blockIdx.y * 32;
#pragma unroll
  for (int i = 0; i < 4; ++i)
    tile[ty + i * 8][tx] = W[(long)(k0 + ty + i * 8) * N + n0 + tx];
  __syncthreads();
#pragma unroll
  for (int i = 0; i < 4; ++i) {
    int r = ty + i * 8;
    Wt[(long)(n0 + r) * K + k0 + tx] = f2bf(tile[tx][r]);
  }
}

// -------- y [16][77][768] f32 -> yp [16][80][768] bf16, pad rows = 0 -------
__global__ __launch_bounds__(256) void cvt_y_pad(const float* __restrict__ y,
                                                 u16* __restrict__ yp) {
  int idx = blockIdx.x * 256 + threadIdx.x;
  int e = idx * 4;  // element index into [16][80][768]
  int c = e % 768;
  int rb = e / 768;
  int r = rb % 80, b = rb / 80;
  ushort4 o;
  if (r < 77) {
    float4 v = *reinterpret_cast<const float4*>(y + ((long)(b * 77 + r) * 768 + c));
    o.x = f2bf(v.x); o.y = f2bf(v.y); o.z = f2bf(v.z); o.w = f2bf(v.w);
  } else {
    o.x = 0; o.y = 0; o.z = 0; o.w = 0;
  }
  *reinterpret_cast<ushort4*>(yp + e) = o;
}

// ---------------- bias concat: bkv = [bk | bv], 2048 f32 ------------------
__global__ __launch_bounds__(256) void concat_bias(const float* __restrict__ a,
                                                   const float* __restrict__ b,
                                                   float* __restrict__ o) {
  int i = blockIdx.x * 256 + threadIdx.x;
  o[i] = (i < 1024) ? a[i] : b[i - 1024];
}

// -- KV [16][80][2048] bf16 (V at col 1024) -> Vt [16][1024][96] (pad 0) ----
__global__ __launch_bounds__(256) void transpose_v(const u16* __restrict__ KV,
                                                   u16* __restrict__ Vt) {
  __shared__ u16 tile[32][34];
  const int tx = threadIdx.x & 31, ty = threadIdx.x >> 5;  // ty: 0..7
  const int b = blockIdx.z;
  const int k0 = blockIdx.y * 32;   // 0,32,64
  const int e0 = blockIdx.x * 32;
  const u16* src = KV + (long)b * 80 * 2048 + 1024;
#pragma unroll
  for (int i = 0; i < 4; ++i) {
    int k = k0 + ty + i * 8;
    tile[ty + i * 8][tx] = (k < 80) ? src[(long)k * 2048 + e0 + tx] : (u16)0;
  }
  __syncthreads();
  u16* dst = Vt + (long)b * 1024 * 96;
#pragma unroll
  for (int i = 0; i < 4; ++i) {
    int e = e0 + ty + i * 8;
    dst[(long)e * 96 + k0 + tx] = tile[tx][ty + i * 8];
  }
}

// --- pack K into fragment-major: Kf[b][kk=32][n=5][lane=64][8] bf16 --------
// Kf element (b,kk,n,lane,e) = K[b][n*16+(lane&15)][kk*32+(lane>>4)*8+e]
// (K = KV cols 0..1023). One wave per (b,kk,n); gather-read once, write 1KB.
__global__ __launch_bounds__(256) void pack_k(const u16* __restrict__ KV,
                                              u16* __restrict__ Kf) {
  const int lane = threadIdx.x & 63;
  const int w = blockIdx.x * 4 + (threadIdx.x >> 6);  // 0..2559
  const int b = w / 160, rem = w % 160;
  const int kk = rem / 5, n = rem % 5;
  const int lr = lane & 15, lk = lane >> 4;
  const u16* src = KV + (long)b * 80 * 2048 + (long)(n * 16 + lr) * 2048 + kk * 32 + lk * 8;
  *reinterpret_cast<ulong2*>(Kf + (long)w * 512 + lane * 8) =
      *reinterpret_cast<const ulong2*>(src);
}

// --- pack Vt into fragment-major: Vf[b][ct=64][kk=3][lane=64][8] bf16 ------
// Vf element (b,ct,kk,lane,e) = Vt[b][ct*16+(lane&15)][kk*32+(lane>>4)*8+e]
__global__ __launch_bounds__(256) void pack_v(const u16* __restrict__ Vt,
                                              u16* __restrict__ Vf) {
  const int lane = threadIdx.x & 63;
  const int w = blockIdx.x * 4 + (threadIdx.x >> 6);  // 0..3071
  const int b = w / 192, rem = w % 192;
  const int ct = rem / 3, kk = rem % 3;
  const int lr = lane & 15, lk = lane >> 4;
  const u16* src = Vt + (long)b * 1024 * 96 + (long)(ct * 16 + lr) * 96 + kk * 32 + lk * 8;
  *reinterpret_cast<ulong2*>(Vf + (long)w * 512 + lane * 8) =
      *reinterpret_cast<const ulong2*>(src);
}

// ============ 256x256 m201-style 8-phase bf16 GEMM, C = A @ Bt^T + bias ====
// (r13-proven: bf16 + f32 epilogues both via LDS transpose -> full-line
// stores; r7-proven K-loop with counted vmcnt(4), T1+T2.)
template <bool OUT_BF16>
__global__ __launch_bounds__(512, 2) void gemm8(const u16* __restrict__ A,
                                                const u16* __restrict__ Bt,
                                                const float* __restrict__ bias,
                                                void* __restrict__ Cv,
                                                int M, int N, int K) {
  extern __shared__ __align__(16) u16 lds[];
  const int tid = threadIdx.x;
  const int lane = tid & 63, wid = tid >> 6;
  const int lr = lane & 15, lk = lane >> 4;
  const int wr = wid >> 2, wc = wid & 3;

  // T1: chunked XCD swizzle (bijective when grid % 8 == 0)
  int flat = blockIdx.x;
  int nb = gridDim.x;
  int widx = flat;
  if ((nb & 7) == 0) {
    int per = nb >> 3;
    widx = (flat & 7) * per + (flat >> 3);
  }
  const int nbx = N >> 8;
  const long m0 = (long)(widx / nbx) * 256;
  const long n0 = (long)(widx % nbx) * 256;
  const int nt = K >> 6;

  f32x4 acc[8][4] = {};

  const long abase = m0 * (long)K;
  const long bbase = n0 * (long)K;
  const int srl = tid >> 3;
  const int scl = tid & 7;

#define STAGE_HALF(SRC, sbase, t_, half_, ldsbase)                           \
  do {                                                                       \
    long k0_ = (long)(t_) * 64;                                              \
    _Pragma("unroll")                                                        \
    for (int j_ = 0; j_ < 2; ++j_) {                                         \
      int row_ = (half_) * 128 + j_ * 64 + srl;                              \
      int cg_ = scl ^ (row_ & 7);                                            \
      GLOAD_LDS16(SRC + (sbase) + (long)row_ * K + k0_ + cg_ * 8,            \
                  lds + (ldsbase) + row_ * 64 + scl * 8);                    \
    }                                                                        \
  } while (0)

#define LDB_ALL(p)                                                           \
  _Pragma("unroll")                                                          \
  for (int n_ = 0; n_ < 4; ++n_)                                             \
    _Pragma("unroll")                                                        \
    for (int kk_ = 0; kk_ < 2; ++kk_) {                                      \
      int row_ = wc * 64 + n_ * 16 + lr;                                     \
      int ch_ = (kk_ * 4 + lk) ^ (lr & 7);                                   \
      bq[n_][kk_] = *reinterpret_cast<const bf16x8*>(                        \
          lds + 32768 + (p) * 16384 + row_ * 64 + ch_ * 8);                  \
    }

#define LDA_Q(p, q)                                                          \
  _Pragma("unroll")                                                          \
  for (int i_ = 0; i_ < 2; ++i_)                                             \
    _Pragma("unroll")                                                        \
    for (int kk_ = 0; kk_ < 2; ++kk_) {                                      \
      int row_ = wr * 128 + ((q) * 2 + i_) * 16 + lr;                        \
      int ch_ = (kk_ * 4 + lk) ^ (lr & 7);                                   \
      af[i_][kk_] = *reinterpret_cast<const bf16x8*>(                        \
          lds + (p) * 16384 + row_ * 64 + ch_ * 8);                          \
    }

// kk_ outermost: 8 independent MFMAs between dependent accumulator reuses
#define MFMA_Q(q)                                                            \
  __builtin_amdgcn_s_setprio(1);                                             \
  _Pragma("unroll")                                                          \
  for (int kk_ = 0; kk_ < 2; ++kk_)                                          \
    _Pragma("unroll")                                                        \
    for (int i_ = 0; i_ < 2; ++i_)                                           \
      _Pragma("unroll")                                                      \
      for (int n_ = 0; n_ < 4; ++n_)                                         \
        acc[(q) * 2 + i_][n_] = __builtin_amdgcn_mfma_f32_16x16x32_bf16(     \
            af[i_][kk_], bq[n_][kk_], acc[(q) * 2 + i_][n_], 0, 0, 0);       \
  __builtin_amdgcn_s_setprio(0);

  STAGE_HALF(A, abase, 0, 0, 0);
  STAGE_HALF(A, abase, 0, 1, 0);
  STAGE_HALF(Bt, bbase, 0, 0, 32768);
  STAGE_HALF(Bt, bbase, 0, 1, 32768);
  STAGE_HALF(Bt, bbase, 1, 0, 49152);
  STAGE_HALF(Bt, bbase, 1, 1, 49152);
  VMCNT(4);
  BAR();

  const int niter = nt >> 1;
  for (int tp = 0; tp < niter; ++tp) {
    const int T = tp << 1;
    const bool more = (T + 2 < nt);
    bf16x8 af[2][2], bq[4][2];

    // ---- tile T (parity 0) ----
    LDB_ALL(0); LDA_Q(0, 0);
    STAGE_HALF(A, abase, T + 1, 0, 16384);
    BAR(); LGKM0(); MFMA_Q(0); BAR();
    LDA_Q(0, 1);
    STAGE_HALF(A, abase, T + 1, 1, 16384);
    BAR(); LGKM0(); MFMA_Q(1); BAR();
    LDA_Q(0, 2);
    if (more) STAGE_HALF(Bt, bbase, T + 2, 0, 32768);
    BAR(); LGKM0(); MFMA_Q(2); BAR();
    LDA_Q(0, 3);
    if (more) { STAGE_HALF(Bt, bbase, T + 2, 1, 32768); VMCNT(4); }
    else VMCNT(0);
    BAR(); LGKM0(); MFMA_Q(3); BAR();

    // ---- tile T+1 (parity 1) ----
    LDB_ALL(1); LDA_Q(1, 0);
    if (more) STAGE_HALF(A, abase, T + 2, 0, 0);
    BAR(); LGKM0(); MFMA_Q(0); BAR();
    LDA_Q(1, 1);
    if (more) STAGE_HALF(A, abase, T + 2, 1, 0);
    BAR(); LGKM0(); MFMA_Q(1); BAR();
    LDA_Q(1, 2);
    if (more) STAGE_HALF(Bt, bbase, T + 3, 0, 49152);
    BAR(); LGKM0(); MFMA_Q(2); BAR();
    LDA_Q(1, 3);
    if (more) { STAGE_HALF(Bt, bbase, T + 3, 1, 49152); VMCNT(4); }
    BAR(); LGKM0(); MFMA_Q(3); BAR();
  }

  const long mrow = m0 + wr * 128;
  const long ncol = n0 + wc * 64;

  if (OUT_BF16) {
    // bf16 epilogue via LDS transpose: full 128B-line stores
    __syncthreads();
    u16* ep = lds + wid * (16 * 72);
    float bb[4];
#pragma unroll
    for (int n = 0; n < 4; ++n) bb[n] = bias[ncol + n * 16 + lr];
    const int rr = lane >> 4, cc = lane & 15;
#pragma unroll
    for (int m = 0; m < 8; ++m) {
#pragma unroll
      for (int n = 0; n < 4; ++n)
#pragma unroll
        for (int j = 0; j < 4; ++j)
          ep[(lk * 4 + j) * 72 + n * 16 + lr] = f2bf(acc[m][n][j] + bb[n]);
      asm volatile("s_waitcnt lgkmcnt(0)" ::: "memory");
#pragma unroll
      for (int s = 0; s < 4; ++s) {
        uint2 v = *reinterpret_cast<const uint2*>(ep + (s * 4 + rr) * 72 + cc * 4);
        *reinterpret_cast<uint2*>((u16*)Cv + (mrow + m * 16 + s * 4 + rr) * N +
                                  ncol + cc * 4) = v;
      }
      asm volatile("s_waitcnt lgkmcnt(0)" ::: "memory");
    }
  } else {
    // f32 epilogue via LDS transpose: 256B-contiguous f32x4 stores
    __syncthreads();
    float* ep = reinterpret_cast<float*>(lds) + wid * (16 * 68);
    float bb[4];
#pragma unroll
    for (int n = 0; n < 4; ++n) bb[n] = bias[ncol + n * 16 + lr];
    const int rr = lane >> 4, cc = lane & 15;
#pragma unroll
    for (int m = 0; m < 8; ++m) {
#pragma unroll
      for (int n = 0; n < 4; ++n)
#pragma unroll
        for (int j = 0; j < 4; ++j)
          ep[(lk * 4 + j) * 68 + n * 16 + lr] = acc[m][n][j] + bb[n];
      asm volatile("s_waitcnt lgkmcnt(0)" ::: "memory");
#pragma unroll
      for (int s = 0; s < 4; ++s) {
        f32x4 v = *reinterpret_cast<const f32x4*>(ep + (s * 4 + rr) * 68 + cc * 4);
        *reinterpret_cast<f32x4*>((float*)Cv + (mrow + m * 16 + s * 4 + rr) * N +
                                  ncol + cc * 4) = v;
      }
      asm volatile("s_waitcnt lgkmcnt(0)" ::: "memory");
    }
  }
#undef STAGE_HALF
#undef LDB_ALL
#undef LDA_Q
#undef MFMA_Q
}

// ------- fused attention: 16 q-rows per block; K/V from packed fragments ---
// Q [16*4096][1024] bf16 (overwritten), Kf [16][32][5][512] bf16 fragment-
// major, Vf [16][64][3][512] bf16 fragment-major (kv-pad zeroed via Vt).
__global__ __launch_bounds__(256) void attn_fused(u16* __restrict__ Q,
                                                  const u16* __restrict__ Kf,
                                                  const u16* __restrict__ Vf) {
  const int blk = blockIdx.x;
  const int b = blk >> 8;               // 256 blocks per batch (4096/16)
  const int q0 = (blk & 255) << 4;
  const long qoff = ((long)b * 4096 + q0) * 1024;
  const int tid = threadIdx.x;
  const int lane = tid & 63, wave = tid >> 6;
  const int lr = lane & 15, lk = lane >> 4;

  __shared__ float S4[4][16][80];
  __shared__ __align__(16) u16 P_lds[16][104];  // bf16 P, stride 104 breaks banks

  // Phase 1: scores via MFMA; wave w covers k-dim slice w*256 .. +255.
  // kf loads are fully coalesced 1KB fragment reads from Kf.
  f32x4 acc[5] = {};
  const u16* qb = Q + qoff;
  const u16* kfb = Kf + (long)b * 32 * 5 * 512;
#pragma unroll
  for (int t = 0; t < 8; ++t) {
    int kk = wave * 8 + t;
    bf16x8 qa = *reinterpret_cast<const bf16x8*>(qb + lr * 1024 + kk * 32 + lk * 8);
#pragma unroll
    for (int n = 0; n < 5; ++n) {
      bf16x8 kf = *reinterpret_cast<const bf16x8*>(kfb + ((long)kk * 5 + n) * 512 + lane * 8);
      acc[n] = __builtin_amdgcn_mfma_f32_16x16x32_bf16(qa, kf, acc[n], 0, 0, 0);
    }
  }
#pragma unroll
  for (int n = 0; n < 5; ++n)
#pragma unroll
    for (int j = 0; j < 4; ++j)
      S4[wave][lk * 4 + j][n * 16 + lr] = acc[n][j];
  __syncthreads();

  // Phase 2: cross-wave reduce + softmax -> P_lds (bf16, cols 80..95 zeroed)
  {
    const int r = tid >> 4, ci = tid & 15;
    const float scale = 0.088388347648318447f;  // 1/sqrt(128)
    float v[5];
    float mx = -3e38f;
#pragma unroll
    for (int i = 0; i < 5; ++i) {
      int c = ci + 16 * i;
      float s = (S4[0][r][c] + S4[1][r][c]) + (S4[2][r][c] + S4[3][r][c]);
      s *= scale;
      if (c >= 77) s = -3e38f;
      v[i] = s;
      mx = fmaxf(mx, s);
    }
#pragma unroll
    for (int off = 1; off < 16; off <<= 1) mx = fmaxf(mx, __shfl_xor(mx, off, 64));
    float sum = 0.f, e[5];
#pragma unroll
    for (int i = 0; i < 5; ++i) { e[i] = __expf(v[i] - mx); sum += e[i]; }
#pragma unroll
    for (int off = 1; off < 16; off <<= 1) sum += __shfl_xor(sum, off, 64);
    float inv = 1.f / sum;
#pragma unroll
    for (int i = 0; i < 5; ++i) P_lds[r][ci + 16 * i] = f2bf(e[i] * inv);
    P_lds[r][80 + ci] = 0;
  }
  __syncthreads();

  // Phase 3: PV via MFMA; vq loads are coalesced 1KB fragment reads from Vf.
  bf16x8 pa[3];
#pragma unroll
  for (int kk = 0; kk < 3; ++kk)
    pa[kk] = *reinterpret_cast<const bf16x8*>(&P_lds[lr][kk * 32 + lk * 8]);
  const u16* vfb = Vf + (long)b * 64 * 3 * 512;
  u16* ob = Q + qoff;
#pragma unroll
  for (int n = 0; n < 16; ++n) {
    int col = wave * 256 + n * 16 + lr;
    int ct = wave * 16 + n;
    f32x4 o = {};
#pragma unroll
    for (int kk = 0; kk < 3; ++kk) {
      bf16x8 vq = *reinterpret_cast<const bf16x8*>(vfb + ((long)ct * 3 + kk) * 512 + lane * 8);
      o = __builtin_amdgcn_mfma_f32_16x16x32_bf16(pa[kk], vq, o, 0, 0, 0);
    }
#pragma unroll
    for (int j = 0; j < 4; ++j) {
      unsigned h = f2bf(o[j]);
      unsigned ph = h | (((unsigned)__shfl_xor((int)h, 1, 64)) << 16);
      unsigned p2 = (unsigned)__shfl_xor((int)ph, 2, 64);
      if ((lane & 3) == 0) {
        uint2 st; st.x = ph; st.y = p2;
        *reinterpret_cast<uint2*>(ob + (long)(lk * 4 + j) * 1024 + col) = st;
      }
    }
  }
}

extern "C" void kernel_launch(void* const* d_in, const int* in_sizes, int n_in,
                              void* d_out, int out_size, void* d_ws, size_t ws_size,
                              hipStream_t stream) {
  const float* x  = (const float*)d_in[0];
  const float* y  = (const float*)d_in[1];
  const float* Wq = (const float*)d_in[2];
  const float* bq = (const float*)d_in[3];
  const float* Wk = (const float*)d_in[4];
  const float* bk = (const float*)d_in[5];
  const float* Wv = (const float*)d_in[6];
  const float* bv = (const float*)d_in[7];
  const float* Wo = (const float*)d_in[8];
  const float* bo = (const float*)d_in[9];

  const int B = 16, Lq = 4096, D = 1024, Dc = 768, Lp = 80;
  const long Mq = (long)B * Lq;  // 65536

  char* p = (char*)d_ws;
  u16* Qb   = (u16*)p; p += (size_t)Mq * D * 2;       // Q, then attn out (in-place)
  u16* Wqt  = (u16*)p; p += (size_t)D * D * 2;
  u16* Wkvt = (u16*)p; p += (size_t)2 * D * Dc * 2;   // [2048][768]: Wk^T | Wv^T
  u16* Wot  = (u16*)p; p += (size_t)D * D * 2;
  u16* yp   = (u16*)p; p += (size_t)B * Lp * Dc * 2;  // [16][80][768], pad zeroed
  u16* KV   = (u16*)p; p += (size_t)B * Lp * 2 * D * 2; // [16][80][2048]
  u16* Vt   = (u16*)p; p += (size_t)B * D * 96 * 2;   // [16][1024][96]
  float* bkv = (float*)p; p += (size_t)2 * D * 4;     // [2048]
  u16* Kf   = (u16*)p; p += (size_t)B * 32 * 5 * 512 * 2;  // 2.6 MB
  u16* Vf   = (u16*)p; p += (size_t)B * 64 * 3 * 512 * 2;  // 3.1 MB
  u16* xb   = (u16*)d_out;  // scratch: x as bf16 lives in d_out until final GEMM

  (void)hipFuncSetAttribute(reinterpret_cast<const void*>(&gemm8<true>),
                            hipFuncAttributeMaxDynamicSharedMemorySize, 131072);
  (void)hipFuncSetAttribute(reinterpret_cast<const void*>(&gemm8<false>),
                            hipFuncAttributeMaxDynamicSharedMemorySize, 131072);

  // conversions
  cvt_f32_bf16<<<(int)(Mq * D / 1024), 256, 0, stream>>>(x, xb, Mq * D / 4);
  transpose_cvt<<<dim3(D / 32, D / 32), 256, 0, stream>>>(Wq, Wqt, D, D);
  transpose_cvt<<<dim3(D / 32, Dc / 32), 256, 0, stream>>>(Wk, Wkvt, Dc, D);
  transpose_cvt<<<dim3(D / 32, Dc / 32), 256, 0, stream>>>(Wv, Wkvt + (size_t)D * Dc, Dc, D);
  transpose_cvt<<<dim3(D / 32, D / 32), 256, 0, stream>>>(Wo, Wot, D, D);
  cvt_y_pad<<<(B * Lp * Dc / 4) / 256, 256, 0, stream>>>(y, yp);
  concat_bias<<<8, 256, 0, stream>>>(bk, bv, bkv);

  // fused K|V projection: [1280][768] @ [768][2048] -> [1280][2048]
  gemm8<true><<<(1280 / 256) * (2 * D / 256), 512, 131072, stream>>>(
      yp, Wkvt, bkv, KV, B * Lp, 2 * D, Dc);

  // V transpose + fragment packs (one-time, ~6 MB total)
  transpose_v<<<dim3(D / 32, 3, B), 256, 0, stream>>>(KV, Vt);
  pack_k<<<(B * 32 * 5) / 4, 256, 0, stream>>>(KV, Kf);
  pack_v<<<(B * 64 * 3) / 4, 256, 0, stream>>>(Vt, Vf);

  // Q projection: [65536][1024] @ [1024][1024] -> [65536][1024] bf16
  gemm8<true><<<(int)(Mq / 256) * (D / 256), 512, 131072, stream>>>(xb, Wqt, bq, Qb, (int)Mq, D, D);

  // fused attention, writes back into Qb (16 q-rows per block)
  attn_fused<<<(int)(Mq / 16), 256, 0, stream>>>(Qb, Kf, Vf);

  // output projection: [65536][1024] @ [1024][1024] -> d_out f32
  gemm8<false><<<(int)(Mq / 256) * (D / 256), 512, 131072, stream>>>(Qb, Wot, bo, d_out, (int)Mq, D, D);
}

// Round 15
// 512.108 us; speedup vs baseline: 1.3345x; 1.1107x over previous
//
#include <hip/hip_runtime.h>

typedef unsigned short u16;
typedef __bf16 bf16x8 __attribute__((ext_vector_type(8)));
typedef float f32x4 __attribute__((ext_vector_type(4)));

static __device__ __forceinline__ u16 f2bf(float f) {
  unsigned u = __builtin_bit_cast(unsigned, f);
  u = u + 0x7FFFu + ((u >> 16) & 1u);   // RNE
  return (u16)(u >> 16);
}
static __device__ __forceinline__ float bf2f(u16 h) {
  return __builtin_bit_cast(float, (unsigned)h << 16);
}

#define GLOAD_LDS16(g, l) __builtin_amdgcn_global_load_lds(              \
    (const __attribute__((address_space(1))) void*)(g),                  \
    (__attribute__((address_space(3))) void*)(l), 16, 0, 0)
#define BAR() asm volatile("s_barrier" ::: "memory")
#define VMCNT(n) asm volatile("s_waitcnt vmcnt(" #n ")" ::: "memory")
#define LGKM0() do { asm volatile("s_waitcnt lgkmcnt(0)" ::: "memory");   \
                     __builtin_amdgcn_sched_barrier(0); } while (0)

// ---------------- elementwise f32 -> bf16 (4 elems/thread) ----------------
__global__ __launch_bounds__(256) void cvt_f32_bf16(const float* __restrict__ in,
                                                    u16* __restrict__ out, long n4) {
  long i = (long)blockIdx.x * 256 + threadIdx.x;
  if (i >= n4) return;
  float4 v = reinterpret_cast<const float4*>(in)[i];
  ushort4 o;
  o.x = f2bf(v.x); o.y = f2bf(v.y); o.z = f2bf(v.z); o.w = f2bf(v.w);
  reinterpret_cast<ushort4*>(out)[i] = o;
}

// ------------- transpose + convert: W[K][N] f32 -> Wt[N][K] bf16 ----------
__global__ __launch_bounds__(256) void transpose_cvt(const float* __restrict__ W,
                                                     u16* __restrict__ Wt,
                                                     int K, int N) {
  __shared__ float tile[32][33];
  const int tx = threadIdx.x & 31, ty = threadIdx.x >> 5;  // ty: 0..7
  const int n0 = blockIdx.x * 32, k0 = blockIdx.y * 32;
#pragma unroll
  for (int i = 0; i < 4; ++i)
    tile[ty + i * 8][tx] = W[(long)(k0 + ty + i * 8) * N + n0 + tx];
  __syncthreads();
#pragma unroll
  for (int i = 0; i < 4; ++i) {
    int r = ty + i * 8;
    Wt[(long)(n0 + r) * K + k0 + tx] = f2bf(tile[tx][r]);
  }
}

// -------- y [16][77][768] f32 -> yp [16][80][768] bf16, pad rows = 0 -------
__global__ __launch_bounds__(256) void cvt_y_pad(const float* __restrict__ y,
                                                 u16* __restrict__ yp) {
  int idx = blockIdx.x * 256 + threadIdx.x;
  int e = idx * 4;  // element index into [16][80][768]
  int c = e % 768;
  int rb = e / 768;
  int r = rb % 80, b = rb / 80;
  ushort4 o;
  if (r < 77) {
    float4 v = *reinterpret_cast<const float4*>(y + ((long)(b * 77 + r) * 768 + c));
    o.x = f2bf(v.x); o.y = f2bf(v.y); o.z = f2bf(v.z); o.w = f2bf(v.w);
  } else {
    o.x = 0; o.y = 0; o.z = 0; o.w = 0;
  }
  *reinterpret_cast<ushort4*>(yp + e) = o;
}

// ---------------- bias concat: bkv = [bk | bv], 2048 f32 ------------------
__global__ __launch_bounds__(256) void concat_bias(const float* __restrict__ a,
                                                   const float* __restrict__ b,
                                                   float* __restrict__ o) {
  int i = blockIdx.x * 256 + threadIdx.x;
  o[i] = (i < 1024) ? a[i] : b[i - 1024];
}

// -- KV [16][80][2048] bf16 (V at col 1024) -> Vt [16][1024][96] (pad 0) ----
__global__ __launch_bounds__(256) void transpose_v(const u16* __restrict__ KV,
                                                   u16* __restrict__ Vt) {
  __shared__ u16 tile[32][34];
  const int tx = threadIdx.x & 31, ty = threadIdx.x >> 5;  // ty: 0..7
  const int b = blockIdx.z;
  const int k0 = blockIdx.y * 32;   // 0,32,64
  const int e0 = blockIdx.x * 32;
  const u16* src = KV + (long)b * 80 * 2048 + 1024;
#pragma unroll
  for (int i = 0; i < 4; ++i) {
    int k = k0 + ty + i * 8;
    tile[ty + i * 8][tx] = (k < 80) ? src[(long)k * 2048 + e0 + tx] : (u16)0;
  }
  __syncthreads();
  u16* dst = Vt + (long)b * 1024 * 96;
#pragma unroll
  for (int i = 0; i < 4; ++i) {
    int e = e0 + ty + i * 8;
    dst[(long)e * 96 + k0 + tx] = tile[tx][ty + i * 8];
  }
}

// --- pack K into fragment-major: Kf[b][kk=32][n=5][lane=64][8] bf16 --------
__global__ __launch_bounds__(256) void pack_k(const u16* __restrict__ KV,
                                              u16* __restrict__ Kf) {
  const int lane = threadIdx.x & 63;
  const int w = blockIdx.x * 4 + (threadIdx.x >> 6);  // 0..2559
  const int b = w / 160, rem = w % 160;
  const int kk = rem / 5, n = rem % 5;
  const int lr = lane & 15, lk = lane >> 4;
  const u16* src = KV + (long)b * 80 * 2048 + (long)(n * 16 + lr) * 2048 + kk * 32 + lk * 8;
  *reinterpret_cast<ulong2*>(Kf + (long)w * 512 + lane * 8) =
      *reinterpret_cast<const ulong2*>(src);
}

// --- pack Vt into fragment-major: Vf[b][ct=64][kk=3][lane=64][8] bf16 ------
__global__ __launch_bounds__(256) void pack_v(const u16* __restrict__ Vt,
                                              u16* __restrict__ Vf) {
  const int lane = threadIdx.x & 63;
  const int w = blockIdx.x * 4 + (threadIdx.x >> 6);  // 0..3071
  const int b = w / 192, rem = w % 192;
  const int ct = rem / 3, kk = rem % 3;
  const int lr = lane & 15, lk = lane >> 4;
  const u16* src = Vt + (long)b * 1024 * 96 + (long)(ct * 16 + lr) * 96 + kk * 32 + lk * 8;
  *reinterpret_cast<ulong2*>(Vf + (long)w * 512 + lane * 8) =
      *reinterpret_cast<const ulong2*>(src);
}

// ============ 256x256 m201-style 8-phase bf16 GEMM, C = A @ Bt^T + bias ====
// OUT_MODE: 0 = f32 row-major, 1 = bf16 row-major, 2 = bf16 fragment-major
// (Qf[rt][kkg][lane][8], rt = row/16, kkg = col/32 — MFMA A-operand layout).
// All epilogues via per-wave LDS transpose -> full-line coalesced stores.
template <int OUT_MODE>
__global__ __launch_bounds__(512, 2) void gemm8(const u16* __restrict__ A,
                                                const u16* __restrict__ Bt,
                                                const float* __restrict__ bias,
                                                void* __restrict__ Cv,
                                                int M, int N, int K) {
  extern __shared__ __align__(16) u16 lds[];
  const int tid = threadIdx.x;
  const int lane = tid & 63, wid = tid >> 6;
  const int lr = lane & 15, lk = lane >> 4;
  const int wr = wid >> 2, wc = wid & 3;

  // T1: chunked XCD swizzle (bijective when grid % 8 == 0)
  int flat = blockIdx.x;
  int nb = gridDim.x;
  int widx = flat;
  if ((nb & 7) == 0) {
    int per = nb >> 3;
    widx = (flat & 7) * per + (flat >> 3);
  }
  const int nbx = N >> 8;
  const long m0 = (long)(widx / nbx) * 256;
  const long n0 = (long)(widx % nbx) * 256;
  const int nt = K >> 6;

  f32x4 acc[8][4] = {};

  const long abase = m0 * (long)K;
  const long bbase = n0 * (long)K;
  const int srl = tid >> 3;
  const int scl = tid & 7;

#define STAGE_HALF(SRC, sbase, t_, half_, ldsbase)                           \
  do {                                                                       \
    long k0_ = (long)(t_) * 64;                                              \
    _Pragma("unroll")                                                        \
    for (int j_ = 0; j_ < 2; ++j_) {                                         \
      int row_ = (half_) * 128 + j_ * 64 + srl;                              \
      int cg_ = scl ^ (row_ & 7);                                            \
      GLOAD_LDS16(SRC + (sbase) + (long)row_ * K + k0_ + cg_ * 8,            \
                  lds + (ldsbase) + row_ * 64 + scl * 8);                    \
    }                                                                        \
  } while (0)

#define LDB_ALL(p)                                                           \
  _Pragma("unroll")                                                          \
  for (int n_ = 0; n_ < 4; ++n_)                                             \
    _Pragma("unroll")                                                        \
    for (int kk_ = 0; kk_ < 2; ++kk_) {                                      \
      int row_ = wc * 64 + n_ * 16 + lr;                                     \
      int ch_ = (kk_ * 4 + lk) ^ (lr & 7);                                   \
      bq[n_][kk_] = *reinterpret_cast<const bf16x8*>(                        \
          lds + 32768 + (p) * 16384 + row_ * 64 + ch_ * 8);                  \
    }

#define LDA_Q(p, q)                                                          \
  _Pragma("unroll")                                                          \
  for (int i_ = 0; i_ < 2; ++i_)                                             \
    _Pragma("unroll")                                                        \
    for (int kk_ = 0; kk_ < 2; ++kk_) {                                      \
      int row_ = wr * 128 + ((q) * 2 + i_) * 16 + lr;                        \
      int ch_ = (kk_ * 4 + lk) ^ (lr & 7);                                   \
      af[i_][kk_] = *reinterpret_cast<const bf16x8*>(                        \
          lds + (p) * 16384 + row_ * 64 + ch_ * 8);                          \
    }

// kk_ outermost: 8 independent MFMAs between dependent accumulator reuses
#define MFMA_Q(q)                                                            \
  __builtin_amdgcn_s_setprio(1);                                             \
  _Pragma("unroll")                                                          \
  for (int kk_ = 0; kk_ < 2; ++kk_)                                          \
    _Pragma("unroll")                                                        \
    for (int i_ = 0; i_ < 2; ++i_)                                           \
      _Pragma("unroll")                                                      \
      for (int n_ = 0; n_ < 4; ++n_)                                         \
        acc[(q) * 2 + i_][n_] = __builtin_amdgcn_mfma_f32_16x16x32_bf16(     \
            af[i_][kk_], bq[n_][kk_], acc[(q) * 2 + i_][n_], 0, 0, 0);       \
  __builtin_amdgcn_s_setprio(0);

  STAGE_HALF(A, abase, 0, 0, 0);
  STAGE_HALF(A, abase, 0, 1, 0);
  STAGE_HALF(Bt, bbase, 0, 0, 32768);
  STAGE_HALF(Bt, bbase, 0, 1, 32768);
  STAGE_HALF(Bt, bbase, 1, 0, 49152);
  STAGE_HALF(Bt, bbase, 1, 1, 49152);
  VMCNT(4);
  BAR();

  const int niter = nt >> 1;
  for (int tp = 0; tp < niter; ++tp) {
    const int T = tp << 1;
    const bool more = (T + 2 < nt);
    bf16x8 af[2][2], bq[4][2];

    // ---- tile T (parity 0) ----
    LDB_ALL(0); LDA_Q(0, 0);
    STAGE_HALF(A, abase, T + 1, 0, 16384);
    BAR(); LGKM0(); MFMA_Q(0); BAR();
    LDA_Q(0, 1);
    STAGE_HALF(A, abase, T + 1, 1, 16384);
    BAR(); LGKM0(); MFMA_Q(1); BAR();
    LDA_Q(0, 2);
    if (more) STAGE_HALF(Bt, bbase, T + 2, 0, 32768);
    BAR(); LGKM0(); MFMA_Q(2); BAR();
    LDA_Q(0, 3);
    if (more) { STAGE_HALF(Bt, bbase, T + 2, 1, 32768); VMCNT(4); }
    else VMCNT(0);
    BAR(); LGKM0(); MFMA_Q(3); BAR();

    // ---- tile T+1 (parity 1) ----
    LDB_ALL(1); LDA_Q(1, 0);
    if (more) STAGE_HALF(A, abase, T + 2, 0, 0);
    BAR(); LGKM0(); MFMA_Q(0); BAR();
    LDA_Q(1, 1);
    if (more) STAGE_HALF(A, abase, T + 2, 1, 0);
    BAR(); LGKM0(); MFMA_Q(1); BAR();
    LDA_Q(1, 2);
    if (more) STAGE_HALF(Bt, bbase, T + 3, 0, 49152);
    BAR(); LGKM0(); MFMA_Q(2); BAR();
    LDA_Q(1, 3);
    if (more) { STAGE_HALF(Bt, bbase, T + 3, 1, 49152); VMCNT(4); }
    BAR(); LGKM0(); MFMA_Q(3); BAR();
  }

  const long mrow = m0 + wr * 128;
  const long ncol = n0 + wc * 64;

  if (OUT_MODE == 1) {
    // bf16 row-major via LDS transpose: full 128B-line stores
    __syncthreads();
    u16* ep = lds + wid * (16 * 72);
    float bb[4];
#pragma unroll
    for (int n = 0; n < 4; ++n) bb[n] = bias[ncol + n * 16 + lr];
    const int rr = lane >> 4, cc = lane & 15;
#pragma unroll
    for (int m = 0; m < 8; ++m) {
#pragma unroll
      for (int n = 0; n < 4; ++n)
#pragma unroll
        for (int j = 0; j < 4; ++j)
          ep[(lk * 4 + j) * 72 + n * 16 + lr] = f2bf(acc[m][n][j] + bb[n]);
      asm volatile("s_waitcnt lgkmcnt(0)" ::: "memory");
#pragma unroll
      for (int s = 0; s < 4; ++s) {
        uint2 v = *reinterpret_cast<const uint2*>(ep + (s * 4 + rr) * 72 + cc * 4);
        *reinterpret_cast<uint2*>((u16*)Cv + (mrow + m * 16 + s * 4 + rr) * N +
                                  ncol + cc * 4) = v;
      }
      asm volatile("s_waitcnt lgkmcnt(0)" ::: "memory");
    }
  } else if (OUT_MODE == 2) {
    // bf16 fragment-major: Cf[rt][kkg][lane][8]; 1KB coalesced stores.
    __syncthreads();
    u16* ep = lds + wid * (16 * 72);
    float bb[4];
#pragma unroll
    for (int n = 0; n < 4; ++n) bb[n] = bias[ncol + n * 16 + lr];
    const long rt0 = (m0 >> 4) + wr * 8;
    const long kk0 = (n0 >> 5) + wc * 2;
#pragma unroll
    for (int m = 0; m < 8; ++m) {
#pragma unroll
      for (int n = 0; n < 4; ++n)
#pragma unroll
        for (int j = 0; j < 4; ++j)
          ep[(lk * 4 + j) * 72 + n * 16 + lr] = f2bf(acc[m][n][j] + bb[n]);
      asm volatile("s_waitcnt lgkmcnt(0)" ::: "memory");
#pragma unroll
      for (int kkl = 0; kkl < 2; ++kkl) {
        ulong2 v = *reinterpret_cast<const ulong2*>(
            ep + (lane & 15) * 72 + kkl * 32 + (lane >> 4) * 8);
        *reinterpret_cast<ulong2*>((u16*)Cv +
            (((rt0 + m) * 32 + kk0 + kkl) * 64 + lane) * 8) = v;
      }
      asm volatile("s_waitcnt lgkmcnt(0)" ::: "memory");
    }
  } else {
    // f32 row-major via LDS transpose: 256B-contiguous f32x4 stores
    __syncthreads();
    float* ep = reinterpret_cast<float*>(lds) + wid * (16 * 68);
    float bb[4];
#pragma unroll
    for (int n = 0; n < 4; ++n) bb[n] = bias[ncol + n * 16 + lr];
    const int rr = lane >> 4, cc = lane & 15;
#pragma unroll
    for (int m = 0; m < 8; ++m) {
#pragma unroll
      for (int n = 0; n < 4; ++n)
#pragma unroll
        for (int j = 0; j < 4; ++j)
          ep[(lk * 4 + j) * 68 + n * 16 + lr] = acc[m][n][j] + bb[n];
      asm volatile("s_waitcnt lgkmcnt(0)" ::: "memory");
#pragma unroll
      for (int s = 0; s < 4; ++s) {
        f32x4 v = *reinterpret_cast<const f32x4*>(ep + (s * 4 + rr) * 68 + cc * 4);
        *reinterpret_cast<f32x4*>((float*)Cv + (mrow + m * 16 + s * 4 + rr) * N +
                                  ncol + cc * 4) = v;
      }
      asm volatile("s_waitcnt lgkmcnt(0)" ::: "memory");
    }
  }
#undef STAGE_HALF
#undef LDB_ALL
#undef LDA_Q
#undef MFMA_Q
}

// ------- fused attention: 16 q-rows per block; all operands fragment-major -
// Q: Qf[rt=4096][kk=32][lane][8] bf16 (rt == blockIdx.x); OVERWRITTEN with
// row-major O in the same 32KB region (safe: block-local).
// Kf [16][32][5][512], Vf [16][64][3][512] fragment-major.
__global__ __launch_bounds__(256) void attn_fused(u16* __restrict__ Q,
                                                  const u16* __restrict__ Kf,
                                                  const u16* __restrict__ Vf) {
  const int blk = blockIdx.x;
  const int b = blk >> 8;               // 256 blocks per batch (4096/16)
  const int tid = threadIdx.x;
  const int lane = tid & 63, wave = tid >> 6;
  const int lr = lane & 15, lk = lane >> 4;

  // smem serves as S4[4][16][80] f32 (20.5KB) in phases 1-2, then as the
  // per-wave O transpose tile [4][16][264] u16 (33.8KB) in phase 3.
  __shared__ __align__(16) u16 smem[4 * 16 * 264];
  __shared__ __align__(16) u16 P_lds[16][104];
  float* S4 = reinterpret_cast<float*>(smem);

  // Phase 1: scores via MFMA; qa/kf both fully-coalesced 1KB fragment loads.
  f32x4 acc[5] = {};
  const u16* qfb = Q + (long)blk * 16384;
  const u16* kfb = Kf + (long)b * 32 * 5 * 512;
#pragma unroll
  for (int t = 0; t < 8; ++t) {
    int kk = wave * 8 + t;
    bf16x8 qa = *reinterpret_cast<const bf16x8*>(qfb + ((long)kk * 64 + lane) * 8);
#pragma unroll
    for (int n = 0; n < 5; ++n) {
      bf16x8 kf = *reinterpret_cast<const bf16x8*>(kfb + ((long)kk * 5 + n) * 512 + lane * 8);
      acc[n] = __builtin_amdgcn_mfma_f32_16x16x32_bf16(qa, kf, acc[n], 0, 0, 0);
    }
  }
#pragma unroll
  for (int n = 0; n < 5; ++n)
#pragma unroll
    for (int j = 0; j < 4; ++j)
      S4[(wave * 16 + lk * 4 + j) * 80 + n * 16 + lr] = acc[n][j];
  __syncthreads();

  // Phase 2: cross-wave reduce + softmax -> P_lds (bf16, cols 80..95 zeroed)
  {
    const int r = tid >> 4, ci = tid & 15;
    const float scale = 0.088388347648318447f;  // 1/sqrt(128)
    float v[5];
    float mx = -3e38f;
#pragma unroll
    for (int i = 0; i < 5; ++i) {
      int c = ci + 16 * i;
      float s = (S4[r * 80 + c] + S4[(16 + r) * 80 + c]) +
                (S4[(32 + r) * 80 + c] + S4[(48 + r) * 80 + c]);
      s *= scale;
      if (c >= 77) s = -3e38f;
      v[i] = s;
      mx = fmaxf(mx, s);
    }
#pragma unroll
    for (int off = 1; off < 16; off <<= 1) mx = fmaxf(mx, __shfl_xor(mx, off, 64));
    float sum = 0.f, e[5];
#pragma unroll
    for (int i = 0; i < 5; ++i) { e[i] = __expf(v[i] - mx); sum += e[i]; }
#pragma unroll
    for (int off = 1; off < 16; off <<= 1) sum += __shfl_xor(sum, off, 64);
    float inv = 1.f / sum;
#pragma unroll
    for (int i = 0; i < 5; ++i) P_lds[r][ci + 16 * i] = f2bf(e[i] * inv);
    P_lds[r][80 + ci] = 0;
  }
  __syncthreads();   // S4 dead after this point; smem becomes the O tile

  // Phase 3: PV via MFMA; o -> per-wave LDS tile (stride 264 = 2-way alias).
  bf16x8 pa[3];
#pragma unroll
  for (int kk = 0; kk < 3; ++kk)
    pa[kk] = *reinterpret_cast<const bf16x8*>(&P_lds[lr][kk * 32 + lk * 8]);
  const u16* vfb = Vf + (long)b * 64 * 3 * 512;
  u16* otile = smem + wave * (16 * 264);
#pragma unroll
  for (int n = 0; n < 16; ++n) {
    int ct = wave * 16 + n;
    f32x4 o = {};
#pragma unroll
    for (int kk = 0; kk < 3; ++kk) {
      bf16x8 vq = *reinterpret_cast<const bf16x8*>(vfb + ((long)ct * 3 + kk) * 512 + lane * 8);
      o = __builtin_amdgcn_mfma_f32_16x16x32_bf16(pa[kk], vq, o, 0, 0, 0);
    }
#pragma unroll
    for (int j = 0; j < 4; ++j)
      otile[(lk * 4 + j) * 264 + n * 16 + lr] = f2bf(o[j]);
  }
  __syncthreads();

  // Bulk store: row-major O over the block's own Qf region (full lines).
  u16* ob = Q + (long)blk * 16384;
#pragma unroll
  for (int rnd = 0; rnd < 8; ++rnd) {
    int off = (rnd * 256 + tid) * 8;       // u16 offset in [0, 16384)
    int row = off >> 10, col = off & 1023;
    int ws = col >> 8, cl = col & 255;
    ulong2 v = *reinterpret_cast<const ulong2*>(smem + ws * (16 * 264) + row * 264 + cl);
    *reinterpret_cast<ulong2*>(ob + off) = v;
  }
}

extern "C" void kernel_launch(void* const* d_in, const int* in_sizes, int n_in,
                              void* d_out, int out_size, void* d_ws, size_t ws_size,
                              hipStream_t stream) {
  const float* x  = (const float*)d_in[0];
  const float* y  = (const float*)d_in[1];
  const float* Wq = (const float*)d_in[2];
  const float* bq = (const float*)d_in[3];
  const float* Wk = (const float*)d_in[4];
  const float* bk = (const float*)d_in[5];
  const float* Wv = (const float*)d_in[6];
  const float* bv = (const float*)d_in[7];
  const float* Wo = (const float*)d_in[8];
  const float* bo = (const float*)d_in[9];

  const int B = 16, Lq = 4096, D = 1024, Dc = 768, Lp = 80;
  const long Mq = (long)B * Lq;  // 65536

  char* p = (char*)d_ws;
  u16* Qb   = (u16*)p; p += (size_t)Mq * D * 2;       // Qf fragment-major, then O row-major
  u16* Wqt  = (u16*)p; p += (size_t)D * D * 2;
  u16* Wkvt = (u16*)p; p += (size_t)2 * D * Dc * 2;   // [2048][768]: Wk^T | Wv^T
  u16* Wot  = (u16*)p; p += (size_t)D * D * 2;
  u16* yp   = (u16*)p; p += (size_t)B * Lp * Dc * 2;  // [16][80][768], pad zeroed
  u16* KV   = (u16*)p; p += (size_t)B * Lp * 2 * D * 2; // [16][80][2048]
  u16* Vt   = (u16*)p; p += (size_t)B * D * 96 * 2;   // [16][1024][96]
  float* bkv = (float*)p; p += (size_t)2 * D * 4;     // [2048]
  u16* Kf   = (u16*)p; p += (size_t)B * 32 * 5 * 512 * 2;  // 2.6 MB
  u16* Vf   = (u16*)p; p += (size_t)B * 64 * 3 * 512 * 2;  // 3.1 MB
  u16* xb   = (u16*)d_out;  // scratch: x as bf16 lives in d_out until final GEMM

  (void)hipFuncSetAttribute(reinterpret_cast<const void*>(&gemm8<0>),
                            hipFuncAttributeMaxDynamicSharedMemorySize, 131072);
  (void)hipFuncSetAttribute(reinterpret_cast<const void*>(&gemm8<1>),
                            hipFuncAttributeMaxDynamicSharedMemorySize, 131072);
  (void)hipFuncSetAttribute(reinterpret_cast<const void*>(&gemm8<2>),
                            hipFuncAttributeMaxDynamicSharedMemorySize, 131072);

  // conversions
  cvt_f32_bf16<<<(int)(Mq * D / 1024), 256, 0, stream>>>(x, xb, Mq * D / 4);
  transpose_cvt<<<dim3(D / 32, D / 32), 256, 0, stream>>>(Wq, Wqt, D, D);
  transpose_cvt<<<dim3(D / 32, Dc / 32), 256, 0, stream>>>(Wk, Wkvt, Dc, D);
  transpose_cvt<<<dim3(D / 32, Dc / 32), 256, 0, stream>>>(Wv, Wkvt + (size_t)D * Dc, Dc, D);
  transpose_cvt<<<dim3(D / 32, D / 32), 256, 0, stream>>>(Wo, Wot, D, D);
  cvt_y_pad<<<(B * Lp * Dc / 4) / 256, 256, 0, stream>>>(y, yp);
  concat_bias<<<8, 256, 0, stream>>>(bk, bv, bkv);

  // fused K|V projection: [1280][768] @ [768][2048] -> [1280][2048]
  gemm8<1><<<(1280 / 256) * (2 * D / 256), 512, 131072, stream>>>(
      yp, Wkvt, bkv, KV, B * Lp, 2 * D, Dc);

  // V transpose + fragment packs (one-time, ~6 MB total)
  transpose_v<<<dim3(D / 32, 3, B), 256, 0, stream>>>(KV, Vt);
  pack_k<<<(B * 32 * 5) / 4, 256, 0, stream>>>(KV, Kf);
  pack_v<<<(B * 64 * 3) / 4, 256, 0, stream>>>(Vt, Vf);

  // Q projection -> fragment-major Qf (attn A-operand layout)
  gemm8<2><<<(int)(Mq / 256) * (D / 256), 512, 131072, stream>>>(
      xb, Wqt, bq, Qb, (int)Mq, D, D);

  // fused attention: reads Qf, writes row-major O in place
  attn_fused<<<(int)(Mq / 16), 256, 0, stream>>>(Qb, Kf, Vf);

  // output projection: [65536][1024] @ [1024][1024] -> d_out f32
  gemm8<0><<<(int)(Mq / 256) * (D / 256), 512, 131072, stream>>>(
      Qb, Wot, bo, d_out, (int)Mq, D, D);
}

// Round 16
// 372.182 us; speedup vs baseline: 1.8362x; 1.3760x over previous
//
#include <hip/hip_runtime.h>

typedef unsigned short u16;
typedef __bf16 bf16x8 __attribute__((ext_vector_type(8)));
typedef float f32x4 __attribute__((ext_vector_type(4)));

static __device__ __forceinline__ u16 f2bf(float f) {
  unsigned u = __builtin_bit_cast(unsigned, f);
  u = u + 0x7FFFu + ((u >> 16) & 1u);   // RNE
  return (u16)(u >> 16);
}
static __device__ __forceinline__ float bf2f(u16 h) {
  return __builtin_bit_cast(float, (unsigned)h << 16);
}

#define GLOAD_LDS16(g, l) __builtin_amdgcn_global_load_lds(              \
    (const __attribute__((address_space(1))) void*)(g),                  \
    (__attribute__((address_space(3))) void*)(l), 16, 0, 0)
#define BAR() asm volatile("s_barrier" ::: "memory")
#define VMCNT(n) asm volatile("s_waitcnt vmcnt(" #n ")" ::: "memory")
#define LGKM0() do { asm volatile("s_waitcnt lgkmcnt(0)" ::: "memory");   \
                     __builtin_amdgcn_sched_barrier(0); } while (0)

// ---------------- elementwise f32 -> bf16 (4 elems/thread) ----------------
__global__ __launch_bounds__(256) void cvt_f32_bf16(const float* __restrict__ in,
                                                    u16* __restrict__ out, long n4) {
  long i = (long)blockIdx.x * 256 + threadIdx.x;
  if (i >= n4) return;
  float4 v = reinterpret_cast<const float4*>(in)[i];
  ushort4 o;
  o.x = f2bf(v.x); o.y = f2bf(v.y); o.z = f2bf(v.z); o.w = f2bf(v.w);
  reinterpret_cast<ushort4*>(out)[i] = o;
}

// --- x [65536][1024] f32 -> xf fragment-major [rt=4096][kk=32][lane][8] ----
// xf(rt,kk,lane,e) = x[rt*16 + (lane&15)][kk*32 + (lane>>4)*8 + e] (bf16)
__global__ __launch_bounds__(256) void cvt_xf(const float* __restrict__ x,
                                              u16* __restrict__ xf) {
  __shared__ u16 tile[16][1032];
  const int tid = threadIdx.x;
  const long blk = blockIdx.x;           // 4096 blocks x 16 rows
  const int row = tid >> 4, cseg = tid & 15;
  const float* src = x + (blk * 16 + row) * 1024 + cseg * 64;
#pragma unroll
  for (int i = 0; i < 16; ++i) {
    f32x4 v = *reinterpret_cast<const f32x4*>(src + i * 4);
    ushort4 o;
    o.x = f2bf(v[0]); o.y = f2bf(v[1]); o.z = f2bf(v[2]); o.w = f2bf(v[3]);
    *reinterpret_cast<ushort4*>(&tile[row][cseg * 64 + i * 4]) = o;
  }
  __syncthreads();
  const int lane = tid & 63, wave = tid >> 6;
  const int lr = lane & 15, lk = lane >> 4;
#pragma unroll
  for (int f = 0; f < 8; ++f) {
    int kk = wave * 8 + f;
    ulong2 v = *reinterpret_cast<const ulong2*>(&tile[lr][kk * 32 + lk * 8]);
    *reinterpret_cast<ulong2*>(xf + blk * 16384 + (long)kk * 512 + lane * 8) = v;
  }
}

// ------------- transpose + convert: W[K][N] f32 -> Wt[N][K] bf16 ----------
__global__ __launch_bounds__(256) void transpose_cvt(const float* __restrict__ W,
                                                     u16* __restrict__ Wt,
                                                     int K, int N) {
  __shared__ float tile[32][33];
  const int tx = threadIdx.x & 31, ty = threadIdx.x >> 5;
  const int n0 = blockIdx.x * 32, k0 = blockIdx.y * 32;
#pragma unroll
  for (int i = 0; i < 4; ++i)
    tile[ty + i * 8][tx] = W[(long)(k0 + ty + i * 8) * N + n0 + tx];
  __syncthreads();
#pragma unroll
  for (int i = 0; i < 4; ++i) {
    int r = ty + i * 8;
    Wt[(long)(n0 + r) * K + k0 + tx] = f2bf(tile[tx][r]);
  }
}

// -------- y [16][77][768] f32 -> yp [16][80][768] bf16, pad rows = 0 -------
__global__ __launch_bounds__(256) void cvt_y_pad(const float* __restrict__ y,
                                                 u16* __restrict__ yp) {
  int idx = blockIdx.x * 256 + threadIdx.x;
  int e = idx * 4;
  int c = e % 768;
  int rb = e / 768;
  int r = rb % 80, b = rb / 80;
  ushort4 o;
  if (r < 77) {
    float4 v = *reinterpret_cast<const float4*>(y + ((long)(b * 77 + r) * 768 + c));
    o.x = f2bf(v.x); o.y = f2bf(v.y); o.z = f2bf(v.z); o.w = f2bf(v.w);
  } else {
    o.x = 0; o.y = 0; o.z = 0; o.w = 0;
  }
  *reinterpret_cast<ushort4*>(yp + e) = o;
}

// ---------------- fill f32 zeros --------------------------------------------
__global__ __launch_bounds__(256) void fill_zero(float* __restrict__ p, int n) {
  int i = blockIdx.x * 256 + threadIdx.x;
  if (i < n) p[i] = 0.f;
}

// ---------------- bvo[j] = sum_e bv[e] * Wo[e][j] ---------------------------
__global__ __launch_bounds__(256) void bias_vo(const float* __restrict__ bv,
                                               const float* __restrict__ Wo,
                                               float* __restrict__ bvo) {
  int j = blockIdx.x * 256 + threadIdx.x;  // 0..1023
  float s = 0.f;
  for (int e = 0; e < 1024; ++e) s += bv[e] * Wo[(long)e * 1024 + j];
  bvo[j] = s;
}

// ---------------- bqk[kc] = sum_d bq[d] * Kp[kc][d] -------------------------
__global__ __launch_bounds__(256) void bias_qk(const float* __restrict__ bq,
                                               const u16* __restrict__ Kp,
                                               float* __restrict__ bqk) {
  int kc = blockIdx.x * 256 + threadIdx.x;  // 0..1279
  float s = 0.f;
  for (int d = 0; d < 1024; ++d) s += bq[d] * bf2f(Kp[(long)kc * 1024 + d]);
  bqk[kc] = s;
}

// -- VWop [1280][1024] bf16 -> Vt [16][1024][96] (k >= 80 zeroed) ------------
__global__ __launch_bounds__(256) void transpose_v(const u16* __restrict__ VWop,
                                                   u16* __restrict__ Vt) {
  __shared__ u16 tile[32][34];
  const int tx = threadIdx.x & 31, ty = threadIdx.x >> 5;
  const int b = blockIdx.z;
  const int k0 = blockIdx.y * 32;   // 0,32,64
  const int e0 = blockIdx.x * 32;
  const u16* src = VWop + (long)b * 80 * 1024;
#pragma unroll
  for (int i = 0; i < 4; ++i) {
    int k = k0 + ty + i * 8;
    tile[ty + i * 8][tx] = (k < 80) ? src[(long)k * 1024 + e0 + tx] : (u16)0;
  }
  __syncthreads();
  u16* dst = Vt + (long)b * 1024 * 96;
#pragma unroll
  for (int i = 0; i < 4; ++i) {
    int e = e0 + ty + i * 8;
    dst[(long)e * 96 + k0 + tx] = tile[tx][ty + i * 8];
  }
}

// --- pack Vt into fragment-major: VWof[b][ct=64][kk=3][lane=64][8] bf16 -----
__global__ __launch_bounds__(256) void pack_v(const u16* __restrict__ Vt,
                                              u16* __restrict__ Vf) {
  const int lane = threadIdx.x & 63;
  const int w = blockIdx.x * 4 + (threadIdx.x >> 6);  // 0..3071
  const int b = w / 192, rem = w % 192;
  const int ct = rem / 3, kk = rem % 3;
  const int lr = lane & 15, lk = lane >> 4;
  const u16* src = Vt + (long)b * 1024 * 96 + (long)(ct * 16 + lr) * 96 + kk * 32 + lk * 8;
  *reinterpret_cast<ulong2*>(Vf + (long)w * 512 + lane * 8) =
      *reinterpret_cast<const ulong2*>(src);
}

// --- pack M1T [1280][1024] into M1f[b][kk=32][n=5][lane][8] bf16 ------------
__global__ __launch_bounds__(256) void pack_m1(const u16* __restrict__ M1T,
                                               u16* __restrict__ M1f) {
  const int lane = threadIdx.x & 63;
  const int w = blockIdx.x * 4 + (threadIdx.x >> 6);  // 0..2559
  const int b = w / 160, rem = w % 160;
  const int kk = rem / 5, n = rem % 5;
  const int lr = lane & 15, lk = lane >> 4;
  const u16* src = M1T + ((long)b * 80 + n * 16 + lr) * 1024 + kk * 32 + lk * 8;
  *reinterpret_cast<ulong2*>(M1f + (long)w * 512 + lane * 8) =
      *reinterpret_cast<const ulong2*>(src);
}

// ====== 256x256 m201-style 8-phase bf16 GEMM body (r13/r15-proven) =========
// C (bf16 row-major) = A @ Bt^T + bias. flat/nb parameterized for pairing.
static __device__ void gemm_body(int flat, int nb,
                                 const u16* __restrict__ A,
                                 const u16* __restrict__ Bt,
                                 const float* __restrict__ bias,
                                 u16* __restrict__ Cv,
                                 int M, int N, int K) {
  extern __shared__ __align__(16) u16 lds[];
  const int tid = threadIdx.x;
  const int lane = tid & 63, wid = tid >> 6;
  const int lr = lane & 15, lk = lane >> 4;
  const int wr = wid >> 2, wc = wid & 3;

  int widx = flat;
  if ((nb & 7) == 0) {
    int per = nb >> 3;
    widx = (flat & 7) * per + (flat >> 3);
  }
  const int nbx = N >> 8;
  const long m0 = (long)(widx / nbx) * 256;
  const long n0 = (long)(widx % nbx) * 256;
  const int nt = K >> 6;

  f32x4 acc[8][4] = {};

  const long abase = m0 * (long)K;
  const long bbase = n0 * (long)K;
  const int srl = tid >> 3;
  const int scl = tid & 7;

#define STAGE_HALF(SRC, sbase, t_, half_, ldsbase)                           \
  do {                                                                       \
    long k0_ = (long)(t_) * 64;                                              \
    _Pragma("unroll")                                                        \
    for (int j_ = 0; j_ < 2; ++j_) {                                         \
      int row_ = (half_) * 128 + j_ * 64 + srl;                              \
      int cg_ = scl ^ (row_ & 7);                                            \
      GLOAD_LDS16(SRC + (sbase) + (long)row_ * K + k0_ + cg_ * 8,            \
                  lds + (ldsbase) + row_ * 64 + scl * 8);                    \
    }                                                                        \
  } while (0)

#define LDB_ALL(p)                                                           \
  _Pragma("unroll")                                                          \
  for (int n_ = 0; n_ < 4; ++n_)                                             \
    _Pragma("unroll")                                                        \
    for (int kk_ = 0; kk_ < 2; ++kk_) {                                      \
      int row_ = wc * 64 + n_ * 16 + lr;                                     \
      int ch_ = (kk_ * 4 + lk) ^ (lr & 7);                                   \
      bq[n_][kk_] = *reinterpret_cast<const bf16x8*>(                        \
          lds + 32768 + (p) * 16384 + row_ * 64 + ch_ * 8);                  \
    }

#define LDA_Q(p, q)                                                          \
  _Pragma("unroll")                                                          \
  for (int i_ = 0; i_ < 2; ++i_)                                             \
    _Pragma("unroll")                                                        \
    for (int kk_ = 0; kk_ < 2; ++kk_) {                                      \
      int row_ = wr * 128 + ((q) * 2 + i_) * 16 + lr;                        \
      int ch_ = (kk_ * 4 + lk) ^ (lr & 7);                                   \
      af[i_][kk_] = *reinterpret_cast<const bf16x8*>(                        \
          lds + (p) * 16384 + row_ * 64 + ch_ * 8);                          \
    }

#define MFMA_Q(q)                                                            \
  __builtin_amdgcn_s_setprio(1);                                             \
  _Pragma("unroll")                                                          \
  for (int kk_ = 0; kk_ < 2; ++kk_)                                          \
    _Pragma("unroll")                                                        \
    for (int i_ = 0; i_ < 2; ++i_)                                           \
      _Pragma("unroll")                                                      \
      for (int n_ = 0; n_ < 4; ++n_)                                         \
        acc[(q) * 2 + i_][n_] = __builtin_amdgcn_mfma_f32_16x16x32_bf16(     \
            af[i_][kk_], bq[n_][kk_], acc[(q) * 2 + i_][n_], 0, 0, 0);       \
  __builtin_amdgcn_s_setprio(0);

  STAGE_HALF(A, abase, 0, 0, 0);
  STAGE_HALF(A, abase, 0, 1, 0);
  STAGE_HALF(Bt, bbase, 0, 0, 32768);
  STAGE_HALF(Bt, bbase, 0, 1, 32768);
  STAGE_HALF(Bt, bbase, 1, 0, 49152);
  STAGE_HALF(Bt, bbase, 1, 1, 49152);
  VMCNT(4);
  BAR();

  const int niter = nt >> 1;
  for (int tp = 0; tp < niter; ++tp) {
    const int T = tp << 1;
    const bool more = (T + 2 < nt);
    bf16x8 af[2][2], bq[4][2];

    LDB_ALL(0); LDA_Q(0, 0);
    STAGE_HALF(A, abase, T + 1, 0, 16384);
    BAR(); LGKM0(); MFMA_Q(0); BAR();
    LDA_Q(0, 1);
    STAGE_HALF(A, abase, T + 1, 1, 16384);
    BAR(); LGKM0(); MFMA_Q(1); BAR();
    LDA_Q(0, 2);
    if (more) STAGE_HALF(Bt, bbase, T + 2, 0, 32768);
    BAR(); LGKM0(); MFMA_Q(2); BAR();
    LDA_Q(0, 3);
    if (more) { STAGE_HALF(Bt, bbase, T + 2, 1, 32768); VMCNT(4); }
    else VMCNT(0);
    BAR(); LGKM0(); MFMA_Q(3); BAR();

    LDB_ALL(1); LDA_Q(1, 0);
    if (more) STAGE_HALF(A, abase, T + 2, 0, 0);
    BAR(); LGKM0(); MFMA_Q(0); BAR();
    LDA_Q(1, 1);
    if (more) STAGE_HALF(A, abase, T + 2, 1, 0);
    BAR(); LGKM0(); MFMA_Q(1); BAR();
    LDA_Q(1, 2);
    if (more) STAGE_HALF(Bt, bbase, T + 3, 0, 49152);
    BAR(); LGKM0(); MFMA_Q(2); BAR();
    LDA_Q(1, 3);
    if (more) { STAGE_HALF(Bt, bbase, T + 3, 1, 49152); VMCNT(4); }
    BAR(); LGKM0(); MFMA_Q(3); BAR();
  }

  const long mrow = m0 + wr * 128;
  const long ncol = n0 + wc * 64;

  // bf16 epilogue via per-wave LDS transpose -> full 128B-line stores
  __syncthreads();
  u16* ep = lds + wid * (16 * 72);
  float bb[4];
#pragma unroll
  for (int n = 0; n < 4; ++n) bb[n] = bias[ncol + n * 16 + lr];
  const int rr = lane >> 4, cc = lane & 15;
#pragma unroll
  for (int m = 0; m < 8; ++m) {
#pragma unroll
    for (int n = 0; n < 4; ++n)
#pragma unroll
      for (int j = 0; j < 4; ++j)
        ep[(lk * 4 + j) * 72 + n * 16 + lr] = f2bf(acc[m][n][j] + bb[n]);
    asm volatile("s_waitcnt lgkmcnt(0)" ::: "memory");
#pragma unroll
    for (int s = 0; s < 4; ++s) {
      uint2 v = *reinterpret_cast<const uint2*>(ep + (s * 4 + rr) * 72 + cc * 4);
      *reinterpret_cast<uint2*>(Cv + (mrow + m * 16 + s * 4 + rr) * N +
                                ncol + cc * 4) = v;
    }
    asm volatile("s_waitcnt lgkmcnt(0)" ::: "memory");
  }
#undef STAGE_HALF
#undef LDB_ALL
#undef LDA_Q
#undef MFMA_Q
}

// Two independent GEMM jobs in one dispatch (fills the machine).
__global__ __launch_bounds__(512, 2) void gemm8_pair(
    int split,
    const u16* A0, const u16* B0, const float* b0, u16* C0, int M0, int N0, int K0,
    const u16* A1, const u16* B1, const float* b1, u16* C1, int M1, int N1, int K1) {
  if ((int)blockIdx.x < split)
    gemm_body(blockIdx.x, split, A0, B0, b0, C0, M0, N0, K0);
  else
    gemm_body(blockIdx.x - split, gridDim.x - split, A1, B1, b1, C1, M1, N1, K1);
}

// ---- attention scores+softmax: 16 q-rows/block; P fragments out ------------
// xf fragment-major (rt == blockIdx.x), M1f [16][32][5][512] fragment-major,
// bqk [1280] f32 (bq . k correction). Pf [4096][3][512] bf16 out.
__global__ __launch_bounds__(256) void attn_qk(const u16* __restrict__ xf,
                                               const u16* __restrict__ M1f,
                                               const float* __restrict__ bqk,
                                               u16* __restrict__ Pf) {
  const int blk = blockIdx.x;
  const int b = blk >> 8;
  const int tid = threadIdx.x;
  const int lane = tid & 63, wave = tid >> 6;
  const int lr = lane & 15, lk = lane >> 4;

  __shared__ float S4[4][16][80];
  __shared__ __align__(16) u16 P_lds[16][104];

  // Phase 1: scores = x @ M1T; wave w covers d-slice w*256..+255
  f32x4 acc[5] = {};
  const u16* qfb = xf + (long)blk * 16384;
  const u16* mfb = M1f + (long)b * 81920;
#pragma unroll
  for (int t = 0; t < 8; ++t) {
    int kk = wave * 8 + t;
    bf16x8 qa = *reinterpret_cast<const bf16x8*>(qfb + ((long)kk * 64 + lane) * 8);
#pragma unroll
    for (int n = 0; n < 5; ++n) {
      bf16x8 mf = *reinterpret_cast<const bf16x8*>(mfb + ((long)kk * 5 + n) * 512 + lane * 8);
      acc[n] = __builtin_amdgcn_mfma_f32_16x16x32_bf16(qa, mf, acc[n], 0, 0, 0);
    }
  }
#pragma unroll
  for (int n = 0; n < 5; ++n)
#pragma unroll
    for (int j = 0; j < 4; ++j)
      S4[wave][lk * 4 + j][n * 16 + lr] = acc[n][j];
  __syncthreads();

  // Phase 2: cross-wave reduce + bqk + softmax -> P_lds (cols 80..95 zeroed)
  {
    const int r = tid >> 4, ci = tid & 15;
    const float scale = 0.088388347648318447f;  // 1/sqrt(128)
    float v[5];
    float mx = -3e38f;
#pragma unroll
    for (int i = 0; i < 5; ++i) {
      int c = ci + 16 * i;
      float s = (S4[0][r][c] + S4[1][r][c]) + (S4[2][r][c] + S4[3][r][c]);
      s = (s + bqk[b * 80 + c]) * scale;
      if (c >= 77) s = -3e38f;
      v[i] = s;
      mx = fmaxf(mx, s);
    }
#pragma unroll
    for (int off = 1; off < 16; off <<= 1) mx = fmaxf(mx, __shfl_xor(mx, off, 64));
    float sum = 0.f, e[5];
#pragma unroll
    for (int i = 0; i < 5; ++i) { e[i] = __expf(v[i] - mx); sum += e[i]; }
#pragma unroll
    for (int off = 1; off < 16; off <<= 1) sum += __shfl_xor(sum, off, 64);
    float inv = 1.f / sum;
#pragma unroll
    for (int i = 0; i < 5; ++i) P_lds[r][ci + 16 * i] = f2bf(e[i] * inv);
    P_lds[r][80 + ci] = 0;
  }
  __syncthreads();

  // Emit P fragments (A-operand layout): 3 x 1KB coalesced stores
  if (wave < 3) {
    ulong2 v = *reinterpret_cast<const ulong2*>(&P_lds[lr][wave * 32 + lk * 8]);
    *reinterpret_cast<ulong2*>(Pf + (long)blk * 1536 + wave * 512 + lane * 8) = v;
  }
}

// ---- final: out = P @ VWo + bo (f32). 64 rows/block, 1024 blocks. ----------
__global__ __launch_bounds__(256, 2) void pv_out(const u16* __restrict__ Pf,
                                                 const u16* __restrict__ VWof,
                                                 const float* __restrict__ bo,
                                                 float* __restrict__ out) {
  extern __shared__ __align__(16) float ot[];   // [4 waves][16*260] f32
  const int tid = threadIdx.x, lane = tid & 63, wave = tid >> 6;
  const int lr = lane & 15, lk = lane >> 4;
  const long blk = blockIdx.x;
  const int b = (int)(blk >> 6);
  const long rt16 = blk * 4 + wave;

  bf16x8 pa[3];
#pragma unroll
  for (int kk = 0; kk < 3; ++kk)
    pa[kk] = *reinterpret_cast<const bf16x8*>(Pf + rt16 * 1536 + kk * 512 + lane * 8);
  const u16* vfb = VWof + (long)b * 64 * 3 * 512;
  float* otw = ot + wave * (16 * 260);
  const int rr = lane >> 4, cc = lane & 15;

#pragma unroll
  for (int grp = 0; grp < 4; ++grp) {
#pragma unroll
    for (int n = 0; n < 16; ++n) {
      int ct = grp * 16 + n;
      f32x4 o = {};
#pragma unroll
      for (int kk = 0; kk < 3; ++kk) {
        bf16x8 vq = *reinterpret_cast<const bf16x8*>(vfb + ((long)ct * 3 + kk) * 512 + lane * 8);
        o = __builtin_amdgcn_mfma_f32_16x16x32_bf16(pa[kk], vq, o, 0, 0, 0);
      }
      float bov = bo[ct * 16 + lr];
#pragma unroll
      for (int j = 0; j < 4; ++j)
        otw[(lk * 4 + j) * 260 + n * 16 + lr] = o[j] + bov;
    }
    asm volatile("s_waitcnt lgkmcnt(0)" ::: "memory");
#pragma unroll
    for (int s = 0; s < 4; ++s)
#pragma unroll
      for (int g = 0; g < 4; ++g) {
        f32x4 v = *reinterpret_cast<const f32x4*>(otw + (s * 4 + rr) * 260 + g * 64 + cc * 4);
        *reinterpret_cast<f32x4*>(out + (rt16 * 16 + s * 4 + rr) * 1024 +
                                  grp * 256 + g * 64 + cc * 4) = v;
      }
    asm volatile("s_waitcnt lgkmcnt(0)" ::: "memory");
  }
}

extern "C" void kernel_launch(void* const* d_in, const int* in_sizes, int n_in,
                              void* d_out, int out_size, void* d_ws, size_t ws_size,
                              hipStream_t stream) {
  const float* x  = (const float*)d_in[0];
  const float* y  = (const float*)d_in[1];
  const float* Wq = (const float*)d_in[2];
  const float* bq = (const float*)d_in[3];
  const float* Wk = (const float*)d_in[4];
  const float* bk = (const float*)d_in[5];
  const float* Wv = (const float*)d_in[6];
  const float* bv = (const float*)d_in[7];
  const float* Wo = (const float*)d_in[8];
  const float* bo = (const float*)d_in[9];

  const int B = 16, D = 1024, Dc = 768, Lp = 80;

  char* p = (char*)d_ws;
  u16* Wqb   = (u16*)p; p += (size_t)D * D * 2;        // Wq bf16 row-major
  u16* Wvb   = (u16*)p; p += (size_t)Dc * D * 2;       // Wv bf16 row-major
  u16* Wkt   = (u16*)p; p += (size_t)D * Dc * 2;       // Wk^T
  u16* Wot   = (u16*)p; p += (size_t)D * D * 2;        // Wo^T
  u16* yp    = (u16*)p; p += (size_t)B * Lp * Dc * 2;  // padded y bf16
  u16* Kp    = (u16*)p; p += (size_t)B * Lp * D * 2;   // K rows [1280][1024]
  u16* WvWoT = (u16*)p; p += (size_t)D * Dc * 2;       // (Wv@Wo)^T [1024][768]
  u16* VWop  = (u16*)p; p += (size_t)B * Lp * D * 2;   // V@Wo rows [1280][1024]
  u16* M1T   = (u16*)p; p += (size_t)B * Lp * D * 2;   // K@Wq (M1^T) [1280][1024]
  u16* Vt    = (u16*)p; p += (size_t)B * D * 96 * 2;   // VWo^T per batch, k-pad
  u16* VWof  = (u16*)p; p += (size_t)B * 64 * 3 * 512 * 2;
  u16* M1f   = (u16*)p; p += (size_t)B * 160 * 512 * 2;
  u16* Pf    = (u16*)p; p += (size_t)4096 * 1536 * 2;  // 12.6 MB
  float* zeros = (float*)p; p += (size_t)1024 * 4;
  float* bvoB  = (float*)p; p += (size_t)1024 * 4;
  float* bqkB  = (float*)p; p += (size_t)1280 * 4;
  u16* xf = (u16*)d_out;  // x fragments live in d_out until pv_out overwrites

  (void)hipFuncSetAttribute(reinterpret_cast<const void*>(&gemm8_pair),
                            hipFuncAttributeMaxDynamicSharedMemorySize, 131072);
  (void)hipFuncSetAttribute(reinterpret_cast<const void*>(&pv_out),
                            hipFuncAttributeMaxDynamicSharedMemorySize, 4 * 16 * 260 * 4);

  // conversions & bias precomputes
  fill_zero<<<4, 256, 0, stream>>>(zeros, 1024);
  bias_vo<<<4, 256, 0, stream>>>(bv, Wo, bvoB);
  cvt_xf<<<4096, 256, 0, stream>>>(x, xf);
  cvt_f32_bf16<<<1024, 256, 0, stream>>>(Wq, Wqb, (long)D * D / 4);
  cvt_f32_bf16<<<768, 256, 0, stream>>>(Wv, Wvb, (long)Dc * D / 4);
  transpose_cvt<<<dim3(D / 32, Dc / 32), 256, 0, stream>>>(Wk, Wkt, Dc, D);
  transpose_cvt<<<dim3(D / 32, D / 32), 256, 0, stream>>>(Wo, Wot, D, D);
  cvt_y_pad<<<(B * Lp * Dc / 4) / 256, 256, 0, stream>>>(y, yp);

  // stage A: Kp = yp @ Wk + bk  ||  WvWoT = Wo^T @ Wv^T (zero bias)
  gemm8_pair<<<32, 512, 131072, stream>>>(
      20,
      yp, Wkt, bk, Kp, B * Lp, D, Dc,
      Wot, Wvb, zeros, WvWoT, D, Dc, D);

  bias_qk<<<5, 256, 0, stream>>>(bq, Kp, bqkB);

  // stage B: VWop = yp @ WvWo + bvo  ||  M1T = Kp @ Wq (zero bias)
  gemm8_pair<<<40, 512, 131072, stream>>>(
      20,
      yp, WvWoT, bvoB, VWop, B * Lp, D, Dc,
      Kp, Wqb, zeros, M1T, B * Lp, D, D);

  // fragment packs
  transpose_v<<<dim3(D / 32, 3, B), 256, 0, stream>>>(VWop, Vt);
  pack_v<<<(B * 64 * 3) / 4, 256, 0, stream>>>(Vt, VWof);
  pack_m1<<<(B * 160) / 4, 256, 0, stream>>>(M1T, M1f);

  // attention scores + softmax -> P fragments
  attn_qk<<<4096, 256, 0, stream>>>(xf, M1f, bqkB, Pf);

  // final: out = P @ VWo + bo (f32)
  pv_out<<<1024, 256, 4 * 16 * 260 * 4, stream>>>(Pf, VWof, bo, (float*)d_out);
}

// Round 17
// 324.851 us; speedup vs baseline: 2.1038x; 1.1457x over previous
//
#include <hip/hip_runtime.h>

typedef unsigned short u16;
typedef __bf16 bf16x8 __attribute__((ext_vector_type(8)));
typedef float f32x4 __attribute__((ext_vector_type(4)));

static __device__ __forceinline__ u16 f2bf(float f) {
  unsigned u = __builtin_bit_cast(unsigned, f);
  u = u + 0x7FFFu + ((u >> 16) & 1u);   // RNE
  return (u16)(u >> 16);
}
static __device__ __forceinline__ float bf2f(u16 h) {
  return __builtin_bit_cast(float, (unsigned)h << 16);
}

#define GLOAD_LDS16(g, l) __builtin_amdgcn_global_load_lds(              \
    (const __attribute__((address_space(1))) void*)(g),                  \
    (__attribute__((address_space(3))) void*)(l), 16, 0, 0)
#define BAR() asm volatile("s_barrier" ::: "memory")
#define VMCNT(n) asm volatile("s_waitcnt vmcnt(" #n ")" ::: "memory")
#define LGKM0() do { asm volatile("s_waitcnt lgkmcnt(0)" ::: "memory");   \
                     __builtin_amdgcn_sched_barrier(0); } while (0)

// ---------------- elementwise f32 -> bf16 (4 elems/thread) ----------------
__global__ __launch_bounds__(256) void cvt_f32_bf16(const float* __restrict__ in,
                                                    u16* __restrict__ out, long n4) {
  long i = (long)blockIdx.x * 256 + threadIdx.x;
  if (i >= n4) return;
  float4 v = reinterpret_cast<const float4*>(in)[i];
  ushort4 o;
  o.x = f2bf(v.x); o.y = f2bf(v.y); o.z = f2bf(v.z); o.w = f2bf(v.w);
  reinterpret_cast<ushort4*>(out)[i] = o;
}

// ------------- transpose + convert: W[K][N] f32 -> Wt[N][K] bf16 ----------
__global__ __launch_bounds__(256) void transpose_cvt(const float* __restrict__ W,
                                                     u16* __restrict__ Wt,
                                                     int K, int N) {
  __shared__ float tile[32][33];
  const int tx = threadIdx.x & 31, ty = threadIdx.x >> 5;
  const int n0 = blockIdx.x * 32, k0 = blockIdx.y * 32;
#pragma unroll
  for (int i = 0; i < 4; ++i)
    tile[ty + i * 8][tx] = W[(long)(k0 + ty + i * 8) * N + n0 + tx];
  __syncthreads();
#pragma unroll
  for (int i = 0; i < 4; ++i) {
    int r = ty + i * 8;
    Wt[(long)(n0 + r) * K + k0 + tx] = f2bf(tile[tx][r]);
  }
}

// -------- y [16][77][768] f32 -> yp [16][80][768] bf16, pad rows = 0 -------
__global__ __launch_bounds__(256) void cvt_y_pad(const float* __restrict__ y,
                                                 u16* __restrict__ yp) {
  int idx = blockIdx.x * 256 + threadIdx.x;
  int e = idx * 4;
  int c = e % 768;
  int rb = e / 768;
  int r = rb % 80, b = rb / 80;
  ushort4 o;
  if (r < 77) {
    float4 v = *reinterpret_cast<const float4*>(y + ((long)(b * 77 + r) * 768 + c));
    o.x = f2bf(v.x); o.y = f2bf(v.y); o.z = f2bf(v.z); o.w = f2bf(v.w);
  } else {
    o.x = 0; o.y = 0; o.z = 0; o.w = 0;
  }
  *reinterpret_cast<ushort4*>(yp + e) = o;
}

// ---------------- fill f32 zeros --------------------------------------------
__global__ __launch_bounds__(256) void fill_zero(float* __restrict__ p, int n) {
  int i = blockIdx.x * 256 + threadIdx.x;
  if (i < n) p[i] = 0.f;
}

// ---------------- bvo[j] = sum_e bv[e] * Wo[e][j] ---------------------------
__global__ __launch_bounds__(256) void bias_vo(const float* __restrict__ bv,
                                               const float* __restrict__ Wo,
                                               float* __restrict__ bvo) {
  int j = blockIdx.x * 256 + threadIdx.x;  // 0..1023
  float s = 0.f;
  for (int e = 0; e < 1024; ++e) s += bv[e] * Wo[(long)e * 1024 + j];
  bvo[j] = s;
}

// ----- out[r] = dot(W[r][0..1024), v) for f32 W; one wave per row ----------
__global__ __launch_bounds__(256) void dot_rows(const float* __restrict__ W,
                                                const float* __restrict__ v,
                                                float* __restrict__ out, int rows) {
  int w = blockIdx.x * 4 + (threadIdx.x >> 6);
  int lane = threadIdx.x & 63;
  if (w >= rows) return;
  const float* r = W + (long)w * 1024;
  float s = 0.f;
#pragma unroll
  for (int i = 0; i < 4; ++i) {
    f32x4 a = *reinterpret_cast<const f32x4*>(r + lane * 4 + i * 256);
    f32x4 b = *reinterpret_cast<const f32x4*>(v + lane * 4 + i * 256);
    s += a[0] * b[0] + a[1] * b[1] + a[2] * b[2] + a[3] * b[3];
  }
#pragma unroll
  for (int off = 1; off < 64; off <<= 1) s += __shfl_xor(s, off, 64);
  if (lane == 0) out[w] = s;
}

// ----- bqk[kc] = dot(yp[kc] (768 bf16), wkbq f32); one wave per row --------
__global__ __launch_bounds__(256) void bqk_yp(const u16* __restrict__ yp,
                                              const float* __restrict__ wkbq,
                                              float* __restrict__ bqk) {
  int w = blockIdx.x * 4 + (threadIdx.x >> 6);   // 0..1279
  int lane = threadIdx.x & 63;
  const u16* r = yp + (long)w * 768;
  float s = 0.f;
#pragma unroll
  for (int i = 0; i < 3; ++i) {
    ushort4 a = *reinterpret_cast<const ushort4*>(r + lane * 4 + i * 256);
    f32x4 b = *reinterpret_cast<const f32x4*>(wkbq + lane * 4 + i * 256);
    s += bf2f(a.x) * b[0] + bf2f(a.y) * b[1] + bf2f(a.z) * b[2] + bf2f(a.w) * b[3];
  }
#pragma unroll
  for (int off = 1; off < 64; off <<= 1) s += __shfl_xor(s, off, 64);
  if (lane == 0) bqk[w] = s;
}

// -- VWop [1280][1024] bf16 -> Vt [16][1024][96] (k >= 80 zeroed) ------------
__global__ __launch_bounds__(256) void transpose_v(const u16* __restrict__ VWop,
                                                   u16* __restrict__ Vt) {
  __shared__ u16 tile[32][34];
  const int tx = threadIdx.x & 31, ty = threadIdx.x >> 5;
  const int b = blockIdx.z;
  const int k0 = blockIdx.y * 32;   // 0,32,64
  const int e0 = blockIdx.x * 32;
  const u16* src = VWop + (long)b * 80 * 1024;
#pragma unroll
  for (int i = 0; i < 4; ++i) {
    int k = k0 + ty + i * 8;
    tile[ty + i * 8][tx] = (k < 80) ? src[(long)k * 1024 + e0 + tx] : (u16)0;
  }
  __syncthreads();
  u16* dst = Vt + (long)b * 1024 * 96;
#pragma unroll
  for (int i = 0; i < 4; ++i) {
    int e = e0 + ty + i * 8;
    dst[(long)e * 96 + k0 + tx] = tile[tx][ty + i * 8];
  }
}

// --- pack Vt into fragment-major: VWof[b][ct=64][kk=3][lane=64][8] bf16 -----
__global__ __launch_bounds__(256) void pack_v(const u16* __restrict__ Vt,
                                              u16* __restrict__ Vf) {
  const int lane = threadIdx.x & 63;
  const int w = blockIdx.x * 4 + (threadIdx.x >> 6);  // 0..3071
  const int b = w / 192, rem = w % 192;
  const int ct = rem / 3, kk = rem % 3;
  const int lr = lane & 15, lk = lane >> 4;
  const u16* src = Vt + (long)b * 1024 * 96 + (long)(ct * 16 + lr) * 96 + kk * 32 + lk * 8;
  *reinterpret_cast<ulong2*>(Vf + (long)w * 512 + lane * 8) =
      *reinterpret_cast<const ulong2*>(src);
}

// --- pack M1T [1280][1024] into M1f[b][kk=32][n=5][lane][8] bf16 ------------
__global__ __launch_bounds__(256) void pack_m1(const u16* __restrict__ M1T,
                                               u16* __restrict__ M1f) {
  const int lane = threadIdx.x & 63;
  const int w = blockIdx.x * 4 + (threadIdx.x >> 6);  // 0..2559
  const int b = w / 160, rem = w % 160;
  const int kk = rem / 5, n = rem % 5;
  const int lr = lane & 15, lk = lane >> 4;
  const u16* src = M1T + ((long)b * 80 + n * 16 + lr) * 1024 + kk * 32 + lk * 8;
  *reinterpret_cast<ulong2*>(M1f + (long)w * 512 + lane * 8) =
      *reinterpret_cast<const ulong2*>(src);
}

// ====== 256x256 m201-style 8-phase bf16 GEMM body (r13/r15-proven) =========
static __device__ void gemm_body(int flat, int nb,
                                 const u16* __restrict__ A,
                                 const u16* __restrict__ Bt,
                                 const float* __restrict__ bias,
                                 u16* __restrict__ Cv,
                                 int M, int N, int K) {
  extern __shared__ __align__(16) u16 lds[];
  const int tid = threadIdx.x;
  const int lane = tid & 63, wid = tid >> 6;
  const int lr = lane & 15, lk = lane >> 4;
  const int wr = wid >> 2, wc = wid & 3;

  int widx = flat;
  if ((nb & 7) == 0) {
    int per = nb >> 3;
    widx = (flat & 7) * per + (flat >> 3);
  }
  const int nbx = N >> 8;
  const long m0 = (long)(widx / nbx) * 256;
  const long n0 = (long)(widx % nbx) * 256;
  const int nt = K >> 6;

  f32x4 acc[8][4] = {};

  const long abase = m0 * (long)K;
  const long bbase = n0 * (long)K;
  const int srl = tid >> 3;
  const int scl = tid & 7;

#define STAGE_HALF(SRC, sbase, t_, half_, ldsbase)                           \
  do {                                                                       \
    long k0_ = (long)(t_) * 64;                                              \
    _Pragma("unroll")                                                        \
    for (int j_ = 0; j_ < 2; ++j_) {                                         \
      int row_ = (half_) * 128 + j_ * 64 + srl;                              \
      int cg_ = scl ^ (row_ & 7);                                            \
      GLOAD_LDS16(SRC + (sbase) + (long)row_ * K + k0_ + cg_ * 8,            \
                  lds + (ldsbase) + row_ * 64 + scl * 8);                    \
    }                                                                        \
  } while (0)

#define LDB_ALL(p)                                                           \
  _Pragma("unroll")                                                          \
  for (int n_ = 0; n_ < 4; ++n_)                                             \
    _Pragma("unroll")                                                        \
    for (int kk_ = 0; kk_ < 2; ++kk_) {                                      \
      int row_ = wc * 64 + n_ * 16 + lr;                                     \
      int ch_ = (kk_ * 4 + lk) ^ (lr & 7);                                   \
      bq[n_][kk_] = *reinterpret_cast<const bf16x8*>(                        \
          lds + 32768 + (p) * 16384 + row_ * 64 + ch_ * 8);                  \
    }

#define LDA_Q(p, q)                                                          \
  _Pragma("unroll")                                                          \
  for (int i_ = 0; i_ < 2; ++i_)                                             \
    _Pragma("unroll")                                                        \
    for (int kk_ = 0; kk_ < 2; ++kk_) {                                      \
      int row_ = wr * 128 + ((q) * 2 + i_) * 16 + lr;                        \
      int ch_ = (kk_ * 4 + lk) ^ (lr & 7);                                   \
      af[i_][kk_] = *reinterpret_cast<const bf16x8*>(                        \
          lds + (p) * 16384 + row_ * 64 + ch_ * 8);                          \
    }

#define MFMA_Q(q)                                                            \
  __builtin_amdgcn_s_setprio(1);                                             \
  _Pragma("unroll")                                                          \
  for (int kk_ = 0; kk_ < 2; ++kk_)                                          \
    _Pragma("unroll")                                                        \
    for (int i_ = 0; i_ < 2; ++i_)                                           \
      _Pragma("unroll")                                                      \
      for (int n_ = 0; n_ < 4; ++n_)                                         \
        acc[(q) * 2 + i_][n_] = __builtin_amdgcn_mfma_f32_16x16x32_bf16(     \
            af[i_][kk_], bq[n_][kk_], acc[(q) * 2 + i_][n_], 0, 0, 0);       \
  __builtin_amdgcn_s_setprio(0);

  STAGE_HALF(A, abase, 0, 0, 0);
  STAGE_HALF(A, abase, 0, 1, 0);
  STAGE_HALF(Bt, bbase, 0, 0, 32768);
  STAGE_HALF(Bt, bbase, 0, 1, 32768);
  STAGE_HALF(Bt, bbase, 1, 0, 49152);
  STAGE_HALF(Bt, bbase, 1, 1, 49152);
  VMCNT(4);
  BAR();

  const int niter = nt >> 1;
  for (int tp = 0; tp < niter; ++tp) {
    const int T = tp << 1;
    const bool more = (T + 2 < nt);
    bf16x8 af[2][2], bq[4][2];

    LDB_ALL(0); LDA_Q(0, 0);
    STAGE_HALF(A, abase, T + 1, 0, 16384);
    BAR(); LGKM0(); MFMA_Q(0); BAR();
    LDA_Q(0, 1);
    STAGE_HALF(A, abase, T + 1, 1, 16384);
    BAR(); LGKM0(); MFMA_Q(1); BAR();
    LDA_Q(0, 2);
    if (more) STAGE_HALF(Bt, bbase, T + 2, 0, 32768);
    BAR(); LGKM0(); MFMA_Q(2); BAR();
    LDA_Q(0, 3);
    if (more) { STAGE_HALF(Bt, bbase, T + 2, 1, 32768); VMCNT(4); }
    else VMCNT(0);
    BAR(); LGKM0(); MFMA_Q(3); BAR();

    LDB_ALL(1); LDA_Q(1, 0);
    if (more) STAGE_HALF(A, abase, T + 2, 0, 0);
    BAR(); LGKM0(); MFMA_Q(0); BAR();
    LDA_Q(1, 1);
    if (more) STAGE_HALF(A, abase, T + 2, 1, 0);
    BAR(); LGKM0(); MFMA_Q(1); BAR();
    LDA_Q(1, 2);
    if (more) STAGE_HALF(Bt, bbase, T + 3, 0, 49152);
    BAR(); LGKM0(); MFMA_Q(2); BAR();
    LDA_Q(1, 3);
    if (more) { STAGE_HALF(Bt, bbase, T + 3, 1, 49152); VMCNT(4); }
    BAR(); LGKM0(); MFMA_Q(3); BAR();
  }

  const long mrow = m0 + wr * 128;
  const long ncol = n0 + wc * 64;

  // bf16 epilogue via per-wave LDS transpose -> full 128B-line stores
  __syncthreads();
  u16* ep = lds + wid * (16 * 72);
  float bb[4];
#pragma unroll
  for (int n = 0; n < 4; ++n) bb[n] = bias[ncol + n * 16 + lr];
  const int rr = lane >> 4, cc = lane & 15;
#pragma unroll
  for (int m = 0; m < 8; ++m) {
#pragma unroll
    for (int n = 0; n < 4; ++n)
#pragma unroll
      for (int j = 0; j < 4; ++j)
        ep[(lk * 4 + j) * 72 + n * 16 + lr] = f2bf(acc[m][n][j] + bb[n]);
    asm volatile("s_waitcnt lgkmcnt(0)" ::: "memory");
#pragma unroll
    for (int s = 0; s < 4; ++s) {
      uint2 v = *reinterpret_cast<const uint2*>(ep + (s * 4 + rr) * 72 + cc * 4);
      *reinterpret_cast<uint2*>(Cv + (mrow + m * 16 + s * 4 + rr) * N +
                                ncol + cc * 4) = v;
    }
    asm volatile("s_waitcnt lgkmcnt(0)" ::: "memory");
  }
#undef STAGE_HALF
#undef LDB_ALL
#undef LDA_Q
#undef MFMA_Q
}

// Two independent GEMM jobs in one dispatch (fills the machine).
__global__ __launch_bounds__(512, 2) void gemm8_pair(
    int split,
    const u16* A0, const u16* B0, const float* b0, u16* C0, int M0, int N0, int K0,
    const u16* A1, const u16* B1, const float* b1, u16* C1, int M1, int N1, int K1) {
  if ((int)blockIdx.x < split)
    gemm_body(blockIdx.x, split, A0, B0, b0, C0, M0, N0, K0);
  else
    gemm_body(blockIdx.x - split, gridDim.x - split, A1, B1, b1, C1, M1, N1, K1);
}

// ---- attention scores+softmax, x-conversion fused: 16 q-rows/block ---------
// x f32 [65536][1024]; M1f [16][32][5][512] fragment-major; bqk [1280] f32.
// Pf [4096][3][512] bf16 out. LDS union: bf16 x-tile (33KB) then S4 f32.
__global__ __launch_bounds__(256) void attn_qk(const float* __restrict__ x,
                                               const u16* __restrict__ M1f,
                                               const float* __restrict__ bqk,
                                               u16* __restrict__ Pf) {
  const long blk = blockIdx.x;
  const int b = (int)(blk >> 8);
  const int tid = threadIdx.x;
  const int lane = tid & 63, wave = tid >> 6;
  const int lr = lane & 15, lk = lane >> 4;

  __shared__ __align__(16) u16 ubuf[16 * 1032];   // x-tile, then S4 (20.5KB)
  __shared__ __align__(16) u16 P_lds[16][104];
  float* S4 = reinterpret_cast<float*>(ubuf);

  // Phase 0: load 16 x-rows f32 coalesced, convert -> bf16 tile
  {
    const int row = tid >> 4, cseg = tid & 15;
    const float* src = x + (blk * 16 + row) * 1024 + cseg * 64;
    u16* dst = ubuf + row * 1032 + cseg * 64;
#pragma unroll
    for (int i = 0; i < 16; ++i) {
      f32x4 v = *reinterpret_cast<const f32x4*>(src + i * 4);
      ushort4 o;
      o.x = f2bf(v[0]); o.y = f2bf(v[1]); o.z = f2bf(v[2]); o.w = f2bf(v[3]);
      *reinterpret_cast<ushort4*>(dst + i * 4) = o;
    }
  }
  __syncthreads();

  // Phase 1: scores = x @ M1T; wave w covers d-slice w*256..+255
  f32x4 acc[5] = {};
  const u16* mfb = M1f + (long)b * 81920;
#pragma unroll
  for (int t = 0; t < 8; ++t) {
    int kk = wave * 8 + t;
    bf16x8 qa = *reinterpret_cast<const bf16x8*>(ubuf + lr * 1032 + kk * 32 + lk * 8);
#pragma unroll
    for (int n = 0; n < 5; ++n) {
      bf16x8 mf = *reinterpret_cast<const bf16x8*>(mfb + ((long)kk * 5 + n) * 512 + lane * 8);
      acc[n] = __builtin_amdgcn_mfma_f32_16x16x32_bf16(qa, mf, acc[n], 0, 0, 0);
    }
  }
  __syncthreads();   // x-tile dead; ubuf becomes S4

#pragma unroll
  for (int n = 0; n < 5; ++n)
#pragma unroll
    for (int j = 0; j < 4; ++j)
      S4[(wave * 16 + lk * 4 + j) * 80 + n * 16 + lr] = acc[n][j];
  __syncthreads();

  // Phase 2: cross-wave reduce + bqk + softmax -> P_lds
  {
    const int r = tid >> 4, ci = tid & 15;
    const float scale = 0.088388347648318447f;  // 1/sqrt(128)
    float v[5];
    float mx = -3e38f;
#pragma unroll
    for (int i = 0; i < 5; ++i) {
      int c = ci + 16 * i;
      float s = (S4[r * 80 + c] + S4[(16 + r) * 80 + c]) +
                (S4[(32 + r) * 80 + c] + S4[(48 + r) * 80 + c]);
      s = (s + bqk[b * 80 + c]) * scale;
      if (c >= 77) s = -3e38f;
      v[i] = s;
      mx = fmaxf(mx, s);
    }
#pragma unroll
    for (int off = 1; off < 16; off <<= 1) mx = fmaxf(mx, __shfl_xor(mx, off, 64));
    float sum = 0.f, e[5];
#pragma unroll
    for (int i = 0; i < 5; ++i) { e[i] = __expf(v[i] - mx); sum += e[i]; }
#pragma unroll
    for (int off = 1; off < 16; off <<= 1) sum += __shfl_xor(sum, off, 64);
    float inv = 1.f / sum;
#pragma unroll
    for (int i = 0; i < 5; ++i) P_lds[r][ci + 16 * i] = f2bf(e[i] * inv);
    P_lds[r][80 + ci] = 0;
  }
  __syncthreads();

  // Emit P fragments (A-operand layout): 3 x 1KB coalesced stores
  if (wave < 3) {
    ulong2 v = *reinterpret_cast<const ulong2*>(&P_lds[lr][wave * 32 + lk * 8]);
    *reinterpret_cast<ulong2*>(Pf + blk * 1536 + wave * 512 + lane * 8) = v;
  }
}

// ---- final: out = P @ VWo + bo (f32). 64 rows/block, 1024 blocks. ----------
__global__ __launch_bounds__(256, 2) void pv_out(const u16* __restrict__ Pf,
                                                 const u16* __restrict__ VWof,
                                                 const float* __restrict__ bo,
                                                 float* __restrict__ out) {
  extern __shared__ __align__(16) float ot[];   // [4 waves][16*260] f32
  const int tid = threadIdx.x, lane = tid & 63, wave = tid >> 6;
  const int lr = lane & 15, lk = lane >> 4;
  const long blk = blockIdx.x;
  const int b = (int)(blk >> 6);
  const long rt16 = blk * 4 + wave;

  bf16x8 pa[3];
#pragma unroll
  for (int kk = 0; kk < 3; ++kk)
    pa[kk] = *reinterpret_cast<const bf16x8*>(Pf + rt16 * 1536 + kk * 512 + lane * 8);
  const u16* vfb = VWof + (long)b * 64 * 3 * 512;
  float* otw = ot + wave * (16 * 260);
  const int rr = lane >> 4, cc = lane & 15;

#pragma unroll
  for (int grp = 0; grp < 4; ++grp) {
#pragma unroll
    for (int n = 0; n < 16; ++n) {
      int ct = grp * 16 + n;
      f32x4 o = {};
#pragma unroll
      for (int kk = 0; kk < 3; ++kk) {
        bf16x8 vq = *reinterpret_cast<const bf16x8*>(vfb + ((long)ct * 3 + kk) * 512 + lane * 8);
        o = __builtin_amdgcn_mfma_f32_16x16x32_bf16(pa[kk], vq, o, 0, 0, 0);
      }
      float bov = bo[ct * 16 + lr];
#pragma unroll
      for (int j = 0; j < 4; ++j)
        otw[(lk * 4 + j) * 260 + n * 16 + lr] = o[j] + bov;
    }
    asm volatile("s_waitcnt lgkmcnt(0)" ::: "memory");
#pragma unroll
    for (int s = 0; s < 4; ++s)
#pragma unroll
      for (int g = 0; g < 4; ++g) {
        f32x4 v = *reinterpret_cast<const f32x4*>(otw + (s * 4 + rr) * 260 + g * 64 + cc * 4);
        *reinterpret_cast<f32x4*>(out + (rt16 * 16 + s * 4 + rr) * 1024 +
                                  grp * 256 + g * 64 + cc * 4) = v;
      }
    asm volatile("s_waitcnt lgkmcnt(0)" ::: "memory");
  }
}

extern "C" void kernel_launch(void* const* d_in, const int* in_sizes, int n_in,
                              void* d_out, int out_size, void* d_ws, size_t ws_size,
                              hipStream_t stream) {
  const float* x  = (const float*)d_in[0];
  const float* y  = (const float*)d_in[1];
  const float* Wq = (const float*)d_in[2];
  const float* bq = (const float*)d_in[3];
  const float* Wk = (const float*)d_in[4];
  const float* bk = (const float*)d_in[5];
  const float* Wv = (const float*)d_in[6];
  const float* bv = (const float*)d_in[7];
  const float* Wo = (const float*)d_in[8];
  const float* bo = (const float*)d_in[9];

  const int B = 16, D = 1024, Dc = 768, Lp = 80;

  char* p = (char*)d_ws;
  u16* Wqb   = (u16*)p; p += (size_t)D * D * 2;        // Wq bf16 row-major
  u16* Wkb   = (u16*)p; p += (size_t)Dc * D * 2;       // Wk bf16 row-major
  u16* Wvb   = (u16*)p; p += (size_t)Dc * D * 2;       // Wv bf16 row-major
  u16* Wot   = (u16*)p; p += (size_t)D * D * 2;        // Wo^T
  u16* yp    = (u16*)p; p += (size_t)B * Lp * Dc * 2;  // padded y bf16
  u16* G     = (u16*)p; p += (size_t)D * Dc * 2;       // (Wq@Wk^T) [1024][768]
  u16* WvWoT = (u16*)p; p += (size_t)D * Dc * 2;       // (Wv@Wo)^T [1024][768]
  u16* M1T   = (u16*)p; p += (size_t)B * Lp * D * 2;   // [1280][1024]
  u16* VWop  = (u16*)p; p += (size_t)B * Lp * D * 2;   // V@Wo rows [1280][1024]
  u16* Vt    = (u16*)p; p += (size_t)B * D * 96 * 2;
  u16* VWof  = (u16*)p; p += (size_t)B * 64 * 3 * 512 * 2;
  u16* M1f   = (u16*)p; p += (size_t)B * 160 * 512 * 2;
  u16* Pf    = (u16*)p; p += (size_t)4096 * 1536 * 2;  // 12.6 MB
  float* zeros = (float*)p; p += (size_t)1024 * 4;
  float* bvoB  = (float*)p; p += (size_t)1024 * 4;
  float* wkbq  = (float*)p; p += (size_t)768 * 4;      // Wk @ bq
  float* bkqB  = (float*)p; p += (size_t)1024 * 4;     // Wq rows . bk
  float* bqkB  = (float*)p; p += (size_t)1280 * 4;     // yp @ wkbq

  (void)hipFuncSetAttribute(reinterpret_cast<const void*>(&gemm8_pair),
                            hipFuncAttributeMaxDynamicSharedMemorySize, 131072);
  (void)hipFuncSetAttribute(reinterpret_cast<const void*>(&pv_out),
                            hipFuncAttributeMaxDynamicSharedMemorySize, 4 * 16 * 260 * 4);

  // conversions & bias precomputes
  fill_zero<<<4, 256, 0, stream>>>(zeros, 1024);
  bias_vo<<<4, 256, 0, stream>>>(bv, Wo, bvoB);
  dot_rows<<<192, 256, 0, stream>>>(Wk, bq, wkbq, 768);     // wkbq = Wk @ bq
  dot_rows<<<256, 256, 0, stream>>>(Wq, bk, bkqB, 1024);    // bkq  = Wq rows . bk
  cvt_f32_bf16<<<1024, 256, 0, stream>>>(Wq, Wqb, (long)D * D / 4);
  cvt_f32_bf16<<<768, 256, 0, stream>>>(Wk, Wkb, (long)Dc * D / 4);
  cvt_f32_bf16<<<768, 256, 0, stream>>>(Wv, Wvb, (long)Dc * D / 4);
  transpose_cvt<<<dim3(D / 32, D / 32), 256, 0, stream>>>(Wo, Wot, D, D);
  cvt_y_pad<<<(B * Lp * Dc / 4) / 256, 256, 0, stream>>>(y, yp);
  bqk_yp<<<320, 256, 0, stream>>>(yp, wkbq, bqkB);

  // stage A (weight-only products): G = Wq@Wk^T || WvWoT = Wo^T@Wv^T
  gemm8_pair<<<24, 512, 131072, stream>>>(
      12,
      Wqb, Wkb, zeros, G, D, Dc, D,
      Wot, Wvb, zeros, WvWoT, D, Dc, D);

  // stage B (yp GEMMs): M1T = yp@G^T + bkq || VWop = yp@WvWo + bvo
  gemm8_pair<<<40, 512, 131072, stream>>>(
      20,
      yp, G, bkqB, M1T, B * Lp, D, Dc,
      yp, WvWoT, bvoB, VWop, B * Lp, D, Dc);

  // fragment packs
  transpose_v<<<dim3(D / 32, 3, B), 256, 0, stream>>>(VWop, Vt);
  pack_v<<<(B * 64 * 3) / 4, 256, 0, stream>>>(Vt, VWof);
  pack_m1<<<(B * 160) / 4, 256, 0, stream>>>(M1T, M1f);

  // attention scores + softmax (x-conversion fused) -> P fragments
  attn_qk<<<4096, 256, 0, stream>>>(x, M1f, bqkB, Pf);

  // final: out = P @ VWo + bo (f32)
  pv_out<<<1024, 256, 4 * 16 * 260 * 4, stream>>>(Pf, VWof, bo, (float*)d_out);
}

// Round 18
// 285.262 us; speedup vs baseline: 2.3957x; 1.1388x over previous
//
#include <hip/hip_runtime.h>

typedef unsigned short u16;
typedef __bf16 bf16x8 __attribute__((ext_vector_type(8)));
typedef float f32x4 __attribute__((ext_vector_type(4)));

static __device__ __forceinline__ u16 f2bf(float f) {
  unsigned u = __builtin_bit_cast(unsigned, f);
  u = u + 0x7FFFu + ((u >> 16) & 1u);   // RNE
  return (u16)(u >> 16);
}
static __device__ __forceinline__ float bf2f(u16 h) {
  return __builtin_bit_cast(float, (unsigned)h << 16);
}

#define GLOAD_LDS16(g, l) __builtin_amdgcn_global_load_lds(              \
    (const __attribute__((address_space(1))) void*)(g),                  \
    (__attribute__((address_space(3))) void*)(l), 16, 0, 0)
#define BAR() asm volatile("s_barrier" ::: "memory")
#define VMCNT(n) asm volatile("s_waitcnt vmcnt(" #n ")" ::: "memory")
#define LGKM0() do { asm volatile("s_waitcnt lgkmcnt(0)" ::: "memory");   \
                     __builtin_amdgcn_sched_barrier(0); } while (0)

// ===== prep: all independent conversions / bias precomputes, one launch =====
// blocks [0,4): zeros | [4,8): bvo=bv@Wo | [8,200): wkbq=Wk.bq |
// [200,456): bkq=Wq.bk | [456,1480): cvt Wq | [1480,2248): cvt Wk |
// [2248,3016): cvt Wv | [3016,4040): transpose Wo | [4040,5000): y pad
__global__ __launch_bounds__(256) void prep(
    const float* __restrict__ Wq, const float* __restrict__ bq,
    const float* __restrict__ Wk, const float* __restrict__ bk,
    const float* __restrict__ Wv, const float* __restrict__ bv,
    const float* __restrict__ Wo, const float* __restrict__ y,
    u16* __restrict__ Wqb, u16* __restrict__ Wkb, u16* __restrict__ Wvb,
    u16* __restrict__ Wot, u16* __restrict__ yp,
    float* __restrict__ zeros, float* __restrict__ bvo,
    float* __restrict__ wkbq, float* __restrict__ bkq) {
  __shared__ float tile[32][33];
  const int blk = blockIdx.x, tid = threadIdx.x;
  if (blk < 4) {
    zeros[blk * 256 + tid] = 0.f;
  } else if (blk < 8) {
    int j = (blk - 4) * 256 + tid;
    float s = 0.f;
    for (int e = 0; e < 1024; ++e) s += bv[e] * Wo[(long)e * 1024 + j];
    bvo[j] = s;
  } else if (blk < 200) {
    int w = (blk - 8) * 4 + (tid >> 6);  // 0..767
    int lane = tid & 63;
    const float* r = Wk + (long)w * 1024;
    float s = 0.f;
#pragma unroll
    for (int i = 0; i < 4; ++i) {
      f32x4 a = *reinterpret_cast<const f32x4*>(r + lane * 4 + i * 256);
      f32x4 b = *reinterpret_cast<const f32x4*>(bq + lane * 4 + i * 256);
      s += a[0] * b[0] + a[1] * b[1] + a[2] * b[2] + a[3] * b[3];
    }
#pragma unroll
    for (int off = 1; off < 64; off <<= 1) s += __shfl_xor(s, off, 64);
    if (lane == 0) wkbq[w] = s;
  } else if (blk < 456) {
    int w = (blk - 200) * 4 + (tid >> 6);  // 0..1023
    int lane = tid & 63;
    const float* r = Wq + (long)w * 1024;
    float s = 0.f;
#pragma unroll
    for (int i = 0; i < 4; ++i) {
      f32x4 a = *reinterpret_cast<const f32x4*>(r + lane * 4 + i * 256);
      f32x4 b = *reinterpret_cast<const f32x4*>(bk + lane * 4 + i * 256);
      s += a[0] * b[0] + a[1] * b[1] + a[2] * b[2] + a[3] * b[3];
    }
#pragma unroll
    for (int off = 1; off < 64; off <<= 1) s += __shfl_xor(s, off, 64);
    if (lane == 0) bkq[w] = s;
  } else if (blk < 3016) {
    const float* src; u16* dst; long i;
    if (blk < 1480)      { src = Wq; dst = Wqb; i = (long)(blk - 456) * 256 + tid; }
    else if (blk < 2248) { src = Wk; dst = Wkb; i = (long)(blk - 1480) * 256 + tid; }
    else                 { src = Wv; dst = Wvb; i = (long)(blk - 2248) * 256 + tid; }
    float4 v = reinterpret_cast<const float4*>(src)[i];
    ushort4 o;
    o.x = f2bf(v.x); o.y = f2bf(v.y); o.z = f2bf(v.z); o.w = f2bf(v.w);
    reinterpret_cast<ushort4*>(dst)[i] = o;
  } else if (blk < 4040) {
    int lb = blk - 3016;
    const int tx = tid & 31, ty = tid >> 5;
    const int n0 = (lb & 31) * 32, k0 = (lb >> 5) * 32;
#pragma unroll
    for (int i = 0; i < 4; ++i)
      tile[ty + i * 8][tx] = Wo[(long)(k0 + ty + i * 8) * 1024 + n0 + tx];
    __syncthreads();
#pragma unroll
    for (int i = 0; i < 4; ++i) {
      int r = ty + i * 8;
      Wot[(long)(n0 + r) * 1024 + k0 + tx] = f2bf(tile[tx][r]);
    }
  } else {
    int idx = (blk - 4040) * 256 + tid;
    int e = idx * 4;
    int c = e % 768;
    int rb = e / 768;
    int r = rb % 80, b = rb / 80;
    ushort4 o;
    if (r < 77) {
      float4 v = *reinterpret_cast<const float4*>(y + ((long)(b * 77 + r) * 768 + c));
      o.x = f2bf(v.x); o.y = f2bf(v.y); o.z = f2bf(v.z); o.w = f2bf(v.w);
    } else {
      o.x = 0; o.y = 0; o.z = 0; o.w = 0;
    }
    *reinterpret_cast<ushort4*>(yp + e) = o;
  }
}

// ====== 256x256 m201-style 8-phase bf16 GEMM body (r13/r15-proven) =========
static __device__ void gemm_body(int flat, int nb,
                                 const u16* __restrict__ A,
                                 const u16* __restrict__ Bt,
                                 const float* __restrict__ bias,
                                 u16* __restrict__ Cv,
                                 int M, int N, int K) {
  extern __shared__ __align__(16) u16 lds[];
  const int tid = threadIdx.x;
  const int lane = tid & 63, wid = tid >> 6;
  const int lr = lane & 15, lk = lane >> 4;
  const int wr = wid >> 2, wc = wid & 3;

  int widx = flat;
  if ((nb & 7) == 0) {
    int per = nb >> 3;
    widx = (flat & 7) * per + (flat >> 3);
  }
  const int nbx = N >> 8;
  const long m0 = (long)(widx / nbx) * 256;
  const long n0 = (long)(widx % nbx) * 256;
  const int nt = K >> 6;

  f32x4 acc[8][4] = {};

  const long abase = m0 * (long)K;
  const long bbase = n0 * (long)K;
  const int srl = tid >> 3;
  const int scl = tid & 7;

#define STAGE_HALF(SRC, sbase, t_, half_, ldsbase)                           \
  do {                                                                       \
    long k0_ = (long)(t_) * 64;                                              \
    _Pragma("unroll")                                                        \
    for (int j_ = 0; j_ < 2; ++j_) {                                         \
      int row_ = (half_) * 128 + j_ * 64 + srl;                              \
      int cg_ = scl ^ (row_ & 7);                                            \
      GLOAD_LDS16(SRC + (sbase) + (long)row_ * K + k0_ + cg_ * 8,            \
                  lds + (ldsbase) + row_ * 64 + scl * 8);                    \
    }                                                                        \
  } while (0)

#define LDB_ALL(p)                                                           \
  _Pragma("unroll")                                                          \
  for (int n_ = 0; n_ < 4; ++n_)                                             \
    _Pragma("unroll")                                                        \
    for (int kk_ = 0; kk_ < 2; ++kk_) {                                      \
      int row_ = wc * 64 + n_ * 16 + lr;                                     \
      int ch_ = (kk_ * 4 + lk) ^ (lr & 7);                                   \
      bq[n_][kk_] = *reinterpret_cast<const bf16x8*>(                        \
          lds + 32768 + (p) * 16384 + row_ * 64 + ch_ * 8);                  \
    }

#define LDA_Q(p, q)                                                          \
  _Pragma("unroll")                                                          \
  for (int i_ = 0; i_ < 2; ++i_)                                             \
    _Pragma("unroll")                                                        \
    for (int kk_ = 0; kk_ < 2; ++kk_) {                                      \
      int row_ = wr * 128 + ((q) * 2 + i_) * 16 + lr;                        \
      int ch_ = (kk_ * 4 + lk) ^ (lr & 7);                                   \
      af[i_][kk_] = *reinterpret_cast<const bf16x8*>(                        \
          lds + (p) * 16384 + row_ * 64 + ch_ * 8);                          \
    }

#define MFMA_Q(q)                                                            \
  __builtin_amdgcn_s_setprio(1);                                             \
  _Pragma("unroll")                                                          \
  for (int kk_ = 0; kk_ < 2; ++kk_)                                          \
    _Pragma("unroll")                                                        \
    for (int i_ = 0; i_ < 2; ++i_)                                           \
      _Pragma("unroll")                                                      \
      for (int n_ = 0; n_ < 4; ++n_)                                         \
        acc[(q) * 2 + i_][n_] = __builtin_amdgcn_mfma_f32_16x16x32_bf16(     \
            af[i_][kk_], bq[n_][kk_], acc[(q) * 2 + i_][n_], 0, 0, 0);       \
  __builtin_amdgcn_s_setprio(0);

  STAGE_HALF(A, abase, 0, 0, 0);
  STAGE_HALF(A, abase, 0, 1, 0);
  STAGE_HALF(Bt, bbase, 0, 0, 32768);
  STAGE_HALF(Bt, bbase, 0, 1, 32768);
  STAGE_HALF(Bt, bbase, 1, 0, 49152);
  STAGE_HALF(Bt, bbase, 1, 1, 49152);
  VMCNT(4);
  BAR();

  const int niter = nt >> 1;
  for (int tp = 0; tp < niter; ++tp) {
    const int T = tp << 1;
    const bool more = (T + 2 < nt);
    bf16x8 af[2][2], bq[4][2];

    LDB_ALL(0); LDA_Q(0, 0);
    STAGE_HALF(A, abase, T + 1, 0, 16384);
    BAR(); LGKM0(); MFMA_Q(0); BAR();
    LDA_Q(0, 1);
    STAGE_HALF(A, abase, T + 1, 1, 16384);
    BAR(); LGKM0(); MFMA_Q(1); BAR();
    LDA_Q(0, 2);
    if (more) STAGE_HALF(Bt, bbase, T + 2, 0, 32768);
    BAR(); LGKM0(); MFMA_Q(2); BAR();
    LDA_Q(0, 3);
    if (more) { STAGE_HALF(Bt, bbase, T + 2, 1, 32768); VMCNT(4); }
    else VMCNT(0);
    BAR(); LGKM0(); MFMA_Q(3); BAR();

    LDB_ALL(1); LDA_Q(1, 0);
    if (more) STAGE_HALF(A, abase, T + 2, 0, 0);
    BAR(); LGKM0(); MFMA_Q(0); BAR();
    LDA_Q(1, 1);
    if (more) STAGE_HALF(A, abase, T + 2, 1, 0);
    BAR(); LGKM0(); MFMA_Q(1); BAR();
    LDA_Q(1, 2);
    if (more) STAGE_HALF(Bt, bbase, T + 3, 0, 49152);
    BAR(); LGKM0(); MFMA_Q(2); BAR();
    LDA_Q(1, 3);
    if (more) { STAGE_HALF(Bt, bbase, T + 3, 1, 49152); VMCNT(4); }
    BAR(); LGKM0(); MFMA_Q(3); BAR();
  }

  const long mrow = m0 + wr * 128;
  const long ncol = n0 + wc * 64;

  __syncthreads();
  u16* ep = lds + wid * (16 * 72);
  float bb[4];
#pragma unroll
  for (int n = 0; n < 4; ++n) bb[n] = bias[ncol + n * 16 + lr];
  const int rr = lane >> 4, cc = lane & 15;
#pragma unroll
  for (int m = 0; m < 8; ++m) {
#pragma unroll
    for (int n = 0; n < 4; ++n)
#pragma unroll
      for (int j = 0; j < 4; ++j)
        ep[(lk * 4 + j) * 72 + n * 16 + lr] = f2bf(acc[m][n][j] + bb[n]);
    asm volatile("s_waitcnt lgkmcnt(0)" ::: "memory");
#pragma unroll
    for (int s = 0; s < 4; ++s) {
      uint2 v = *reinterpret_cast<const uint2*>(ep + (s * 4 + rr) * 72 + cc * 4);
      *reinterpret_cast<uint2*>(Cv + (mrow + m * 16 + s * 4 + rr) * N +
                                ncol + cc * 4) = v;
    }
    asm volatile("s_waitcnt lgkmcnt(0)" ::: "memory");
  }
#undef STAGE_HALF
#undef LDB_ALL
#undef LDA_Q
#undef MFMA_Q
}

// ---- stage A: G = Wq@Wk^T | WvWoT = Wo^T@Wv^T | bqk = yp @ wkbq ----------
__global__ __launch_bounds__(512, 2) void stageA(
    const u16* Wqb, const u16* Wkb, const u16* Wvb, const u16* Wot,
    const float* zeros, u16* G, u16* WvWoT,
    const u16* yp, const float* wkbq, float* bqk) {
  if (blockIdx.x < 24) {
    if (blockIdx.x < 12)
      gemm_body(blockIdx.x, 12, Wqb, Wkb, zeros, G, 1024, 768, 1024);
    else
      gemm_body(blockIdx.x - 12, 12, Wot, Wvb, zeros, WvWoT, 1024, 768, 1024);
  } else {
    int w = (int)(blockIdx.x - 24) * 8 + ((int)threadIdx.x >> 6);  // 0..1279
    int lane = threadIdx.x & 63;
    const u16* r = yp + (long)w * 768;
    float s = 0.f;
#pragma unroll
    for (int i = 0; i < 3; ++i) {
      ushort4 a = *reinterpret_cast<const ushort4*>(r + lane * 4 + i * 256);
      f32x4 b = *reinterpret_cast<const f32x4*>(wkbq + lane * 4 + i * 256);
      s += bf2f(a.x) * b[0] + bf2f(a.y) * b[1] + bf2f(a.z) * b[2] + bf2f(a.w) * b[3];
    }
#pragma unroll
    for (int off = 1; off < 64; off <<= 1) s += __shfl_xor(s, off, 64);
    if (lane == 0) bqk[w] = s;
  }
}

// ---- stage B: M1T = yp@G^T + bkq  ||  VWop = yp@WvWo + bvo -----------------
__global__ __launch_bounds__(512, 2) void gemm8_pair(
    int split,
    const u16* A0, const u16* B0, const float* b0, u16* C0, int M0, int N0, int K0,
    const u16* A1, const u16* B1, const float* b1, u16* C1, int M1, int N1, int K1) {
  if ((int)blockIdx.x < split)
    gemm_body(blockIdx.x, split, A0, B0, b0, C0, M0, N0, K0);
  else
    gemm_body(blockIdx.x - split, gridDim.x - split, A1, B1, b1, C1, M1, N1, K1);
}

// ---- packs1: transpose_v (VWop->Vt, flattened) + pack_m1 -------------------
__global__ __launch_bounds__(256) void packs1(const u16* __restrict__ VWop,
                                              u16* __restrict__ Vt,
                                              const u16* __restrict__ M1T,
                                              u16* __restrict__ M1f) {
  __shared__ u16 tile[32][34];
  const int blk = blockIdx.x, tid = threadIdx.x;
  if (blk < 1536) {
    const int tx = tid & 31, ty = tid >> 5;
    const int e0 = (blk & 31) * 32;
    const int k0 = ((blk >> 5) % 3) * 32;
    const int b = blk / 96;
    const u16* src = VWop + (long)b * 80 * 1024;
#pragma unroll
    for (int i = 0; i < 4; ++i) {
      int k = k0 + ty + i * 8;
      tile[ty + i * 8][tx] = (k < 80) ? src[(long)k * 1024 + e0 + tx] : (u16)0;
    }
    __syncthreads();
    u16* dst = Vt + (long)b * 1024 * 96;
#pragma unroll
    for (int i = 0; i < 4; ++i) {
      int e = e0 + ty + i * 8;
      dst[(long)e * 96 + k0 + tx] = tile[tx][ty + i * 8];
    }
  } else {
    const int lane = tid & 63;
    const int w = (blk - 1536) * 4 + (tid >> 6);  // 0..2559
    const int b = w / 160, rem = w % 160;
    const int kk = rem / 5, n = rem % 5;
    const int lr = lane & 15, lk = lane >> 4;
    const u16* src = M1T + ((long)b * 80 + n * 16 + lr) * 1024 + kk * 32 + lk * 8;
    *reinterpret_cast<ulong2*>(M1f + (long)w * 512 + lane * 8) =
        *reinterpret_cast<const ulong2*>(src);
  }
}

// --- pack Vt into fragment-major: VWof[b][ct=64][kk=3][lane=64][8] bf16 -----
__global__ __launch_bounds__(256) void pack_v(const u16* __restrict__ Vt,
                                              u16* __restrict__ Vf) {
  const int lane = threadIdx.x & 63;
  const int w = blockIdx.x * 4 + (threadIdx.x >> 6);  // 0..3071
  const int b = w / 192, rem = w % 192;
  const int ct = rem / 3, kk = rem % 3;
  const int lr = lane & 15, lk = lane >> 4;
  const u16* src = Vt + (long)b * 1024 * 96 + (long)(ct * 16 + lr) * 96 + kk * 32 + lk * 8;
  *reinterpret_cast<ulong2*>(Vf + (long)w * 512 + lane * 8) =
      *reinterpret_cast<const ulong2*>(src);
}

// ---- attn_full: x-cvt + scores + softmax + PV + f32 out, one kernel --------
// x f32 [65536][1024]; M1f [16][32][5][512]; bqk [1280]; VWof [16][64][3][512];
// out f32 [65536][1024]. 16 q-rows per block, 4096 blocks.
// Dynamic LDS union: x-tile (33KB) -> S4 (20.5KB) -> otile (66.5KB).
__global__ __launch_bounds__(256, 2) void attn_full(const float* __restrict__ x,
                                                    const u16* __restrict__ M1f,
                                                    const float* __restrict__ bqk,
                                                    const u16* __restrict__ VWof,
                                                    const float* __restrict__ bo,
                                                    float* __restrict__ out) {
  extern __shared__ __align__(16) u16 dl[];
  __shared__ __align__(16) u16 P_lds[16][104];
  const long blk = blockIdx.x;
  const int b = (int)(blk >> 8);
  const int tid = threadIdx.x;
  const int lane = tid & 63, wave = tid >> 6;
  const int lr = lane & 15, lk = lane >> 4;
  float* S4 = reinterpret_cast<float*>(dl);
  float* otf = reinterpret_cast<float*>(dl);

  // Phase 0: load 16 x-rows f32 coalesced, convert -> bf16 tile (stride 1032)
  {
    const int row = tid >> 4, cseg = tid & 15;
    const float* src = x + (blk * 16 + row) * 1024 + cseg * 64;
    u16* dst = dl + row * 1032 + cseg * 64;
#pragma unroll
    for (int i = 0; i < 16; ++i) {
      f32x4 v = *reinterpret_cast<const f32x4*>(src + i * 4);
      ushort4 o;
      o.x = f2bf(v[0]); o.y = f2bf(v[1]); o.z = f2bf(v[2]); o.w = f2bf(v[3]);
      *reinterpret_cast<ushort4*>(dst + i * 4) = o;
    }
  }
  __syncthreads();

  // Phase 1: scores = x @ M1T; wave w covers d-slice w*256..+255
  f32x4 acc[5] = {};
  const u16* mfb = M1f + (long)b * 81920;
#pragma unroll
  for (int t = 0; t < 8; ++t) {
    int kk = wave * 8 + t;
    bf16x8 qa = *reinterpret_cast<const bf16x8*>(dl + lr * 1032 + kk * 32 + lk * 8);
#pragma unroll
    for (int n = 0; n < 5; ++n) {
      bf16x8 mf = *reinterpret_cast<const bf16x8*>(mfb + ((long)kk * 5 + n) * 512 + lane * 8);
      acc[n] = __builtin_amdgcn_mfma_f32_16x16x32_bf16(qa, mf, acc[n], 0, 0, 0);
    }
  }
  __syncthreads();   // x-tile dead; dl becomes S4

#pragma unroll
  for (int n = 0; n < 5; ++n)
#pragma unroll
    for (int j = 0; j < 4; ++j)
      S4[(wave * 16 + lk * 4 + j) * 80 + n * 16 + lr] = acc[n][j];
  __syncthreads();

  // Phase 2: cross-wave reduce + bqk + softmax -> P_lds
  {
    const int r = tid >> 4, ci = tid & 15;
    const float scale = 0.088388347648318447f;  // 1/sqrt(128)
    float v[5];
    float mx = -3e38f;
#pragma unroll
    for (int i = 0; i < 5; ++i) {
      int c = ci + 16 * i;
      float s = (S4[r * 80 + c] + S4[(16 + r) * 80 + c]) +
                (S4[(32 + r) * 80 + c] + S4[(48 + r) * 80 + c]);
      s = (s + bqk[b * 80 + c]) * scale;
      if (c >= 77) s = -3e38f;
      v[i] = s;
      mx = fmaxf(mx, s);
    }
#pragma unroll
    for (int off = 1; off < 16; off <<= 1) mx = fmaxf(mx, __shfl_xor(mx, off, 64));
    float sum = 0.f, e[5];
#pragma unroll
    for (int i = 0; i < 5; ++i) { e[i] = __expf(v[i] - mx); sum += e[i]; }
#pragma unroll
    for (int off = 1; off < 16; off <<= 1) sum += __shfl_xor(sum, off, 64);
    float inv = 1.f / sum;
#pragma unroll
    for (int i = 0; i < 5; ++i) P_lds[r][ci + 16 * i] = f2bf(e[i] * inv);
    P_lds[r][80 + ci] = 0;
  }
  __syncthreads();   // S4 dead; dl becomes otile

  // Phase 3: PV via MFMA; each wave covers cols wave*256..+255
  bf16x8 pa[3];
#pragma unroll
  for (int kk = 0; kk < 3; ++kk)
    pa[kk] = *reinterpret_cast<const bf16x8*>(&P_lds[lr][kk * 32 + lk * 8]);
  const u16* vfb = VWof + (long)b * 98304;
  float* otw = otf + wave * (16 * 260);
#pragma unroll
  for (int n = 0; n < 16; ++n) {
    int ct = wave * 16 + n;
    f32x4 o = {};
#pragma unroll
    for (int kk = 0; kk < 3; ++kk) {
      bf16x8 vq = *reinterpret_cast<const bf16x8*>(vfb + ((long)ct * 3 + kk) * 512 + lane * 8);
      o = __builtin_amdgcn_mfma_f32_16x16x32_bf16(pa[kk], vq, o, 0, 0, 0);
    }
    float bov = bo[ct * 16 + lr];
#pragma unroll
    for (int j = 0; j < 4; ++j)
      otw[(lk * 4 + j) * 260 + n * 16 + lr] = o[j] + bov;
  }
  __syncthreads();

  // Bulk store: 16 rows x 1024 f32, fully coalesced f32x4 (full lines)
  float* ob = out + blk * 16384;
#pragma unroll
  for (int rnd = 0; rnd < 16; ++rnd) {
    int off = (rnd * 256 + tid) * 4;     // f32 offset in [0, 16384)
    int row = off >> 10, col = off & 1023;
    int ws = col >> 8, cl = col & 255;
    f32x4 v = *reinterpret_cast<const f32x4*>(otf + ws * (16 * 260) + row * 260 + cl);
    *reinterpret_cast<f32x4*>(ob + off) = v;
  }
}

extern "C" void kernel_launch(void* const* d_in, const int* in_sizes, int n_in,
                              void* d_out, int out_size, void* d_ws, size_t ws_size,
                              hipStream_t stream) {
  const float* x  = (const float*)d_in[0];
  const float* y  = (const float*)d_in[1];
  const float* Wq = (const float*)d_in[2];
  const float* bq = (const float*)d_in[3];
  const float* Wk = (const float*)d_in[4];
  const float* bk = (const float*)d_in[5];
  const float* Wv = (const float*)d_in[6];
  const float* bv = (const float*)d_in[7];
  const float* Wo = (const float*)d_in[8];
  const float* bo = (const float*)d_in[9];

  const int B = 16, D = 1024, Dc = 768, Lp = 80;

  char* p = (char*)d_ws;
  u16* Wqb   = (u16*)p; p += (size_t)D * D * 2;
  u16* Wkb   = (u16*)p; p += (size_t)Dc * D * 2;
  u16* Wvb   = (u16*)p; p += (size_t)Dc * D * 2;
  u16* Wot   = (u16*)p; p += (size_t)D * D * 2;
  u16* yp    = (u16*)p; p += (size_t)B * Lp * Dc * 2;
  u16* G     = (u16*)p; p += (size_t)D * Dc * 2;
  u16* WvWoT = (u16*)p; p += (size_t)D * Dc * 2;
  u16* M1T   = (u16*)p; p += (size_t)B * Lp * D * 2;
  u16* VWop  = (u16*)p; p += (size_t)B * Lp * D * 2;
  u16* Vt    = (u16*)p; p += (size_t)B * D * 96 * 2;
  u16* VWof  = (u16*)p; p += (size_t)B * 64 * 3 * 512 * 2;
  u16* M1f   = (u16*)p; p += (size_t)B * 160 * 512 * 2;
  float* zeros = (float*)p; p += (size_t)1024 * 4;
  float* bvoB  = (float*)p; p += (size_t)1024 * 4;
  float* wkbq  = (float*)p; p += (size_t)768 * 4;
  float* bkqB  = (float*)p; p += (size_t)1024 * 4;
  float* bqkB  = (float*)p; p += (size_t)1280 * 4;

  (void)hipFuncSetAttribute(reinterpret_cast<const void*>(&stageA),
                            hipFuncAttributeMaxDynamicSharedMemorySize, 131072);
  (void)hipFuncSetAttribute(reinterpret_cast<const void*>(&gemm8_pair),
                            hipFuncAttributeMaxDynamicSharedMemorySize, 131072);
  (void)hipFuncSetAttribute(reinterpret_cast<const void*>(&attn_full),
                            hipFuncAttributeMaxDynamicSharedMemorySize, 66560);

  // 1) all conversions + bias precomputes (one launch)
  prep<<<5000, 256, 0, stream>>>(Wq, bq, Wk, bk, Wv, bv, Wo, y,
                                 Wqb, Wkb, Wvb, Wot, yp,
                                 zeros, bvoB, wkbq, bkqB);

  // 2) stage A: weight-only products + bqk
  stageA<<<184, 512, 131072, stream>>>(Wqb, Wkb, Wvb, Wot, zeros, G, WvWoT,
                                       yp, wkbq, bqkB);

  // 3) stage B: M1T = yp@G^T + bkq || VWop = yp@WvWo + bvo
  gemm8_pair<<<40, 512, 131072, stream>>>(
      20,
      yp, G, bkqB, M1T, B * Lp, D, Dc,
      yp, WvWoT, bvoB, VWop, B * Lp, D, Dc);

  // 4) packs: Vt transpose + M1 fragments
  packs1<<<2176, 256, 0, stream>>>(VWop, Vt, M1T, M1f);
  // 5) V fragments
  pack_v<<<768, 256, 0, stream>>>(Vt, VWof);

  // 6) fused attention: x-cvt + QK^T + softmax + PV + bo -> f32 out
  attn_full<<<4096, 256, 66560, stream>>>(x, M1f, bqkB, VWof, bo, (float*)d_out);
}

// Round 19
// 252.440 us; speedup vs baseline: 2.7072x; 1.1300x over previous
//
#include <hip/hip_runtime.h>

typedef unsigned short u16;
typedef __bf16 bf16x8 __attribute__((ext_vector_type(8)));
typedef float f32x4 __attribute__((ext_vector_type(4)));

static __device__ __forceinline__ u16 f2bf(float f) {
  unsigned u = __builtin_bit_cast(unsigned, f);
  u = u + 0x7FFFu + ((u >> 16) & 1u);   // RNE
  return (u16)(u >> 16);
}
static __device__ __forceinline__ float bf2f(u16 h) {
  return __builtin_bit_cast(float, (unsigned)h << 16);
}

#define GLOAD_LDS16(g, l) __builtin_amdgcn_global_load_lds(              \
    (const __attribute__((address_space(1))) void*)(g),                  \
    (__attribute__((address_space(3))) void*)(l), 16, 0, 0)
#define BAR() asm volatile("s_barrier" ::: "memory")
#define VMCNT(n) asm volatile("s_waitcnt vmcnt(" #n ")" ::: "memory")
#define LGKM0() do { asm volatile("s_waitcnt lgkmcnt(0)" ::: "memory");   \
                     __builtin_amdgcn_sched_barrier(0); } while (0)

// ===== prep: all independent conversions / bias precomputes, one launch =====
__global__ __launch_bounds__(256) void prep(
    const float* __restrict__ Wq, const float* __restrict__ bq,
    const float* __restrict__ Wk, const float* __restrict__ bk,
    const float* __restrict__ Wv, const float* __restrict__ bv,
    const float* __restrict__ Wo, const float* __restrict__ y,
    u16* __restrict__ Wqb, u16* __restrict__ Wkb, u16* __restrict__ Wvb,
    u16* __restrict__ Wot, u16* __restrict__ yp,
    float* __restrict__ zeros, float* __restrict__ bvo,
    float* __restrict__ wkbq, float* __restrict__ bkq) {
  __shared__ float tile[32][33];
  const int blk = blockIdx.x, tid = threadIdx.x;
  if (blk < 4) {
    zeros[blk * 256 + tid] = 0.f;
  } else if (blk < 8) {
    int j = (blk - 4) * 256 + tid;
    float s = 0.f;
    for (int e = 0; e < 1024; ++e) s += bv[e] * Wo[(long)e * 1024 + j];
    bvo[j] = s;
  } else if (blk < 200) {
    int w = (blk - 8) * 4 + (tid >> 6);  // 0..767
    int lane = tid & 63;
    const float* r = Wk + (long)w * 1024;
    float s = 0.f;
#pragma unroll
    for (int i = 0; i < 4; ++i) {
      f32x4 a = *reinterpret_cast<const f32x4*>(r + lane * 4 + i * 256);
      f32x4 b = *reinterpret_cast<const f32x4*>(bq + lane * 4 + i * 256);
      s += a[0] * b[0] + a[1] * b[1] + a[2] * b[2] + a[3] * b[3];
    }
#pragma unroll
    for (int off = 1; off < 64; off <<= 1) s += __shfl_xor(s, off, 64);
    if (lane == 0) wkbq[w] = s;
  } else if (blk < 456) {
    int w = (blk - 200) * 4 + (tid >> 6);  // 0..1023
    int lane = tid & 63;
    const float* r = Wq + (long)w * 1024;
    float s = 0.f;
#pragma unroll
    for (int i = 0; i < 4; ++i) {
      f32x4 a = *reinterpret_cast<const f32x4*>(r + lane * 4 + i * 256);
      f32x4 b = *reinterpret_cast<const f32x4*>(bk + lane * 4 + i * 256);
      s += a[0] * b[0] + a[1] * b[1] + a[2] * b[2] + a[3] * b[3];
    }
#pragma unroll
    for (int off = 1; off < 64; off <<= 1) s += __shfl_xor(s, off, 64);
    if (lane == 0) bkq[w] = s;
  } else if (blk < 3016) {
    const float* src; u16* dst; long i;
    if (blk < 1480)      { src = Wq; dst = Wqb; i = (long)(blk - 456) * 256 + tid; }
    else if (blk < 2248) { src = Wk; dst = Wkb; i = (long)(blk - 1480) * 256 + tid; }
    else                 { src = Wv; dst = Wvb; i = (long)(blk - 2248) * 256 + tid; }
    float4 v = reinterpret_cast<const float4*>(src)[i];
    ushort4 o;
    o.x = f2bf(v.x); o.y = f2bf(v.y); o.z = f2bf(v.z); o.w = f2bf(v.w);
    reinterpret_cast<ushort4*>(dst)[i] = o;
  } else if (blk < 4040) {
    int lb = blk - 3016;
    const int tx = tid & 31, ty = tid >> 5;
    const int n0 = (lb & 31) * 32, k0 = (lb >> 5) * 32;
#pragma unroll
    for (int i = 0; i < 4; ++i)
      tile[ty + i * 8][tx] = Wo[(long)(k0 + ty + i * 8) * 1024 + n0 + tx];
    __syncthreads();
#pragma unroll
    for (int i = 0; i < 4; ++i) {
      int r = ty + i * 8;
      Wot[(long)(n0 + r) * 1024 + k0 + tx] = f2bf(tile[tx][r]);
    }
  } else {
    int idx = (blk - 4040) * 256 + tid;
    int e = idx * 4;
    int c = e % 768;
    int rb = e / 768;
    int r = rb % 80, b = rb / 80;
    ushort4 o;
    if (r < 77) {
      float4 v = *reinterpret_cast<const float4*>(y + ((long)(b * 77 + r) * 768 + c));
      o.x = f2bf(v.x); o.y = f2bf(v.y); o.z = f2bf(v.z); o.w = f2bf(v.w);
    } else {
      o.x = 0; o.y = 0; o.z = 0; o.w = 0;
    }
    *reinterpret_cast<ushort4*>(yp + e) = o;
  }
}

// ====== 256x256 m201-style 8-phase bf16 GEMM body (r13/r15-proven) =========
static __device__ void gemm_body(int flat, int nb,
                                 const u16* __restrict__ A,
                                 const u16* __restrict__ Bt,
                                 const float* __restrict__ bias,
                                 u16* __restrict__ Cv,
                                 int M, int N, int K) {
  extern __shared__ __align__(16) u16 lds[];
  const int tid = threadIdx.x;
  const int lane = tid & 63, wid = tid >> 6;
  const int lr = lane & 15, lk = lane >> 4;
  const int wr = wid >> 2, wc = wid & 3;

  int widx = flat;
  if ((nb & 7) == 0) {
    int per = nb >> 3;
    widx = (flat & 7) * per + (flat >> 3);
  }
  const int nbx = N >> 8;
  const long m0 = (long)(widx / nbx) * 256;
  const long n0 = (long)(widx % nbx) * 256;
  const int nt = K >> 6;

  f32x4 acc[8][4] = {};

  const long abase = m0 * (long)K;
  const long bbase = n0 * (long)K;
  const int srl = tid >> 3;
  const int scl = tid & 7;

#define STAGE_HALF(SRC, sbase, t_, half_, ldsbase)                           \
  do {                                                                       \
    long k0_ = (long)(t_) * 64;                                              \
    _Pragma("unroll")                                                        \
    for (int j_ = 0; j_ < 2; ++j_) {                                         \
      int row_ = (half_) * 128 + j_ * 64 + srl;                              \
      int cg_ = scl ^ (row_ & 7);                                            \
      GLOAD_LDS16(SRC + (sbase) + (long)row_ * K + k0_ + cg_ * 8,            \
                  lds + (ldsbase) + row_ * 64 + scl * 8);                    \
    }                                                                        \
  } while (0)

#define LDB_ALL(p)                                                           \
  _Pragma("unroll")                                                          \
  for (int n_ = 0; n_ < 4; ++n_)                                             \
    _Pragma("unroll")                                                        \
    for (int kk_ = 0; kk_ < 2; ++kk_) {                                      \
      int row_ = wc * 64 + n_ * 16 + lr;                                     \
      int ch_ = (kk_ * 4 + lk) ^ (lr & 7);                                   \
      bq[n_][kk_] = *reinterpret_cast<const bf16x8*>(                        \
          lds + 32768 + (p) * 16384 + row_ * 64 + ch_ * 8);                  \
    }

#define LDA_Q(p, q)                                                          \
  _Pragma("unroll")                                                          \
  for (int i_ = 0; i_ < 2; ++i_)                                             \
    _Pragma("unroll")                                                        \
    for (int kk_ = 0; kk_ < 2; ++kk_) {                                      \
      int row_ = wr * 128 + ((q) * 2 + i_) * 16 + lr;                        \
      int ch_ = (kk_ * 4 + lk) ^ (lr & 7);                                   \
      af[i_][kk_] = *reinterpret_cast<const bf16x8*>(                        \
          lds + (p) * 16384 + row_ * 64 + ch_ * 8);                          \
    }

#define MFMA_Q(q)                                                            \
  __builtin_amdgcn_s_setprio(1);                                             \
  _Pragma("unroll")                                                          \
  for (int kk_ = 0; kk_ < 2; ++kk_)                                          \
    _Pragma("unroll")                                                        \
    for (int i_ = 0; i_ < 2; ++i_)                                           \
      _Pragma("unroll")                                                      \
      for (int n_ = 0; n_ < 4; ++n_)                                         \
        acc[(q) * 2 + i_][n_] = __builtin_amdgcn_mfma_f32_16x16x32_bf16(     \
            af[i_][kk_], bq[n_][kk_], acc[(q) * 2 + i_][n_], 0, 0, 0);       \
  __builtin_amdgcn_s_setprio(0);

  STAGE_HALF(A, abase, 0, 0, 0);
  STAGE_HALF(A, abase, 0, 1, 0);
  STAGE_HALF(Bt, bbase, 0, 0, 32768);
  STAGE_HALF(Bt, bbase, 0, 1, 32768);
  STAGE_HALF(Bt, bbase, 1, 0, 49152);
  STAGE_HALF(Bt, bbase, 1, 1, 49152);
  VMCNT(4);
  BAR();

  const int niter = nt >> 1;
  for (int tp = 0; tp < niter; ++tp) {
    const int T = tp << 1;
    const bool more = (T + 2 < nt);
    bf16x8 af[2][2], bq[4][2];

    LDB_ALL(0); LDA_Q(0, 0);
    STAGE_HALF(A, abase, T + 1, 0, 16384);
    BAR(); LGKM0(); MFMA_Q(0); BAR();
    LDA_Q(0, 1);
    STAGE_HALF(A, abase, T + 1, 1, 16384);
    BAR(); LGKM0(); MFMA_Q(1); BAR();
    LDA_Q(0, 2);
    if (more) STAGE_HALF(Bt, bbase, T + 2, 0, 32768);
    BAR(); LGKM0(); MFMA_Q(2); BAR();
    LDA_Q(0, 3);
    if (more) { STAGE_HALF(Bt, bbase, T + 2, 1, 32768); VMCNT(4); }
    else VMCNT(0);
    BAR(); LGKM0(); MFMA_Q(3); BAR();

    LDB_ALL(1); LDA_Q(1, 0);
    if (more) STAGE_HALF(A, abase, T + 2, 0, 0);
    BAR(); LGKM0(); MFMA_Q(0); BAR();
    LDA_Q(1, 1);
    if (more) STAGE_HALF(A, abase, T + 2, 1, 0);
    BAR(); LGKM0(); MFMA_Q(1); BAR();
    LDA_Q(1, 2);
    if (more) STAGE_HALF(Bt, bbase, T + 3, 0, 49152);
    BAR(); LGKM0(); MFMA_Q(2); BAR();
    LDA_Q(1, 3);
    if (more) { STAGE_HALF(Bt, bbase, T + 3, 1, 49152); VMCNT(4); }
    BAR(); LGKM0(); MFMA_Q(3); BAR();
  }

  const long mrow = m0 + wr * 128;
  const long ncol = n0 + wc * 64;

  __syncthreads();
  u16* ep = lds + wid * (16 * 72);
  float bb[4];
#pragma unroll
  for (int n = 0; n < 4; ++n) bb[n] = bias[ncol + n * 16 + lr];
  const int rr = lane >> 4, cc = lane & 15;
#pragma unroll
  for (int m = 0; m < 8; ++m) {
#pragma unroll
    for (int n = 0; n < 4; ++n)
#pragma unroll
      for (int j = 0; j < 4; ++j)
        ep[(lk * 4 + j) * 72 + n * 16 + lr] = f2bf(acc[m][n][j] + bb[n]);
    asm volatile("s_waitcnt lgkmcnt(0)" ::: "memory");
#pragma unroll
    for (int s = 0; s < 4; ++s) {
      uint2 v = *reinterpret_cast<const uint2*>(ep + (s * 4 + rr) * 72 + cc * 4);
      *reinterpret_cast<uint2*>(Cv + (mrow + m * 16 + s * 4 + rr) * N +
                                ncol + cc * 4) = v;
    }
    asm volatile("s_waitcnt lgkmcnt(0)" ::: "memory");
  }
#undef STAGE_HALF
#undef LDB_ALL
#undef LDA_Q
#undef MFMA_Q
}

// ---- stage A: G = Wq@Wk^T | WvWoT = Wo^T@Wv^T | bqk = yp @ wkbq ----------
__global__ __launch_bounds__(512, 2) void stageA(
    const u16* Wqb, const u16* Wkb, const u16* Wvb, const u16* Wot,
    const float* zeros, u16* G, u16* WvWoT,
    const u16* yp, const float* wkbq, float* bqk) {
  if (blockIdx.x < 24) {
    if (blockIdx.x < 12)
      gemm_body(blockIdx.x, 12, Wqb, Wkb, zeros, G, 1024, 768, 1024);
    else
      gemm_body(blockIdx.x - 12, 12, Wot, Wvb, zeros, WvWoT, 1024, 768, 1024);
  } else {
    int w = (int)(blockIdx.x - 24) * 8 + ((int)threadIdx.x >> 6);  // 0..1279
    int lane = threadIdx.x & 63;
    const u16* r = yp + (long)w * 768;
    float s = 0.f;
#pragma unroll
    for (int i = 0; i < 3; ++i) {
      ushort4 a = *reinterpret_cast<const ushort4*>(r + lane * 4 + i * 256);
      f32x4 b = *reinterpret_cast<const f32x4*>(wkbq + lane * 4 + i * 256);
      s += bf2f(a.x) * b[0] + bf2f(a.y) * b[1] + bf2f(a.z) * b[2] + bf2f(a.w) * b[3];
    }
#pragma unroll
    for (int off = 1; off < 64; off <<= 1) s += __shfl_xor(s, off, 64);
    if (lane == 0) bqk[w] = s;
  }
}

// ---- stage B pair ----------------------------------------------------------
__global__ __launch_bounds__(512, 2) void gemm8_pair(
    int split,
    const u16* A0, const u16* B0, const float* b0, u16* C0, int M0, int N0, int K0,
    const u16* A1, const u16* B1, const float* b1, u16* C1, int M1, int N1, int K1) {
  if ((int)blockIdx.x < split)
    gemm_body(blockIdx.x, split, A0, B0, b0, C0, M0, N0, K0);
  else
    gemm_body(blockIdx.x - split, gridDim.x - split, A1, B1, b1, C1, M1, N1, K1);
}

// ---- packs1: transpose_v (VWop->Vt, flattened) + pack_m1 -------------------
__global__ __launch_bounds__(256) void packs1(const u16* __restrict__ VWop,
                                              u16* __restrict__ Vt,
                                              const u16* __restrict__ M1T,
                                              u16* __restrict__ M1f) {
  __shared__ u16 tile[32][34];
  const int blk = blockIdx.x, tid = threadIdx.x;
  if (blk < 1536) {
    const int tx = tid & 31, ty = tid >> 5;
    const int e0 = (blk & 31) * 32;
    const int k0 = ((blk >> 5) % 3) * 32;
    const int b = blk / 96;
    const u16* src = VWop + (long)b * 80 * 1024;
#pragma unroll
    for (int i = 0; i < 4; ++i) {
      int k = k0 + ty + i * 8;
      tile[ty + i * 8][tx] = (k < 80) ? src[(long)k * 1024 + e0 + tx] : (u16)0;
    }
    __syncthreads();
    u16* dst = Vt + (long)b * 1024 * 96;
#pragma unroll
    for (int i = 0; i < 4; ++i) {
      int e = e0 + ty + i * 8;
      dst[(long)e * 96 + k0 + tx] = tile[tx][ty + i * 8];
    }
  } else {
    const int lane = tid & 63;
    const int w = (blk - 1536) * 4 + (tid >> 6);  // 0..2559
    const int b = w / 160, rem = w % 160;
    const int kk = rem / 5, n = rem % 5;
    const int lr = lane & 15, lk = lane >> 4;
    const u16* src = M1T + ((long)b * 80 + n * 16 + lr) * 1024 + kk * 32 + lk * 8;
    *reinterpret_cast<ulong2*>(M1f + (long)w * 512 + lane * 8) =
        *reinterpret_cast<const ulong2*>(src);
  }
}

// --- pack Vt into fragment-major: VWof[b][ct=64][kk=3][lane=64][8] bf16 -----
__global__ __launch_bounds__(256) void pack_v(const u16* __restrict__ Vt,
                                              u16* __restrict__ Vf) {
  const int lane = threadIdx.x & 63;
  const int w = blockIdx.x * 4 + (threadIdx.x >> 6);  // 0..3071
  const int b = w / 192, rem = w % 192;
  const int ct = rem / 3, kk = rem % 3;
  const int lr = lane & 15, lk = lane >> 4;
  const u16* src = Vt + (long)b * 1024 * 96 + (long)(ct * 16 + lr) * 96 + kk * 32 + lk * 8;
  *reinterpret_cast<ulong2*>(Vf + (long)w * 512 + lane * 8) =
      *reinterpret_cast<const ulong2*>(src);
}

// ---- attn_full v2: coalesced x-read -> padded fragment tile; grouped PV ----
// Dynamic LDS: 33280 B (x fragment tile, padded stride 520/frag; then S4;
// then per-wave [16][68] f32 output tiles). 4 blocks/CU.
__global__ __launch_bounds__(256, 4) void attn_full(const float* __restrict__ x,
                                                    const u16* __restrict__ M1f,
                                                    const float* __restrict__ bqk,
                                                    const u16* __restrict__ VWof,
                                                    const float* __restrict__ bo,
                                                    float* __restrict__ out) {
  extern __shared__ __align__(16) u16 dl[];
  __shared__ __align__(16) u16 P_lds[16][104];
  const long blk = blockIdx.x;
  const int b = (int)(blk >> 8);
  const int tid = threadIdx.x;
  const int lane = tid & 63, wave = tid >> 6;
  const int lr = lane & 15, lk = lane >> 4;
  float* S4 = reinterpret_cast<float*>(dl);

  // Phase 0: row-per-round coalesced f32 reads -> padded fragment-major tile.
  // Fragment kk at dl + kk*520 (u16); element (row r, col c) -> lane
  // ((c>>3)&3)*16 + r, e = c&7.
  {
    const float* xb = x + blk * 16384;
#pragma unroll
    for (int r = 0; r < 16; ++r) {
      f32x4 v = *reinterpret_cast<const f32x4*>(xb + r * 1024 + tid * 4);
      ushort4 o;
      o.x = f2bf(v[0]); o.y = f2bf(v[1]); o.z = f2bf(v[2]); o.w = f2bf(v[3]);
      int c = tid * 4;
      int kk = c >> 5, lkx = (c >> 3) & 3, e = c & 7;
      *reinterpret_cast<ushort4*>(dl + kk * 520 + (lkx * 16 + r) * 8 + e) = o;
    }
  }
  __syncthreads();

  // Phase 1: scores = x @ M1T; wave w covers d-slice w*256..+255
  f32x4 acc[5] = {};
  const u16* mfb = M1f + (long)b * 81920;
#pragma unroll
  for (int t = 0; t < 8; ++t) {
    int kk = wave * 8 + t;
    bf16x8 qa = *reinterpret_cast<const bf16x8*>(dl + kk * 520 + lane * 8);
#pragma unroll
    for (int n = 0; n < 5; ++n) {
      bf16x8 mf = *reinterpret_cast<const bf16x8*>(mfb + ((long)kk * 5 + n) * 512 + lane * 8);
      acc[n] = __builtin_amdgcn_mfma_f32_16x16x32_bf16(qa, mf, acc[n], 0, 0, 0);
    }
  }
  __syncthreads();   // x-tile dead; dl becomes S4

#pragma unroll
  for (int n = 0; n < 5; ++n)
#pragma unroll
    for (int j = 0; j < 4; ++j)
      S4[(wave * 16 + lk * 4 + j) * 80 + n * 16 + lr] = acc[n][j];
  __syncthreads();

  // Phase 2: cross-wave reduce + bqk + softmax -> P_lds
  {
    const int r = tid >> 4, ci = tid & 15;
    const float scale = 0.088388347648318447f;  // 1/sqrt(128)
    float v[5];
    float mx = -3e38f;
#pragma unroll
    for (int i = 0; i < 5; ++i) {
      int c = ci + 16 * i;
      float s = (S4[r * 80 + c] + S4[(16 + r) * 80 + c]) +
                (S4[(32 + r) * 80 + c] + S4[(48 + r) * 80 + c]);
      s = (s + bqk[b * 80 + c]) * scale;
      if (c >= 77) s = -3e38f;
      v[i] = s;
      mx = fmaxf(mx, s);
    }
#pragma unroll
    for (int off = 1; off < 16; off <<= 1) mx = fmaxf(mx, __shfl_xor(mx, off, 64));
    float sum = 0.f, e[5];
#pragma unroll
    for (int i = 0; i < 5; ++i) { e[i] = __expf(v[i] - mx); sum += e[i]; }
#pragma unroll
    for (int off = 1; off < 16; off <<= 1) sum += __shfl_xor(sum, off, 64);
    float inv = 1.f / sum;
#pragma unroll
    for (int i = 0; i < 5; ++i) P_lds[r][ci + 16 * i] = f2bf(e[i] * inv);
    P_lds[r][80 + ci] = 0;
  }
  __syncthreads();   // S4 dead; dl becomes per-wave output tiles

  // Phase 3: PV via MFMA in 4 column-groups; per-wave [16][68] f32 tile.
  bf16x8 pa[3];
#pragma unroll
  for (int kk = 0; kk < 3; ++kk)
    pa[kk] = *reinterpret_cast<const bf16x8*>(&P_lds[lr][kk * 32 + lk * 8]);
  const u16* vfb = VWof + (long)b * 98304;
  float* otw = reinterpret_cast<float*>(dl) + wave * (16 * 68);
  float* ob = out + blk * 16384;
  const int rr = lane >> 4, cc = lane & 15;
#pragma unroll
  for (int grp = 0; grp < 4; ++grp) {
#pragma unroll
    for (int n = 0; n < 4; ++n) {
      int ct = wave * 16 + grp * 4 + n;
      f32x4 o = {};
#pragma unroll
      for (int kk = 0; kk < 3; ++kk) {
        bf16x8 vq = *reinterpret_cast<const bf16x8*>(vfb + ((long)ct * 3 + kk) * 512 + lane * 8);
        o = __builtin_amdgcn_mfma_f32_16x16x32_bf16(pa[kk], vq, o, 0, 0, 0);
      }
      float bov = bo[ct * 16 + lr];
#pragma unroll
      for (int j = 0; j < 4; ++j)
        otw[(lk * 4 + j) * 68 + n * 16 + lr] = o[j] + bov;
    }
    asm volatile("s_waitcnt lgkmcnt(0)" ::: "memory");
#pragma unroll
    for (int s = 0; s < 4; ++s) {
      f32x4 v = *reinterpret_cast<const f32x4*>(otw + (s * 4 + rr) * 68 + cc * 4);
      *reinterpret_cast<f32x4*>(ob + (s * 4 + rr) * 1024 + wave * 256 +
                                grp * 64 + cc * 4) = v;
    }
    asm volatile("s_waitcnt lgkmcnt(0)" ::: "memory");
  }
}

extern "C" void kernel_launch(void* const* d_in, const int* in_sizes, int n_in,
                              void* d_out, int out_size, void* d_ws, size_t ws_size,
                              hipStream_t stream) {
  const float* x  = (const float*)d_in[0];
  const float* y  = (const float*)d_in[1];
  const float* Wq = (const float*)d_in[2];
  const float* bq = (const float*)d_in[3];
  const float* Wk = (const float*)d_in[4];
  const float* bk = (const float*)d_in[5];
  const float* Wv = (const float*)d_in[6];
  const float* bv = (const float*)d_in[7];
  const float* Wo = (const float*)d_in[8];
  const float* bo = (const float*)d_in[9];

  const int B = 16, D = 1024, Dc = 768, Lp = 80;

  char* p = (char*)d_ws;
  u16* Wqb   = (u16*)p; p += (size_t)D * D * 2;
  u16* Wkb   = (u16*)p; p += (size_t)Dc * D * 2;
  u16* Wvb   = (u16*)p; p += (size_t)Dc * D * 2;
  u16* Wot   = (u16*)p; p += (size_t)D * D * 2;
  u16* yp    = (u16*)p; p += (size_t)B * Lp * Dc * 2;
  u16* G     = (u16*)p; p += (size_t)D * Dc * 2;
  u16* WvWoT = (u16*)p; p += (size_t)D * Dc * 2;
  u16* M1T   = (u16*)p; p += (size_t)B * Lp * D * 2;
  u16* VWop  = (u16*)p; p += (size_t)B * Lp * D * 2;
  u16* Vt    = (u16*)p; p += (size_t)B * D * 96 * 2;
  u16* VWof  = (u16*)p; p += (size_t)B * 64 * 3 * 512 * 2;
  u16* M1f   = (u16*)p; p += (size_t)B * 160 * 512 * 2;
  float* zeros = (float*)p; p += (size_t)1024 * 4;
  float* bvoB  = (float*)p; p += (size_t)1024 * 4;
  float* wkbq  = (float*)p; p += (size_t)768 * 4;
  float* bkqB  = (float*)p; p += (size_t)1024 * 4;
  float* bqkB  = (float*)p; p += (size_t)1280 * 4;

  (void)hipFuncSetAttribute(reinterpret_cast<const void*>(&stageA),
                            hipFuncAttributeMaxDynamicSharedMemorySize, 131072);
  (void)hipFuncSetAttribute(reinterpret_cast<const void*>(&gemm8_pair),
                            hipFuncAttributeMaxDynamicSharedMemorySize, 131072);
  (void)hipFuncSetAttribute(reinterpret_cast<const void*>(&attn_full),
                            hipFuncAttributeMaxDynamicSharedMemorySize, 33280);

  // 1) all conversions + bias precomputes (one launch)
  prep<<<5000, 256, 0, stream>>>(Wq, bq, Wk, bk, Wv, bv, Wo, y,
                                 Wqb, Wkb, Wvb, Wot, yp,
                                 zeros, bvoB, wkbq, bkqB);

  // 2) stage A: weight-only products + bqk
  stageA<<<184, 512, 131072, stream>>>(Wqb, Wkb, Wvb, Wot, zeros, G, WvWoT,
                                       yp, wkbq, bqkB);

  // 3) stage B: M1T = yp@G^T + bkq || VWop = yp@WvWo + bvo
  gemm8_pair<<<40, 512, 131072, stream>>>(
      20,
      yp, G, bkqB, M1T, B * Lp, D, Dc,
      yp, WvWoT, bvoB, VWop, B * Lp, D, Dc);

  // 4) packs: Vt transpose + M1 fragments
  packs1<<<2176, 256, 0, stream>>>(VWop, Vt, M1T, M1f);
  // 5) V fragments
  pack_v<<<768, 256, 0, stream>>>(Vt, VWof);

  // 6) fused attention: x-cvt + QK^T + softmax + PV + bo -> f32 out
  attn_full<<<4096, 256, 33280, stream>>>(x, M1f, bqkB, VWof, bo, (float*)d_out);
}